// Round 11
// baseline (1886.930 us; speedup 1.0000x reference)
//
#include <hip/hip_runtime.h>
#include <hip/hip_bf16.h>
#include <hip/hip_fp16.h>
#include <math.h>

// ---------------------------------------------------------------------------
// GATGNN forward. fp32 math + fp32 LDS tiles (r8 core, zero-spill, proven);
// ea / M(tj) HBM streams fp16; P fp16 (~138 MB ws).
//   h = x@Wn + bn; ea = leaky_relu(eattr@We + be)        [ea fp16 in HBM]
//   CSR build once (counts/scan/fill -> offs, pos[e] = CSR slot of edge e).
//   per layer:
//     P = h@Wtop  (fp16 out)             (fp32 register-tiled GEMM)
//     fused: M = ea@Wbot; ti=sp(P[dst]+M), tj=sp(P[src]+M);
//            tj -> Mp[pos[e]] (fp16, CSR-ordered); a1 -> a1p[pos[e]];
//            a1 stats via atomics
//     aggregate (CSR, sequential reads, no indirection, no atomics):
//            per dst node i in [offs[n],offs[n+1]): w=exp(sp(BN(a1p[i])));
//            aggn = (sum Mp[i]*w)/(sum w); col stats block-reduced
//     h = sp(BN(aggn))                    (conv_bias cancels in BN)
//   comp attention + seg-softmax over sorted batch + pool + fc
// Lessons pinned:
//  - NEVER pass min-waves to __launch_bounds__ (r6/r7: VGPR cap -> GBs spill).
//  - r9: dot2 reg-tiles (VGPR 144) killed occupancy -> keep 52-VGPR fp32 LDS.
//  - r10: CSR gather with eids->a1->M double indirection was as slow as
//    atomics (dependent-load chain). This round: permute AT WRITE time.
// ---------------------------------------------------------------------------

typedef unsigned short ushortt;

__device__ __forceinline__ float sp_f(float x) {
  return x > 20.0f ? x : __logf(1.0f + __expf(x));
}
__device__ __forceinline__ float h2f(ushortt u) {
  union { ushortt u; __half h; } c; c.u = u;
  return __half2float(c.h);
}
__device__ __forceinline__ ushortt f2h(float f) {
  union { __half h; ushortt u; } c; c.h = __float2half(f);
  return c.u;
}
__device__ __forceinline__ float4 h4_to_f4(ushort4 u) {
  return make_float4(h2f(u.x), h2f(u.y), h2f(u.z), h2f(u.w));
}

// Register-tiled GEMM: out[R,64] = act(in[R,K] @ W[K,64] (+ b))
// Block: 256 thr, tile 64 rows x 64 cols; thread: 4 rows x 4 cols.
// LDS tiles ALWAYS fp32 (r8 core). FP16IN: global `in` is fp16, converted
// during LDS staging. FUSE_A: epilogue gathers fp16 P[dst],P[src], writes tj
// (fp16) to out[pos[e]], a1 to a1p[pos[e]], a1 sum/sumsq into stats[0..1].
template<int K, int ACT, int BIAS, int FUSE_A, int FP16IN, typename IT, typename OT>
__global__ __launch_bounds__(256) void k_gemm_rt(
    const IT* __restrict__ in, const float* __restrict__ W,
    const float* __restrict__ b, OT* __restrict__ out, int R,
    const ushortt* __restrict__ P, const int* __restrict__ eidx,
    const int* __restrict__ pos, const float* __restrict__ catt,
    float* __restrict__ a1, float* __restrict__ stats)
{
  constexpr int KP = (K + 3) / 4 * 4;   // k padded to x4 (zero-filled)
  constexpr int LS = KP + 4;            // ins row stride (floats, 16B-aligned)
  __shared__ __align__(16) float ins[64 * LS];
  __shared__ __align__(16) float Ws[KP * 64];
  __shared__ float atts[128];
  __shared__ float ssum[4], ssq[4];

  const int tx = threadIdx.x;
  const int b0 = blockIdx.x * 64;

  for (int i = tx; i < KP * 64; i += 256) {
    const int k = i >> 6;
    Ws[i] = (k < K) ? W[i] : 0.0f;      // W row-major [K][64]; pad rows zero
  }
  if (FP16IN) {
    static_assert(!FP16IN || (K % 8 == 0), "fp16 staging needs K%8==0");
    for (int i = tx; i < 64 * (K / 8); i += 256) {
      const int row = i / (K / 8);
      const int k8 = i % (K / 8);
      long r = b0 + row; if (r >= R) r = R - 1;   // clamp: values unused
      const ushortt* sp = &((const ushortt*)in)[r * (long)K + k8 * 8];
      const ushort4 u0 = *(const ushort4*)sp;
      const ushort4 u1 = *(const ushort4*)(sp + 4);
      *(float4*)&ins[row * LS + k8 * 8]     = h4_to_f4(u0);
      *(float4*)&ins[row * LS + k8 * 8 + 4] = h4_to_f4(u1);
    }
  } else {
    for (int i = tx; i < 64 * (KP / 4); i += 256) {
      const int row = i / (KP / 4);
      const int k4 = i % (KP / 4);
      long r = b0 + row; if (r >= R) r = R - 1;   // clamp: values unused
      float4 v;
      if (K % 4 == 0) {
        v = *(const float4*)&((const float*)in)[r * (long)K + k4 * 4];
      } else {
        float t[4];
        #pragma unroll
        for (int j = 0; j < 4; ++j) {
          const int k = k4 * 4 + j;
          t[j] = (k < K) ? ((const float*)in)[r * (long)K + k] : 0.0f;
        }
        v = make_float4(t[0], t[1], t[2], t[3]);
      }
      *(float4*)&ins[row * LS + k4 * 4] = v;
    }
  }
  if (FUSE_A) { if (tx < 128) atts[tx] = catt[tx]; }
  __syncthreads();

  const int lr0 = ((tx >> 6) << 4) + (((tx >> 4) & 3) << 2);  // local row base
  const int c0 = (tx & 15) << 2;                               // col base
  float acc[4][4];
  #pragma unroll
  for (int i = 0; i < 4; ++i)
    #pragma unroll
    for (int j = 0; j < 4; ++j) acc[i][j] = 0.0f;

  #pragma unroll 4
  for (int k4 = 0; k4 < KP / 4; ++k4) {
    float4 w[4], a[4];
    #pragma unroll
    for (int kk = 0; kk < 4; ++kk)
      w[kk] = *(const float4*)&Ws[(k4 * 4 + kk) * 64 + c0];
    #pragma unroll
    for (int ri = 0; ri < 4; ++ri)
      a[ri] = *(const float4*)&ins[(lr0 + ri) * LS + k4 * 4];
    #pragma unroll
    for (int ri = 0; ri < 4; ++ri) {
      const float* av = (const float*)&a[ri];
      #pragma unroll
      for (int kk = 0; kk < 4; ++kk) {
        acc[ri][0] = fmaf(av[kk], w[kk].x, acc[ri][0]);
        acc[ri][1] = fmaf(av[kk], w[kk].y, acc[ri][1]);
        acc[ri][2] = fmaf(av[kk], w[kk].z, acc[ri][2]);
        acc[ri][3] = fmaf(av[kk], w[kk].w, acc[ri][3]);
      }
    }
  }

  if (!FUSE_A) {
    float4 bias = make_float4(0.f, 0.f, 0.f, 0.f);
    if (BIAS) bias = *(const float4*)&b[c0];
    #pragma unroll
    for (int ri = 0; ri < 4; ++ri) {
      const long r = b0 + lr0 + ri;
      if (r >= R) continue;
      float4 v;
      v.x = acc[ri][0] + bias.x; v.y = acc[ri][1] + bias.y;
      v.z = acc[ri][2] + bias.z; v.w = acc[ri][3] + bias.w;
      if (ACT == 1) {
        v.x = v.x >= 0.f ? v.x : 0.2f * v.x;  v.y = v.y >= 0.f ? v.y : 0.2f * v.y;
        v.z = v.z >= 0.f ? v.z : 0.2f * v.z;  v.w = v.w >= 0.f ? v.w : 0.2f * v.w;
      }
      if (sizeof(OT) == 4) {
        *(float4*)&out[r * 64 + c0] = v;
      } else {
        ushort4 u;
        u.x = f2h(v.x); u.y = f2h(v.y); u.z = f2h(v.z); u.w = f2h(v.w);
        *(ushort4*)&out[r * 64 + c0] = u;
      }
    }
  } else {
    // epilogue: ti/tj from fp16 P; tj -> out[pos[e]] (fp16, CSR order);
    // a1 -> a1p[pos[e]]; a1 stats
    float s1 = 0.f, s2 = 0.f;
    #pragma unroll
    for (int ri = 0; ri < 4; ++ri) {
      const long e = b0 + lr0 + ri;
      float part = 0.0f;
      int pe = 0;
      if (e < R) {
        const int s = eidx[e];
        const int d = eidx[(long)R + e];
        pe = pos[e];
        const float4 Pd = h4_to_f4(*(const ushort4*)&P[(long)d * 64 + c0]);
        const float4 Ps = h4_to_f4(*(const ushort4*)&P[(long)s * 64 + c0]);
        float tj[4];
        const float ti0 = sp_f(Pd.x + acc[ri][0]);
        const float ti1 = sp_f(Pd.y + acc[ri][1]);
        const float ti2 = sp_f(Pd.z + acc[ri][2]);
        const float ti3 = sp_f(Pd.w + acc[ri][3]);
        tj[0] = sp_f(Ps.x + acc[ri][0]);
        tj[1] = sp_f(Ps.y + acc[ri][1]);
        tj[2] = sp_f(Ps.z + acc[ri][2]);
        tj[3] = sp_f(Ps.w + acc[ri][3]);
        ushort4 u;
        u.x = f2h(tj[0]); u.y = f2h(tj[1]); u.z = f2h(tj[2]); u.w = f2h(tj[3]);
        *(ushort4*)&out[(long)pe * 64 + c0] = u;
        part = ti0 * atts[c0] + ti1 * atts[c0 + 1] + ti2 * atts[c0 + 2] + ti3 * atts[c0 + 3]
             + tj[0] * atts[64 + c0] + tj[1] * atts[64 + c0 + 1]
             + tj[2] * atts[64 + c0 + 2] + tj[3] * atts[64 + c0 + 3];
      }
      #pragma unroll
      for (int off = 8; off; off >>= 1) part += __shfl_xor(part, off);
      if ((tx & 15) == 0 && e < R) {
        const float v = sp_f(part);
        a1[pe] = v;
        s1 += v; s2 += v * v;
      }
    }
    s1 += __shfl_xor(s1, 16); s2 += __shfl_xor(s2, 16);
    s1 += __shfl_xor(s1, 32); s2 += __shfl_xor(s2, 32);
    if ((tx & 63) == 0) { ssum[tx >> 6] = s1; ssq[tx >> 6] = s2; }
    __syncthreads();
    if (tx == 0) {
      atomicAdd(&stats[0], ssum[0] + ssum[1] + ssum[2] + ssum[3]);
      atomicAdd(&stats[1], ssq[0] + ssq[1] + ssq[2] + ssq[3]);
    }
  }
}

// ---------- CSR build (once per launch; graph static across layers) --------
__global__ __launch_bounds__(256) void k_count(
    const int* __restrict__ dst, int* __restrict__ counts, int E)
{
  for (int i = blockIdx.x * 256 + threadIdx.x; i < E; i += gridDim.x * 256)
    atomicAdd(&counts[dst[i]], 1);
}

// single-block exclusive scan: offs[0..N-1] = exclusive prefix, offs[N] = E
__global__ __launch_bounds__(1024) void k_scan(
    const int* __restrict__ counts, int* __restrict__ offs, int N)
{
  __shared__ int part[1024];
  const int t = threadIdx.x;
  const int chunk = (N + 1023) >> 10;
  const int s0 = t * chunk;
  int sum = 0;
  for (int i = 0; i < chunk; ++i) {
    const int idx = s0 + i;
    if (idx < N) sum += counts[idx];
  }
  part[t] = sum;
  __syncthreads();
  for (int off = 1; off < 1024; off <<= 1) {
    const int v = (t >= off) ? part[t - off] : 0;
    __syncthreads();
    part[t] += v;
    __syncthreads();
  }
  int base = (t == 0) ? 0 : part[t - 1];
  for (int i = 0; i < chunk; ++i) {
    const int idx = s0 + i;
    if (idx < N) { offs[idx] = base; base += counts[idx]; }
  }
  if (N - 1 >= s0 && N - 1 < s0 + chunk) offs[N] = base;
}

// pos[e] = CSR slot of edge e
__global__ __launch_bounds__(256) void k_fill(
    const int* __restrict__ dst, const int* __restrict__ offs,
    int* __restrict__ cursors, int* __restrict__ pos, int E)
{
  for (int i = blockIdx.x * 256 + threadIdx.x; i < E; i += gridDim.x * 256) {
    const int d = dst[i];
    pos[i] = offs[d] + atomicAdd(&cursors[d], 1);
  }
}

// ---------- aggregate: CSR-ordered sequential reads, no atomics on agg ------
// one wave per dst node: w = exp(sp(BN(a1p[i]))) inline;
// aggn[n] = (sum_i Mp[i]*w)/(sum_i w); col sum/sumsq block-reduced into cs.
__global__ __launch_bounds__(256) void k_aggregate(
    const int* __restrict__ offs, const float* __restrict__ a1p,
    const ushortt* __restrict__ Mp, const float* __restrict__ stats,
    float invE, float* __restrict__ aggn, float* __restrict__ cs, int N)
{
  const float mean = stats[0] * invE;
  const float var = stats[1] * invE - mean * mean;
  const float scl = rsqrtf(var + 1e-5f);
  const int t = threadIdx.x & 63;
  const int wid = threadIdx.x >> 6;
  float s = 0.f, s2 = 0.f;
  const long step = (long)gridDim.x * 4;
  for (long n = (long)blockIdx.x * 4 + wid; n < N; n += step) {
    const int o0 = offs[n];
    const int o1 = offs[n + 1];
    float av = 0.f, sew = 0.f;
    #pragma unroll 2
    for (int i = o0; i < o1; ++i) {
      const float w = __expf(sp_f((a1p[i] - mean) * scl));
      av = fmaf(h2f(Mp[(long)i * 64 + t]), w, av);
      sew += w;
    }
    const float v = (o1 > o0) ? av / sew : 0.0f;
    aggn[n * 64 + t] = v;
    s += v; s2 += v * v;
  }
  __shared__ float b1[256], b2[256];
  b1[threadIdx.x] = s; b2[threadIdx.x] = s2;
  __syncthreads();
  if (threadIdx.x < 64) {
    atomicAdd(&cs[t], b1[t] + b1[64 + t] + b1[128 + t] + b1[192 + t]);
    atomicAdd(&cs[64 + t], b2[t] + b2[64 + t] + b2[128 + t] + b2[192 + t]);
  }
}

// h = sp((aggn - mean_c) * rsqrt(var_c + eps))
__global__ __launch_bounds__(256) void k_hnew(
    const float* __restrict__ aggn, const float* __restrict__ cs,
    float invN, float* __restrict__ h, int N)
{
  const int c = threadIdx.x & 63;
  const int r = threadIdx.x >> 6;
  const float mean = cs[c] * invN;
  const float var = cs[64 + c] * invN - mean * mean;
  const float scl = rsqrtf(var + 1e-5f);
  for (long n = (long)blockIdx.x * 4 + r; n < N; n += (long)gridDim.x * 4)
    h[n * 64 + c] = sp_f((aggn[n * 64 + c] - mean) * scl);
}

// composition attention score a[n] = sp(concat(h,gf)@Wc + bc) @ attW + attb
__global__ __launch_bounds__(256) void k_comp(
    const float* __restrict__ h, const float* __restrict__ gf,
    const int* __restrict__ batch, const float* __restrict__ Wc,
    const float* __restrict__ bc, const float* __restrict__ aw,
    const float* __restrict__ ab, float* __restrict__ aN, int N)
{
  __shared__ float Wcs[167 * 32];
  __shared__ float aws[32];
  __shared__ float bcs[32];
  for (int i = threadIdx.x; i < 167 * 32; i += 256) Wcs[i] = Wc[i];
  if (threadIdx.x < 32) { aws[threadIdx.x] = aw[threadIdx.x]; bcs[threadIdx.x] = bc[threadIdx.x]; }
  __syncthreads();
  const int t = threadIdx.x & 63;
  const int wid = threadIdx.x >> 6;
  const int col = t & 31;
  const float ab0 = ab[0];
  const int step = gridDim.x * 4;
  for (int n = blockIdx.x * 4 + wid; n < N; n += step) {
    const int g = batch[n];
    const float hq = h[(long)n * 64 + t];
    const float g1 = gf[(long)g * 103 + t];
    const float g2 = (t < 39) ? gf[(long)g * 103 + 64 + t] : 0.f;
    float acc = bcs[col];
    #pragma unroll 8
    for (int k = 0; k < 64; ++k) acc = fmaf(__shfl(hq, k), Wcs[k * 32 + col], acc);
    #pragma unroll 8
    for (int k = 0; k < 64; ++k) acc = fmaf(__shfl(g1, k), Wcs[(64 + k) * 32 + col], acc);
    #pragma unroll
    for (int k = 0; k < 39; ++k) acc = fmaf(__shfl(g2, k), Wcs[(128 + k) * 32 + col], acc);
    float val = sp_f(acc) * aws[col];
    #pragma unroll
    for (int off = 16; off; off >>= 1) val += __shfl_xor(val, off);
    if (t == 0) aN[n] = val + ab0;
  }
}

// one 64-thread block per graph: seg-softmax over sorted batch + pool + fc
__global__ __launch_bounds__(64) void k_pool(
    const float* __restrict__ h, const float* __restrict__ aN,
    const int* __restrict__ batch, const float* __restrict__ fcW,
    const float* __restrict__ fcb, float* __restrict__ out, int N, int G)
{
  const int g = blockIdx.x;
  const int t = threadIdx.x;
  int lo = 0, hi = N;
  while (lo < hi) { int mid = (lo + hi) >> 1; if (batch[mid] < g) lo = mid + 1; else hi = mid; }
  const int s = lo;
  hi = N;
  while (lo < hi) { int mid = (lo + hi) >> 1; if (batch[mid] < g + 1) lo = mid + 1; else hi = mid; }
  const int e2 = lo;
  if (s >= e2) { if (t == 0) out[g] = fcb[0]; return; }
  float mx = -1e30f;
  for (int i = s + t; i < e2; i += 64) mx = fmaxf(mx, aN[i]);
  #pragma unroll
  for (int off = 32; off; off >>= 1) mx = fmaxf(mx, __shfl_xor(mx, off));
  float se = 0.f;
  for (int i = s + t; i < e2; i += 64) se += __expf(aN[i] - mx);
  #pragma unroll
  for (int off = 32; off; off >>= 1) se += __shfl_xor(se, off);
  float acc = 0.f;
  for (int n = s; n < e2; ++n) {
    const float w = __expf(aN[n] - mx);
    acc = fmaf(h[(long)n * 64 + t], w, acc);
  }
  float part = (acc / se) * fcW[t];
  #pragma unroll
  for (int off = 32; off; off >>= 1) part += __shfl_xor(part, off);
  if (t == 0) out[g] = part + fcb[0];
}

extern "C" void kernel_launch(void* const* d_in, const int* in_sizes, int n_in,
                              void* d_out, int out_size, void* d_ws, size_t ws_size,
                              hipStream_t stream)
{
  const float* x     = (const float*)d_in[0];
  const int*   eidx  = (const int*)  d_in[1];
  const float* eattr = (const float*)d_in[2];
  const int*   batch = (const int*)  d_in[3];
  const float* gfeat = (const float*)d_in[4];
  const float* embnW = (const float*)d_in[5];
  const float* embnb = (const float*)d_in[6];
  const float* embeW = (const float*)d_in[7];
  const float* embeb = (const float*)d_in[8];
  const float* convW = (const float*)d_in[9];
  const float* convA = (const float*)d_in[10];
  // d_in[11] = conv_bias: cancels exactly in training-mode BatchNorm
  const float* compW = (const float*)d_in[12];
  const float* compb = (const float*)d_in[13];
  const float* attW  = (const float*)d_in[14];
  const float* attb  = (const float*)d_in[15];
  const float* fcW   = (const float*)d_in[16];
  const float* fcb   = (const float*)d_in[17];
  float* out = (float*)d_out;

  const int N = in_sizes[0] / 92;
  const int E = in_sizes[1] / 2;
  const int G = in_sizes[4] / 103;

  // workspace (~138 MB): fp32 node buffers, CSR ints, fp16 edge streams + P
  char* pw = (char*)d_ws;
  float* h     = (float*)pw;  pw += (size_t)N * 64 * 4;
  float* aggn  = (float*)pw;  pw += (size_t)N * 64 * 4;
  float* aE    = (float*)pw;  pw += (size_t)E * 4;        // a1p (CSR-ordered)
  float* stats = (float*)pw;  pw += 256 * 4;              // [0..1] BN-E, [64..191] cs
  float* aN    = (float*)pw;  pw += (size_t)N * 4;
  int* counts  = (int*)pw;    pw += (size_t)N * 4;        // counts+cursors: one memset
  int* cursors = (int*)pw;    pw += (size_t)N * 4;
  int* offs    = (int*)pw;    pw += ((size_t)N + 1) * 4;
  int* pos     = (int*)pw;    pw += (size_t)E * 4;
  pw = (char*)(((size_t)pw + 63) & ~(size_t)63);
  ushortt* Pp  = (ushortt*)pw; pw += (size_t)N * 64 * 2;  // P fp16
  ushortt* ea  = (ushortt*)pw; pw += (size_t)E * 64 * 2;  // fp16
  ushortt* M   = (ushortt*)pw;                            // fp16 tj, CSR-ordered

  const int gE64 = (E + 63) / 64;
  const int gN64 = (N + 63) / 64;

  k_gemm_rt<92, 0, 1, 0, 0, float, float><<<gN64, 256, 0, stream>>>(
      x, embnW, embnb, h, N, nullptr, nullptr, nullptr, nullptr, nullptr, nullptr);
  k_gemm_rt<41, 1, 1, 0, 0, float, ushortt><<<gE64, 256, 0, stream>>>(
      eattr, embeW, embeb, ea, E, nullptr, nullptr, nullptr, nullptr, nullptr, nullptr);

  // CSR build (dst = eidx[E..2E))
  hipMemsetAsync(counts, 0, 2 * (size_t)N * sizeof(int), stream);
  k_count<<<2048, 256, 0, stream>>>(eidx + E, counts, E);
  k_scan<<<1, 1024, 0, stream>>>(counts, offs, N);
  k_fill<<<2048, 256, 0, stream>>>(eidx + E, offs, cursors, pos, E);

  for (int l = 0; l < 3; ++l) {
    const float* Wl = convW + (size_t)l * 128 * 64;
    const float* Al = convA + (size_t)l * 128;
    hipMemsetAsync(stats, 0, 256 * sizeof(float), stream);
    k_gemm_rt<64, 0, 0, 0, 0, float, ushortt><<<gN64, 256, 0, stream>>>(
        h, Wl, nullptr, Pp, N, nullptr, nullptr, nullptr, nullptr, nullptr, nullptr);
    k_gemm_rt<64, 0, 0, 1, 1, ushortt, ushortt><<<gE64, 256, 0, stream>>>(
        ea, Wl + 64 * 64, nullptr, M, E, Pp, eidx, pos, Al, aE, stats);
    k_aggregate<<<(N + 3) / 4, 256, 0, stream>>>(offs, aE, M, stats,
                                                 1.0f / (float)E, aggn, stats + 64, N);
    k_hnew<<<2048, 256, 0, stream>>>(aggn, stats + 64, 1.0f / (float)N, h, N);
  }

  k_comp<<<gN64, 256, 0, stream>>>(h, gfeat, batch, compW, compb, attW, attb, aN, N);
  k_pool<<<G, 64, 0, stream>>>(h, aN, batch, fcW, fcb, out, N, G);

  (void)n_in; (void)out_size; (void)ws_size;
}

// Round 12
// 1070.243 us; speedup vs baseline: 1.7631x; 1.7631x over previous
//
#include <hip/hip_runtime.h>
#include <hip/hip_bf16.h>
#include <hip/hip_fp16.h>
#include <math.h>

// ---------------------------------------------------------------------------
// GATGNN forward. fp32 math + fp32 LDS tiles (52-VGPR zero-spill core);
// edge streams fp16 and ALL CSR-ordered from the start (~140 MB ws).
//   CSR build first: eids (CSR slot -> edge), srcp/dstp (CSR-ordered endpoints)
//   h = x@Wn + bn
//   ea = leaky_relu(eattr@We + be)  -- staging GATHERS rows by eids, so ea is
//                                      written CSR-ordered, coalesced
//   per layer (everything edge-indexed is sequential in CSR slot i):
//     P = h@Wtop (fp16 out)
//     fused: M = ea@Wbot; ti=sp(P[dstp]+M), tj=sp(P[srcp]+M); M<-tj (fp16);
//            a1 = sp(dot(ti,att_i)+dot(tj,att_j)); a1 stats via atomics
//     aggregate: per dst node, sequential walk [offs[n],offs[n+1]);
//            w=exp(sp(BN(a1))); aggn=(sum tj*w)/(sum w);
//            col stats -> 4-way banked cs (atomic-contention fix)
//     h = sp(BN(aggn))                    (conv_bias cancels in BN)
//   comp attention + seg-softmax over sorted batch + pool + fc
// Lessons pinned:
//  - NEVER pass min-waves to __launch_bounds__ (r6/r7: VGPR cap -> GB spills).
//  - r9: big reg-tiles (VGPR 144) killed occupancy -> keep 52-VGPR core.
//  - r11: 12.5k same-address atomics = ~250us queueing (agg 306us, all pipes
//    idle). Same-address atomic ~20ns: keep per-address count <= ~500.
//  - r11: per-layer scattered 8B writes cost ~66us/layer -> permute ONCE.
// ---------------------------------------------------------------------------

typedef unsigned short ushortt;

__device__ __forceinline__ float sp_f(float x) {
  return x > 20.0f ? x : __logf(1.0f + __expf(x));
}
__device__ __forceinline__ float h2f(ushortt u) {
  union { ushortt u; __half h; } c; c.u = u;
  return __half2float(c.h);
}
__device__ __forceinline__ ushortt f2h(float f) {
  union { __half h; ushortt u; } c; c.h = __float2half(f);
  return c.u;
}
__device__ __forceinline__ float4 h4_to_f4(ushort4 u) {
  return make_float4(h2f(u.x), h2f(u.y), h2f(u.z), h2f(u.w));
}

// Register-tiled GEMM: out[R,64] = act(in[rows?][K] @ W[K,64] (+ b))
// Block: 256 thr, tile 64 rows x 64 cols; thread: 4 rows x 4 cols.
// LDS tiles ALWAYS fp32. FP16IN: global `in` fp16, converted in staging.
// GATHER: staging reads source row rows[r] (one-time permutes).
// FUSE_A: epilogue gathers fp16 P[dstp[e]],P[srcp[e]], writes tj (fp16) to
//         out[e], a1[e], a1 sum/sumsq into stats[0..1]. All e-sequential.
template<int K, int ACT, int BIAS, int FUSE_A, int FP16IN, int GATHER,
         typename IT, typename OT>
__global__ __launch_bounds__(256) void k_gemm_rt(
    const IT* __restrict__ in, const float* __restrict__ W,
    const float* __restrict__ b, OT* __restrict__ out, int R,
    const int* __restrict__ rows, const ushortt* __restrict__ P,
    const int* __restrict__ srcp, const int* __restrict__ dstp,
    const float* __restrict__ catt, float* __restrict__ a1,
    float* __restrict__ stats)
{
  constexpr int KP = (K + 3) / 4 * 4;   // k padded to x4 (zero-filled)
  constexpr int LS = KP + 4;            // ins row stride (floats, 16B-aligned)
  __shared__ __align__(16) float ins[64 * LS];
  __shared__ __align__(16) float Ws[KP * 64];
  __shared__ float atts[128];
  __shared__ float ssum[4], ssq[4];

  const int tx = threadIdx.x;
  const int b0 = blockIdx.x * 64;

  for (int i = tx; i < KP * 64; i += 256) {
    const int k = i >> 6;
    Ws[i] = (k < K) ? W[i] : 0.0f;      // W row-major [K][64]; pad rows zero
  }
  if (FP16IN) {
    static_assert(!FP16IN || (K % 8 == 0), "fp16 staging needs K%8==0");
    for (int i = tx; i < 64 * (K / 8); i += 256) {
      const int row = i / (K / 8);
      const int k8 = i % (K / 8);
      long r = b0 + row; if (r >= R) r = R - 1;   // clamp: values unused
      if (GATHER) r = rows[r];
      const ushortt* sp = &((const ushortt*)in)[r * (long)K + k8 * 8];
      const ushort4 u0 = *(const ushort4*)sp;
      const ushort4 u1 = *(const ushort4*)(sp + 4);
      *(float4*)&ins[row * LS + k8 * 8]     = h4_to_f4(u0);
      *(float4*)&ins[row * LS + k8 * 8 + 4] = h4_to_f4(u1);
    }
  } else {
    for (int i = tx; i < 64 * (KP / 4); i += 256) {
      const int row = i / (KP / 4);
      const int k4 = i % (KP / 4);
      long r = b0 + row; if (r >= R) r = R - 1;   // clamp: values unused
      if (GATHER) r = rows[r];
      float4 v;
      if (K % 4 == 0) {
        v = *(const float4*)&((const float*)in)[r * (long)K + k4 * 4];
      } else {
        float t[4];
        #pragma unroll
        for (int j = 0; j < 4; ++j) {
          const int k = k4 * 4 + j;
          t[j] = (k < K) ? ((const float*)in)[r * (long)K + k] : 0.0f;
        }
        v = make_float4(t[0], t[1], t[2], t[3]);
      }
      *(float4*)&ins[row * LS + k4 * 4] = v;
    }
  }
  if (FUSE_A) { if (tx < 128) atts[tx] = catt[tx]; }
  __syncthreads();

  const int lr0 = ((tx >> 6) << 4) + (((tx >> 4) & 3) << 2);  // local row base
  const int c0 = (tx & 15) << 2;                               // col base
  float acc[4][4];
  #pragma unroll
  for (int i = 0; i < 4; ++i)
    #pragma unroll
    for (int j = 0; j < 4; ++j) acc[i][j] = 0.0f;

  #pragma unroll 4
  for (int k4 = 0; k4 < KP / 4; ++k4) {
    float4 w[4], a[4];
    #pragma unroll
    for (int kk = 0; kk < 4; ++kk)
      w[kk] = *(const float4*)&Ws[(k4 * 4 + kk) * 64 + c0];
    #pragma unroll
    for (int ri = 0; ri < 4; ++ri)
      a[ri] = *(const float4*)&ins[(lr0 + ri) * LS + k4 * 4];
    #pragma unroll
    for (int ri = 0; ri < 4; ++ri) {
      const float* av = (const float*)&a[ri];
      #pragma unroll
      for (int kk = 0; kk < 4; ++kk) {
        acc[ri][0] = fmaf(av[kk], w[kk].x, acc[ri][0]);
        acc[ri][1] = fmaf(av[kk], w[kk].y, acc[ri][1]);
        acc[ri][2] = fmaf(av[kk], w[kk].z, acc[ri][2]);
        acc[ri][3] = fmaf(av[kk], w[kk].w, acc[ri][3]);
      }
    }
  }

  if (!FUSE_A) {
    float4 bias = make_float4(0.f, 0.f, 0.f, 0.f);
    if (BIAS) bias = *(const float4*)&b[c0];
    #pragma unroll
    for (int ri = 0; ri < 4; ++ri) {
      const long r = b0 + lr0 + ri;
      if (r >= R) continue;
      float4 v;
      v.x = acc[ri][0] + bias.x; v.y = acc[ri][1] + bias.y;
      v.z = acc[ri][2] + bias.z; v.w = acc[ri][3] + bias.w;
      if (ACT == 1) {
        v.x = v.x >= 0.f ? v.x : 0.2f * v.x;  v.y = v.y >= 0.f ? v.y : 0.2f * v.y;
        v.z = v.z >= 0.f ? v.z : 0.2f * v.z;  v.w = v.w >= 0.f ? v.w : 0.2f * v.w;
      }
      if (sizeof(OT) == 4) {
        *(float4*)&out[r * 64 + c0] = v;
      } else {
        ushort4 u;
        u.x = f2h(v.x); u.y = f2h(v.y); u.z = f2h(v.z); u.w = f2h(v.w);
        *(ushort4*)&out[r * 64 + c0] = u;
      }
    }
  } else {
    // epilogue: ti/tj from fp16 P; tj -> out[e] (fp16), a1[e]; a1 stats
    float s1 = 0.f, s2 = 0.f;
    #pragma unroll
    for (int ri = 0; ri < 4; ++ri) {
      const long e = b0 + lr0 + ri;
      float part = 0.0f;
      if (e < R) {
        const int s = srcp[e];
        const int d = dstp[e];
        const float4 Pd = h4_to_f4(*(const ushort4*)&P[(long)d * 64 + c0]);
        const float4 Ps = h4_to_f4(*(const ushort4*)&P[(long)s * 64 + c0]);
        float tj[4];
        const float ti0 = sp_f(Pd.x + acc[ri][0]);
        const float ti1 = sp_f(Pd.y + acc[ri][1]);
        const float ti2 = sp_f(Pd.z + acc[ri][2]);
        const float ti3 = sp_f(Pd.w + acc[ri][3]);
        tj[0] = sp_f(Ps.x + acc[ri][0]);
        tj[1] = sp_f(Ps.y + acc[ri][1]);
        tj[2] = sp_f(Ps.z + acc[ri][2]);
        tj[3] = sp_f(Ps.w + acc[ri][3]);
        ushort4 u;
        u.x = f2h(tj[0]); u.y = f2h(tj[1]); u.z = f2h(tj[2]); u.w = f2h(tj[3]);
        *(ushort4*)&out[e * 64 + c0] = u;
        part = ti0 * atts[c0] + ti1 * atts[c0 + 1] + ti2 * atts[c0 + 2] + ti3 * atts[c0 + 3]
             + tj[0] * atts[64 + c0] + tj[1] * atts[64 + c0 + 1]
             + tj[2] * atts[64 + c0 + 2] + tj[3] * atts[64 + c0 + 3];
      }
      #pragma unroll
      for (int off = 8; off; off >>= 1) part += __shfl_xor(part, off);
      if ((tx & 15) == 0 && e < R) {
        const float v = sp_f(part);
        a1[e] = v;
        s1 += v; s2 += v * v;
      }
    }
    s1 += __shfl_xor(s1, 16); s2 += __shfl_xor(s2, 16);
    s1 += __shfl_xor(s1, 32); s2 += __shfl_xor(s2, 32);
    if ((tx & 63) == 0) { ssum[tx >> 6] = s1; ssq[tx >> 6] = s2; }
    __syncthreads();
    if (tx == 0) {
      atomicAdd(&stats[0], ssum[0] + ssum[1] + ssum[2] + ssum[3]);
      atomicAdd(&stats[1], ssq[0] + ssq[1] + ssq[2] + ssq[3]);
    }
  }
}

// ---------- CSR build (once per launch; graph static across layers) --------
__global__ __launch_bounds__(256) void k_count(
    const int* __restrict__ dst, int* __restrict__ counts, int E)
{
  for (int i = blockIdx.x * 256 + threadIdx.x; i < E; i += gridDim.x * 256)
    atomicAdd(&counts[dst[i]], 1);
}

// single-block exclusive scan: offs[0..N-1] = exclusive prefix, offs[N] = E
__global__ __launch_bounds__(1024) void k_scan(
    const int* __restrict__ counts, int* __restrict__ offs, int N)
{
  __shared__ int part[1024];
  const int t = threadIdx.x;
  const int chunk = (N + 1023) >> 10;
  const int s0 = t * chunk;
  int sum = 0;
  for (int i = 0; i < chunk; ++i) {
    const int idx = s0 + i;
    if (idx < N) sum += counts[idx];
  }
  part[t] = sum;
  __syncthreads();
  for (int off = 1; off < 1024; off <<= 1) {
    const int v = (t >= off) ? part[t - off] : 0;
    __syncthreads();
    part[t] += v;
    __syncthreads();
  }
  int base = (t == 0) ? 0 : part[t - 1];
  for (int i = 0; i < chunk; ++i) {
    const int idx = s0 + i;
    if (idx < N) { offs[idx] = base; base += counts[idx]; }
  }
  if (N - 1 >= s0 && N - 1 < s0 + chunk) offs[N] = base;
}

// eids[CSR slot] = original edge id
__global__ __launch_bounds__(256) void k_fill(
    const int* __restrict__ dst, const int* __restrict__ offs,
    int* __restrict__ cursors, int* __restrict__ eids, int E)
{
  for (int i = blockIdx.x * 256 + threadIdx.x; i < E; i += gridDim.x * 256) {
    const int d = dst[i];
    eids[offs[d] + atomicAdd(&cursors[d], 1)] = i;
  }
}

// srcp/dstp in CSR order
__global__ __launch_bounds__(256) void k_permidx(
    const int* __restrict__ eids, const int* __restrict__ eidx,
    int* __restrict__ srcp, int* __restrict__ dstp, int E)
{
  for (int i = blockIdx.x * 256 + threadIdx.x; i < E; i += gridDim.x * 256) {
    const int e = eids[i];
    srcp[i] = eidx[e];
    dstp[i] = eidx[(long)E + e];
  }
}

// ---------- aggregate: sequential CSR reads, banked col-stats ---------------
// one wave per dst node (stride): w = exp(sp(BN(a1p[i])));
// aggn[n] = (sum Mp[i]*w)/(sum w); col sum/sumsq -> cs bank (blockIdx&3).
__global__ __launch_bounds__(256) void k_aggregate(
    const int* __restrict__ offs, const float* __restrict__ a1p,
    const ushortt* __restrict__ Mp, const float* __restrict__ stats,
    float invE, float* __restrict__ aggn, float* __restrict__ cs, int N)
{
  const float mean = stats[0] * invE;
  const float var = stats[1] * invE - mean * mean;
  const float scl = rsqrtf(var + 1e-5f);
  const int t = threadIdx.x & 63;
  const int wid = threadIdx.x >> 6;
  float s = 0.f, s2 = 0.f;
  const long step = (long)gridDim.x * 4;
  for (long n = (long)blockIdx.x * 4 + wid; n < N; n += step) {
    const int o0 = offs[n];
    const int o1 = offs[n + 1];
    float av = 0.f, sew = 0.f;
    #pragma unroll 4
    for (int i = o0; i < o1; ++i) {
      const float w = __expf(sp_f((a1p[i] - mean) * scl));
      av = fmaf(h2f(Mp[(long)i * 64 + t]), w, av);
      sew += w;
    }
    const float v = (o1 > o0) ? av / sew : 0.0f;
    aggn[n * 64 + t] = v;
    s += v; s2 += v * v;
  }
  __shared__ float b1[256], b2[256];
  b1[threadIdx.x] = s; b2[threadIdx.x] = s2;
  __syncthreads();
  if (threadIdx.x < 64) {
    const int bank = (blockIdx.x & 3) * 128;
    atomicAdd(&cs[bank + t], b1[t] + b1[64 + t] + b1[128 + t] + b1[192 + t]);
    atomicAdd(&cs[bank + 64 + t], b2[t] + b2[64 + t] + b2[128 + t] + b2[192 + t]);
  }
}

// h = sp((aggn - mean_c) * rsqrt(var_c + eps)); cs has 4 banks of 128
__global__ __launch_bounds__(256) void k_hnew(
    const float* __restrict__ aggn, const float* __restrict__ cs,
    float invN, float* __restrict__ h, int N)
{
  const int c = threadIdx.x & 63;
  const int r = threadIdx.x >> 6;
  const float mean = (cs[c] + cs[128 + c] + cs[256 + c] + cs[384 + c]) * invN;
  const float sq = (cs[64 + c] + cs[192 + c] + cs[320 + c] + cs[448 + c]) * invN;
  const float scl = rsqrtf(sq - mean * mean + 1e-5f);
  for (long n = (long)blockIdx.x * 4 + r; n < N; n += (long)gridDim.x * 4)
    h[n * 64 + c] = sp_f((aggn[n * 64 + c] - mean) * scl);
}

// composition attention score a[n] = sp(concat(h,gf)@Wc + bc) @ attW + attb
__global__ __launch_bounds__(256) void k_comp(
    const float* __restrict__ h, const float* __restrict__ gf,
    const int* __restrict__ batch, const float* __restrict__ Wc,
    const float* __restrict__ bc, const float* __restrict__ aw,
    const float* __restrict__ ab, float* __restrict__ aN, int N)
{
  __shared__ float Wcs[167 * 32];
  __shared__ float aws[32];
  __shared__ float bcs[32];
  for (int i = threadIdx.x; i < 167 * 32; i += 256) Wcs[i] = Wc[i];
  if (threadIdx.x < 32) { aws[threadIdx.x] = aw[threadIdx.x]; bcs[threadIdx.x] = bc[threadIdx.x]; }
  __syncthreads();
  const int t = threadIdx.x & 63;
  const int wid = threadIdx.x >> 6;
  const int col = t & 31;
  const float ab0 = ab[0];
  const int step = gridDim.x * 4;
  for (int n = blockIdx.x * 4 + wid; n < N; n += step) {
    const int g = batch[n];
    const float hq = h[(long)n * 64 + t];
    const float g1 = gf[(long)g * 103 + t];
    const float g2 = (t < 39) ? gf[(long)g * 103 + 64 + t] : 0.f;
    float acc = bcs[col];
    #pragma unroll 8
    for (int k = 0; k < 64; ++k) acc = fmaf(__shfl(hq, k), Wcs[k * 32 + col], acc);
    #pragma unroll 8
    for (int k = 0; k < 64; ++k) acc = fmaf(__shfl(g1, k), Wcs[(64 + k) * 32 + col], acc);
    #pragma unroll
    for (int k = 0; k < 39; ++k) acc = fmaf(__shfl(g2, k), Wcs[(128 + k) * 32 + col], acc);
    float val = sp_f(acc) * aws[col];
    #pragma unroll
    for (int off = 16; off; off >>= 1) val += __shfl_xor(val, off);
    if (t == 0) aN[n] = val + ab0;
  }
}

// one 64-thread block per graph: seg-softmax over sorted batch + pool + fc
__global__ __launch_bounds__(64) void k_pool(
    const float* __restrict__ h, const float* __restrict__ aN,
    const int* __restrict__ batch, const float* __restrict__ fcW,
    const float* __restrict__ fcb, float* __restrict__ out, int N, int G)
{
  const int g = blockIdx.x;
  const int t = threadIdx.x;
  int lo = 0, hi = N;
  while (lo < hi) { int mid = (lo + hi) >> 1; if (batch[mid] < g) lo = mid + 1; else hi = mid; }
  const int s = lo;
  hi = N;
  while (lo < hi) { int mid = (lo + hi) >> 1; if (batch[mid] < g + 1) lo = mid + 1; else hi = mid; }
  const int e2 = lo;
  if (s >= e2) { if (t == 0) out[g] = fcb[0]; return; }
  float mx = -1e30f;
  for (int i = s + t; i < e2; i += 64) mx = fmaxf(mx, aN[i]);
  #pragma unroll
  for (int off = 32; off; off >>= 1) mx = fmaxf(mx, __shfl_xor(mx, off));
  float se = 0.f;
  for (int i = s + t; i < e2; i += 64) se += __expf(aN[i] - mx);
  #pragma unroll
  for (int off = 32; off; off >>= 1) se += __shfl_xor(se, off);
  float acc = 0.f;
  for (int n = s; n < e2; ++n) {
    const float w = __expf(aN[n] - mx);
    acc = fmaf(h[(long)n * 64 + t], w, acc);
  }
  float part = (acc / se) * fcW[t];
  #pragma unroll
  for (int off = 32; off; off >>= 1) part += __shfl_xor(part, off);
  if (t == 0) out[g] = part + fcb[0];
}

extern "C" void kernel_launch(void* const* d_in, const int* in_sizes, int n_in,
                              void* d_out, int out_size, void* d_ws, size_t ws_size,
                              hipStream_t stream)
{
  const float* x     = (const float*)d_in[0];
  const int*   eidx  = (const int*)  d_in[1];
  const float* eattr = (const float*)d_in[2];
  const int*   batch = (const int*)  d_in[3];
  const float* gfeat = (const float*)d_in[4];
  const float* embnW = (const float*)d_in[5];
  const float* embnb = (const float*)d_in[6];
  const float* embeW = (const float*)d_in[7];
  const float* embeb = (const float*)d_in[8];
  const float* convW = (const float*)d_in[9];
  const float* convA = (const float*)d_in[10];
  // d_in[11] = conv_bias: cancels exactly in training-mode BatchNorm
  const float* compW = (const float*)d_in[12];
  const float* compb = (const float*)d_in[13];
  const float* attW  = (const float*)d_in[14];
  const float* attb  = (const float*)d_in[15];
  const float* fcW   = (const float*)d_in[16];
  const float* fcb   = (const float*)d_in[17];
  float* out = (float*)d_out;

  const int N = in_sizes[0] / 92;
  const int E = in_sizes[1] / 2;
  const int G = in_sizes[4] / 103;

  // workspace (~140 MB): fp32 node buffers, CSR ints, fp16 edge streams + P
  char* pw = (char*)d_ws;
  float* h     = (float*)pw;  pw += (size_t)N * 64 * 4;
  float* aggn  = (float*)pw;  pw += (size_t)N * 64 * 4;
  float* aE    = (float*)pw;  pw += (size_t)E * 4;        // a1 (CSR-ordered)
  float* stats = (float*)pw;  pw += 1024 * 4;             // [0..1] BN-E; cs@64 (4x128)
  float* aN    = (float*)pw;  pw += (size_t)N * 4;
  int* counts  = (int*)pw;    pw += (size_t)N * 4;        // counts+cursors: one memset
  int* cursors = (int*)pw;    pw += (size_t)N * 4;
  int* offs    = (int*)pw;    pw += ((size_t)N + 1) * 4;
  int* eids    = (int*)pw;    pw += (size_t)E * 4;
  int* srcp    = (int*)pw;    pw += (size_t)E * 4;
  int* dstp    = (int*)pw;    pw += (size_t)E * 4;
  pw = (char*)(((size_t)pw + 63) & ~(size_t)63);
  ushortt* Pp  = (ushortt*)pw; pw += (size_t)N * 64 * 2;  // P fp16
  ushortt* ea  = (ushortt*)pw; pw += (size_t)E * 64 * 2;  // fp16, CSR-ordered
  ushortt* M   = (ushortt*)pw;                            // fp16 tj, CSR-ordered

  const int gE64 = (E + 63) / 64;
  const int gN64 = (N + 63) / 64;

  // CSR build (dst = eidx[E..2E)), then index permutes
  hipMemsetAsync(counts, 0, 2 * (size_t)N * sizeof(int), stream);
  k_count<<<2048, 256, 0, stream>>>(eidx + E, counts, E);
  k_scan<<<1, 1024, 0, stream>>>(counts, offs, N);
  k_fill<<<2048, 256, 0, stream>>>(eidx + E, offs, cursors, eids, E);
  k_permidx<<<2048, 256, 0, stream>>>(eids, eidx, srcp, dstp, E);

  k_gemm_rt<92, 0, 1, 0, 0, 0, float, float><<<gN64, 256, 0, stream>>>(
      x, embnW, embnb, h, N, nullptr, nullptr, nullptr, nullptr, nullptr,
      nullptr, nullptr);
  // ea-embed: gather eattr rows by eids -> ea written CSR-ordered, coalesced
  k_gemm_rt<41, 1, 1, 0, 0, 1, float, ushortt><<<gE64, 256, 0, stream>>>(
      eattr, embeW, embeb, ea, E, eids, nullptr, nullptr, nullptr, nullptr,
      nullptr, nullptr);

  for (int l = 0; l < 3; ++l) {
    const float* Wl = convW + (size_t)l * 128 * 64;
    const float* Al = convA + (size_t)l * 128;
    hipMemsetAsync(stats, 0, 1024 * sizeof(float), stream);
    k_gemm_rt<64, 0, 0, 0, 0, 0, float, ushortt><<<gN64, 256, 0, stream>>>(
        h, Wl, nullptr, Pp, N, nullptr, nullptr, nullptr, nullptr, nullptr,
        nullptr, nullptr);
    k_gemm_rt<64, 0, 0, 1, 1, 0, ushortt, ushortt><<<gE64, 256, 0, stream>>>(
        ea, Wl + 64 * 64, nullptr, M, E, nullptr, Pp, srcp, dstp, Al, aE, stats);
    k_aggregate<<<2048, 256, 0, stream>>>(offs, aE, M, stats,
                                          1.0f / (float)E, aggn, stats + 64, N);
    k_hnew<<<2048, 256, 0, stream>>>(aggn, stats + 64, 1.0f / (float)N, h, N);
  }

  k_comp<<<gN64, 256, 0, stream>>>(h, gfeat, batch, compW, compb, attW, attb, aN, N);
  k_pool<<<G, 64, 0, stream>>>(h, aN, batch, fcW, fcb, out, N, G);

  (void)n_in; (void)out_size; (void)ws_size;
}

// Round 13
// 1057.743 us; speedup vs baseline: 1.7839x; 1.0118x over previous
//
#include <hip/hip_runtime.h>
#include <hip/hip_bf16.h>
#include <hip/hip_fp16.h>
#include <math.h>

// ---------------------------------------------------------------------------
// GATGNN forward. fp32 math; edge streams fp16, ALL CSR-ordered (~140 MB ws).
//   CSR build first: eids (CSR slot -> edge), srcp/dstp (CSR-ordered endpoints)
//   h = x@Wn + bn
//   ea = leaky_relu(eattr@We + be)   [gathered by eids -> CSR-ordered fp16]
//   per layer (edge streams sequential in CSR slot):
//     P = h@Wtop (fp16 out)
//     fused: M = ea@Wbot  [fp16 LDS + v_dot2_f32_f16, fp32 acc, ROLLED k8
//            loop to keep VGPR ~50 (r9 lesson)]; ti=sp(P[dstp]+M),
//            tj=sp(P[srcp]+M); M<-tj (fp16); a1=sp(dot attention); a1 stats
//     aggregate: per dst node sequential walk; w=exp(sp(BN(a1)));
//            aggn=(sum tj*w)/(sum w); col stats -> 4-way banked cs
//     h = sp(BN(aggn))                    (conv_bias cancels in BN)
//   comp attention + seg-softmax over sorted batch + pool + fc
// Lessons pinned:
//  - NEVER pass min-waves to __launch_bounds__ (r6/r7: VGPR cap -> GB spills).
//  - r9: FULL-UNROLL k8 loop hoisted reg tiles -> VGPR 144, occupancy 10%.
//    Fix: #pragma unroll 1 on k8; load wv once, av per-ri, consume at once.
//  - r11: >500 same-address atomics queue (~20ns each) -> banked cs.
//  - r12 PMC: fp32-LDS MAC loop = CU LDS-pipe-bound (62us floor, VALU 37%).
//    dot2 halves LDS reads AND VALU ops.
// ---------------------------------------------------------------------------

typedef unsigned short ushortt;
typedef _Float16 half2v __attribute__((ext_vector_type(2)));

__device__ __forceinline__ float sp_f(float x) {
  return x > 20.0f ? x : __logf(1.0f + __expf(x));
}
__device__ __forceinline__ float h2f(ushortt u) {
  union { ushortt u; __half h; } c; c.u = u;
  return __half2float(c.h);
}
__device__ __forceinline__ ushortt f2h(float f) {
  union { __half h; ushortt u; } c; c.h = __float2half(f);
  return c.u;
}
__device__ __forceinline__ float4 h4_to_f4(ushort4 u) {
  return make_float4(h2f(u.x), h2f(u.y), h2f(u.z), h2f(u.w));
}
__device__ __forceinline__ unsigned pack2h(float a, float b) {
  union { _Float16 h[2]; unsigned u; } c;
  c.h[0] = (_Float16)a; c.h[1] = (_Float16)b;
  return c.u;
}
__device__ __forceinline__ float fdot2f(unsigned a, unsigned b, float c) {
  return __builtin_amdgcn_fdot2(__builtin_bit_cast(half2v, a),
                                __builtin_bit_cast(half2v, b), c, false);
}

// Register-tiled GEMM: out[R,64] = act(in[rows?][K] @ W[K,64] (+ b))
// Block: 256 thr, tile 64 rows x 64 cols; thread: 4 rows x 4 cols.
// LH16: in fp16; A-tile fp16 raw-copied to LDS; W-tile k-pair-packed half2;
//       MACs via v_dot2_f32_f16 with ROLLED k8 loop (VGPR control).
// else: fp32 LDS tiles (52-VGPR core). GATHER: staging reads rows[r].
// FUSE_A: epilogue gathers fp16 P[dstp[e]],P[srcp[e]], writes tj (fp16) to
//         out[e], a1[e], a1 sum/sumsq into stats[0..1]. All e-sequential.
template<int K, int ACT, int BIAS, int FUSE_A, int LH16, int GATHER,
         typename IT, typename OT>
__global__ __launch_bounds__(256) void k_gemm_rt(
    const IT* __restrict__ in, const float* __restrict__ W,
    const float* __restrict__ b, OT* __restrict__ out, int R,
    const int* __restrict__ rows, const ushortt* __restrict__ P,
    const int* __restrict__ srcp, const int* __restrict__ dstp,
    const float* __restrict__ catt, float* __restrict__ a1,
    float* __restrict__ stats)
{
  constexpr int KP  = (K + 3) / 4 * 4;       // fp32 path: k padded to x4
  constexpr int LSf = KP + 4;                // fp32 ins stride (floats)
  constexpr int LSb = K + 8;                 // fp16 ins stride (shorts)
  constexpr size_t INS_B = LH16 ? (size_t)64 * LSb * 2 : (size_t)64 * LSf * 4;
  constexpr size_t WS_B  = LH16 ? (size_t)(K / 2) * 64 * 4 : (size_t)KP * 64 * 4;
  __shared__ __align__(16) unsigned char smem[INS_B + WS_B];
  __shared__ float atts[128];
  __shared__ float ssum[4], ssq[4];
  ushortt*  insb = (ushortt*)smem;
  unsigned* Wp   = (unsigned*)(smem + INS_B);   // LH16: [K/2][64] half2-packed
  float*    insf = (float*)smem;
  float*    Wsf  = (float*)(smem + INS_B);

  const int tx = threadIdx.x;
  const int b0 = blockIdx.x * 64;

  if (LH16) {
    static_assert(!LH16 || (K % 8 == 0), "fp16 path needs K%8==0");
    // W packed: Wp[k2*64+c] = half2(W[2k2][c], W[2k2+1][c])
    for (int i = tx; i < (K / 2) * 64; i += 256) {
      const int k2 = i >> 6;
      const int c = i & 63;
      Wp[i] = pack2h(W[(2 * k2) * 64 + c], W[(2 * k2 + 1) * 64 + c]);
    }
    for (int i = tx; i < 64 * (K / 8); i += 256) {
      const int row = i / (K / 8);
      const int k8 = i % (K / 8);
      long r = b0 + row; if (r >= R) r = R - 1;   // clamp: values unused
      if (GATHER) r = rows[r];
      *(uint4*)&insb[row * LSb + k8 * 8] =
          *(const uint4*)&((const ushortt*)in)[r * (long)K + k8 * 8];
    }
  } else {
    for (int i = tx; i < KP * 64; i += 256) {
      const int k = i >> 6;
      Wsf[i] = (k < K) ? W[i] : 0.0f;
    }
    for (int i = tx; i < 64 * (KP / 4); i += 256) {
      const int row = i / (KP / 4);
      const int k4 = i % (KP / 4);
      long r = b0 + row; if (r >= R) r = R - 1;   // clamp: values unused
      if (GATHER) r = rows[r];
      float4 v;
      if (K % 4 == 0) {
        v = *(const float4*)&((const float*)in)[r * (long)K + k4 * 4];
      } else {
        float t[4];
        #pragma unroll
        for (int j = 0; j < 4; ++j) {
          const int k = k4 * 4 + j;
          t[j] = (k < K) ? ((const float*)in)[r * (long)K + k] : 0.0f;
        }
        v = make_float4(t[0], t[1], t[2], t[3]);
      }
      *(float4*)&insf[row * LSf + k4 * 4] = v;
    }
  }
  if (FUSE_A) { if (tx < 128) atts[tx] = catt[tx]; }
  __syncthreads();

  const int lr0 = ((tx >> 6) << 4) + (((tx >> 4) & 3) << 2);  // local row base
  const int c0 = (tx & 15) << 2;                               // col base
  float acc[4][4];
  #pragma unroll
  for (int i = 0; i < 4; ++i)
    #pragma unroll
    for (int j = 0; j < 4; ++j) acc[i][j] = 0.0f;

  if (LH16) {
    // ROLLED k8 loop: wv loaded once/iter, av per-ri, consumed immediately.
    #pragma unroll 1
    for (int k8 = 0; k8 < K / 8; ++k8) {
      const uint4 wv0 = *(const uint4*)&Wp[(k8 * 4 + 0) * 64 + c0];
      const uint4 wv1 = *(const uint4*)&Wp[(k8 * 4 + 1) * 64 + c0];
      const uint4 wv2 = *(const uint4*)&Wp[(k8 * 4 + 2) * 64 + c0];
      const uint4 wv3 = *(const uint4*)&Wp[(k8 * 4 + 3) * 64 + c0];
      #pragma unroll
      for (int ri = 0; ri < 4; ++ri) {
        const uint4 av = *(const uint4*)&insb[(lr0 + ri) * LSb + k8 * 8];
        acc[ri][0] = fdot2f(av.x, wv0.x, acc[ri][0]);
        acc[ri][1] = fdot2f(av.x, wv0.y, acc[ri][1]);
        acc[ri][2] = fdot2f(av.x, wv0.z, acc[ri][2]);
        acc[ri][3] = fdot2f(av.x, wv0.w, acc[ri][3]);
        acc[ri][0] = fdot2f(av.y, wv1.x, acc[ri][0]);
        acc[ri][1] = fdot2f(av.y, wv1.y, acc[ri][1]);
        acc[ri][2] = fdot2f(av.y, wv1.z, acc[ri][2]);
        acc[ri][3] = fdot2f(av.y, wv1.w, acc[ri][3]);
        acc[ri][0] = fdot2f(av.z, wv2.x, acc[ri][0]);
        acc[ri][1] = fdot2f(av.z, wv2.y, acc[ri][1]);
        acc[ri][2] = fdot2f(av.z, wv2.z, acc[ri][2]);
        acc[ri][3] = fdot2f(av.z, wv2.w, acc[ri][3]);
        acc[ri][0] = fdot2f(av.w, wv3.x, acc[ri][0]);
        acc[ri][1] = fdot2f(av.w, wv3.y, acc[ri][1]);
        acc[ri][2] = fdot2f(av.w, wv3.z, acc[ri][2]);
        acc[ri][3] = fdot2f(av.w, wv3.w, acc[ri][3]);
      }
    }
  } else {
    #pragma unroll 4
    for (int k4 = 0; k4 < KP / 4; ++k4) {
      float4 w[4], a[4];
      #pragma unroll
      for (int kk = 0; kk < 4; ++kk)
        w[kk] = *(const float4*)&Wsf[(k4 * 4 + kk) * 64 + c0];
      #pragma unroll
      for (int ri = 0; ri < 4; ++ri)
        a[ri] = *(const float4*)&insf[(lr0 + ri) * LSf + k4 * 4];
      #pragma unroll
      for (int ri = 0; ri < 4; ++ri) {
        const float* av = (const float*)&a[ri];
        #pragma unroll
        for (int kk = 0; kk < 4; ++kk) {
          acc[ri][0] = fmaf(av[kk], w[kk].x, acc[ri][0]);
          acc[ri][1] = fmaf(av[kk], w[kk].y, acc[ri][1]);
          acc[ri][2] = fmaf(av[kk], w[kk].z, acc[ri][2]);
          acc[ri][3] = fmaf(av[kk], w[kk].w, acc[ri][3]);
        }
      }
    }
  }

  if (!FUSE_A) {
    float4 bias = make_float4(0.f, 0.f, 0.f, 0.f);
    if (BIAS) bias = *(const float4*)&b[c0];
    #pragma unroll
    for (int ri = 0; ri < 4; ++ri) {
      const long r = b0 + lr0 + ri;
      if (r >= R) continue;
      float4 v;
      v.x = acc[ri][0] + bias.x; v.y = acc[ri][1] + bias.y;
      v.z = acc[ri][2] + bias.z; v.w = acc[ri][3] + bias.w;
      if (ACT == 1) {
        v.x = v.x >= 0.f ? v.x : 0.2f * v.x;  v.y = v.y >= 0.f ? v.y : 0.2f * v.y;
        v.z = v.z >= 0.f ? v.z : 0.2f * v.z;  v.w = v.w >= 0.f ? v.w : 0.2f * v.w;
      }
      if (sizeof(OT) == 4) {
        *(float4*)&out[r * 64 + c0] = v;
      } else {
        ushort4 u;
        u.x = f2h(v.x); u.y = f2h(v.y); u.z = f2h(v.z); u.w = f2h(v.w);
        *(ushort4*)&out[r * 64 + c0] = u;
      }
    }
  } else {
    // epilogue: ti/tj from fp16 P; tj -> out[e] (fp16), a1[e]; a1 stats
    float s1 = 0.f, s2 = 0.f;
    #pragma unroll
    for (int ri = 0; ri < 4; ++ri) {
      const long e = b0 + lr0 + ri;
      float part = 0.0f;
      if (e < R) {
        const int s = srcp[e];
        const int d = dstp[e];
        const float4 Pd = h4_to_f4(*(const ushort4*)&P[(long)d * 64 + c0]);
        const float4 Ps = h4_to_f4(*(const ushort4*)&P[(long)s * 64 + c0]);
        float tj[4];
        const float ti0 = sp_f(Pd.x + acc[ri][0]);
        const float ti1 = sp_f(Pd.y + acc[ri][1]);
        const float ti2 = sp_f(Pd.z + acc[ri][2]);
        const float ti3 = sp_f(Pd.w + acc[ri][3]);
        tj[0] = sp_f(Ps.x + acc[ri][0]);
        tj[1] = sp_f(Ps.y + acc[ri][1]);
        tj[2] = sp_f(Ps.z + acc[ri][2]);
        tj[3] = sp_f(Ps.w + acc[ri][3]);
        ushort4 u;
        u.x = f2h(tj[0]); u.y = f2h(tj[1]); u.z = f2h(tj[2]); u.w = f2h(tj[3]);
        *(ushort4*)&out[e * 64 + c0] = u;
        part = ti0 * atts[c0] + ti1 * atts[c0 + 1] + ti2 * atts[c0 + 2] + ti3 * atts[c0 + 3]
             + tj[0] * atts[64 + c0] + tj[1] * atts[64 + c0 + 1]
             + tj[2] * atts[64 + c0 + 2] + tj[3] * atts[64 + c0 + 3];
      }
      #pragma unroll
      for (int off = 8; off; off >>= 1) part += __shfl_xor(part, off);
      if ((tx & 15) == 0 && e < R) {
        const float v = sp_f(part);
        a1[e] = v;
        s1 += v; s2 += v * v;
      }
    }
    s1 += __shfl_xor(s1, 16); s2 += __shfl_xor(s2, 16);
    s1 += __shfl_xor(s1, 32); s2 += __shfl_xor(s2, 32);
    if ((tx & 63) == 0) { ssum[tx >> 6] = s1; ssq[tx >> 6] = s2; }
    __syncthreads();
    if (tx == 0) {
      atomicAdd(&stats[0], ssum[0] + ssum[1] + ssum[2] + ssum[3]);
      atomicAdd(&stats[1], ssq[0] + ssq[1] + ssq[2] + ssq[3]);
    }
  }
}

// ---------- CSR build (once per launch; graph static across layers) --------
__global__ __launch_bounds__(256) void k_count(
    const int* __restrict__ dst, int* __restrict__ counts, int E)
{
  for (int i = blockIdx.x * 256 + threadIdx.x; i < E; i += gridDim.x * 256)
    atomicAdd(&counts[dst[i]], 1);
}

// single-block exclusive scan: offs[0..N-1] = exclusive prefix, offs[N] = E
__global__ __launch_bounds__(1024) void k_scan(
    const int* __restrict__ counts, int* __restrict__ offs, int N)
{
  __shared__ int part[1024];
  const int t = threadIdx.x;
  const int chunk = (N + 1023) >> 10;
  const int s0 = t * chunk;
  int sum = 0;
  for (int i = 0; i < chunk; ++i) {
    const int idx = s0 + i;
    if (idx < N) sum += counts[idx];
  }
  part[t] = sum;
  __syncthreads();
  for (int off = 1; off < 1024; off <<= 1) {
    const int v = (t >= off) ? part[t - off] : 0;
    __syncthreads();
    part[t] += v;
    __syncthreads();
  }
  int base = (t == 0) ? 0 : part[t - 1];
  for (int i = 0; i < chunk; ++i) {
    const int idx = s0 + i;
    if (idx < N) { offs[idx] = base; base += counts[idx]; }
  }
  if (N - 1 >= s0 && N - 1 < s0 + chunk) offs[N] = base;
}

// eids[CSR slot] = original edge id
__global__ __launch_bounds__(256) void k_fill(
    const int* __restrict__ dst, const int* __restrict__ offs,
    int* __restrict__ cursors, int* __restrict__ eids, int E)
{
  for (int i = blockIdx.x * 256 + threadIdx.x; i < E; i += gridDim.x * 256) {
    const int d = dst[i];
    eids[offs[d] + atomicAdd(&cursors[d], 1)] = i;
  }
}

// srcp/dstp in CSR order
__global__ __launch_bounds__(256) void k_permidx(
    const int* __restrict__ eids, const int* __restrict__ eidx,
    int* __restrict__ srcp, int* __restrict__ dstp, int E)
{
  for (int i = blockIdx.x * 256 + threadIdx.x; i < E; i += gridDim.x * 256) {
    const int e = eids[i];
    srcp[i] = eidx[e];
    dstp[i] = eidx[(long)E + e];
  }
}

// ---------- aggregate: sequential CSR reads, banked col-stats ---------------
__global__ __launch_bounds__(256) void k_aggregate(
    const int* __restrict__ offs, const float* __restrict__ a1p,
    const ushortt* __restrict__ Mp, const float* __restrict__ stats,
    float invE, float* __restrict__ aggn, float* __restrict__ cs, int N)
{
  const float mean = stats[0] * invE;
  const float var = stats[1] * invE - mean * mean;
  const float scl = rsqrtf(var + 1e-5f);
  const int t = threadIdx.x & 63;
  const int wid = threadIdx.x >> 6;
  float s = 0.f, s2 = 0.f;
  const long step = (long)gridDim.x * 4;
  for (long n = (long)blockIdx.x * 4 + wid; n < N; n += step) {
    const int o0 = offs[n];
    const int o1 = offs[n + 1];
    float av = 0.f, sew = 0.f;
    #pragma unroll 4
    for (int i = o0; i < o1; ++i) {
      const float w = __expf(sp_f((a1p[i] - mean) * scl));
      av = fmaf(h2f(Mp[(long)i * 64 + t]), w, av);
      sew += w;
    }
    const float v = (o1 > o0) ? av / sew : 0.0f;
    aggn[n * 64 + t] = v;
    s += v; s2 += v * v;
  }
  __shared__ float b1[256], b2[256];
  b1[threadIdx.x] = s; b2[threadIdx.x] = s2;
  __syncthreads();
  if (threadIdx.x < 64) {
    const int bank = (blockIdx.x & 3) * 128;
    atomicAdd(&cs[bank + t], b1[t] + b1[64 + t] + b1[128 + t] + b1[192 + t]);
    atomicAdd(&cs[bank + 64 + t], b2[t] + b2[64 + t] + b2[128 + t] + b2[192 + t]);
  }
}

// h = sp((aggn - mean_c) * rsqrt(var_c + eps)); cs has 4 banks of 128
__global__ __launch_bounds__(256) void k_hnew(
    const float* __restrict__ aggn, const float* __restrict__ cs,
    float invN, float* __restrict__ h, int N)
{
  const int c = threadIdx.x & 63;
  const int r = threadIdx.x >> 6;
  const float mean = (cs[c] + cs[128 + c] + cs[256 + c] + cs[384 + c]) * invN;
  const float sq = (cs[64 + c] + cs[192 + c] + cs[320 + c] + cs[448 + c]) * invN;
  const float scl = rsqrtf(sq - mean * mean + 1e-5f);
  for (long n = (long)blockIdx.x * 4 + r; n < N; n += (long)gridDim.x * 4)
    h[n * 64 + c] = sp_f((aggn[n * 64 + c] - mean) * scl);
}

// composition attention score a[n] = sp(concat(h,gf)@Wc + bc) @ attW + attb
__global__ __launch_bounds__(256) void k_comp(
    const float* __restrict__ h, const float* __restrict__ gf,
    const int* __restrict__ batch, const float* __restrict__ Wc,
    const float* __restrict__ bc, const float* __restrict__ aw,
    const float* __restrict__ ab, float* __restrict__ aN, int N)
{
  __shared__ float Wcs[167 * 32];
  __shared__ float aws[32];
  __shared__ float bcs[32];
  for (int i = threadIdx.x; i < 167 * 32; i += 256) Wcs[i] = Wc[i];
  if (threadIdx.x < 32) { aws[threadIdx.x] = aw[threadIdx.x]; bcs[threadIdx.x] = bc[threadIdx.x]; }
  __syncthreads();
  const int t = threadIdx.x & 63;
  const int wid = threadIdx.x >> 6;
  const int col = t & 31;
  const float ab0 = ab[0];
  const int step = gridDim.x * 4;
  for (int n = blockIdx.x * 4 + wid; n < N; n += step) {
    const int g = batch[n];
    const float hq = h[(long)n * 64 + t];
    const float g1 = gf[(long)g * 103 + t];
    const float g2 = (t < 39) ? gf[(long)g * 103 + 64 + t] : 0.f;
    float acc = bcs[col];
    #pragma unroll 8
    for (int k = 0; k < 64; ++k) acc = fmaf(__shfl(hq, k), Wcs[k * 32 + col], acc);
    #pragma unroll 8
    for (int k = 0; k < 64; ++k) acc = fmaf(__shfl(g1, k), Wcs[(64 + k) * 32 + col], acc);
    #pragma unroll
    for (int k = 0; k < 39; ++k) acc = fmaf(__shfl(g2, k), Wcs[(128 + k) * 32 + col], acc);
    float val = sp_f(acc) * aws[col];
    #pragma unroll
    for (int off = 16; off; off >>= 1) val += __shfl_xor(val, off);
    if (t == 0) aN[n] = val + ab0;
  }
}

// one 64-thread block per graph: seg-softmax over sorted batch + pool + fc
__global__ __launch_bounds__(64) void k_pool(
    const float* __restrict__ h, const float* __restrict__ aN,
    const int* __restrict__ batch, const float* __restrict__ fcW,
    const float* __restrict__ fcb, float* __restrict__ out, int N, int G)
{
  const int g = blockIdx.x;
  const int t = threadIdx.x;
  int lo = 0, hi = N;
  while (lo < hi) { int mid = (lo + hi) >> 1; if (batch[mid] < g) lo = mid + 1; else hi = mid; }
  const int s = lo;
  hi = N;
  while (lo < hi) { int mid = (lo + hi) >> 1; if (batch[mid] < g + 1) lo = mid + 1; else hi = mid; }
  const int e2 = lo;
  if (s >= e2) { if (t == 0) out[g] = fcb[0]; return; }
  float mx = -1e30f;
  for (int i = s + t; i < e2; i += 64) mx = fmaxf(mx, aN[i]);
  #pragma unroll
  for (int off = 32; off; off >>= 1) mx = fmaxf(mx, __shfl_xor(mx, off));
  float se = 0.f;
  for (int i = s + t; i < e2; i += 64) se += __expf(aN[i] - mx);
  #pragma unroll
  for (int off = 32; off; off >>= 1) se += __shfl_xor(se, off);
  float acc = 0.f;
  for (int n = s; n < e2; ++n) {
    const float w = __expf(aN[n] - mx);
    acc = fmaf(h[(long)n * 64 + t], w, acc);
  }
  float part = (acc / se) * fcW[t];
  #pragma unroll
  for (int off = 32; off; off >>= 1) part += __shfl_xor(part, off);
  if (t == 0) out[g] = part + fcb[0];
}

extern "C" void kernel_launch(void* const* d_in, const int* in_sizes, int n_in,
                              void* d_out, int out_size, void* d_ws, size_t ws_size,
                              hipStream_t stream)
{
  const float* x     = (const float*)d_in[0];
  const int*   eidx  = (const int*)  d_in[1];
  const float* eattr = (const float*)d_in[2];
  const int*   batch = (const int*)  d_in[3];
  const float* gfeat = (const float*)d_in[4];
  const float* embnW = (const float*)d_in[5];
  const float* embnb = (const float*)d_in[6];
  const float* embeW = (const float*)d_in[7];
  const float* embeb = (const float*)d_in[8];
  const float* convW = (const float*)d_in[9];
  const float* convA = (const float*)d_in[10];
  // d_in[11] = conv_bias: cancels exactly in training-mode BatchNorm
  const float* compW = (const float*)d_in[12];
  const float* compb = (const float*)d_in[13];
  const float* attW  = (const float*)d_in[14];
  const float* attb  = (const float*)d_in[15];
  const float* fcW   = (const float*)d_in[16];
  const float* fcb   = (const float*)d_in[17];
  float* out = (float*)d_out;

  const int N = in_sizes[0] / 92;
  const int E = in_sizes[1] / 2;
  const int G = in_sizes[4] / 103;

  // workspace (~140 MB): fp32 node buffers, CSR ints, fp16 edge streams + P
  char* pw = (char*)d_ws;
  float* h     = (float*)pw;  pw += (size_t)N * 64 * 4;
  float* aggn  = (float*)pw;  pw += (size_t)N * 64 * 4;
  float* aE    = (float*)pw;  pw += (size_t)E * 4;        // a1 (CSR-ordered)
  float* stats = (float*)pw;  pw += 1024 * 4;             // [0..1] BN-E; cs@64 (4x128)
  float* aN    = (float*)pw;  pw += (size_t)N * 4;
  int* counts  = (int*)pw;    pw += (size_t)N * 4;        // counts+cursors: one memset
  int* cursors = (int*)pw;    pw += (size_t)N * 4;
  int* offs    = (int*)pw;    pw += ((size_t)N + 1) * 4;
  int* eids    = (int*)pw;    pw += (size_t)E * 4;
  int* srcp    = (int*)pw;    pw += (size_t)E * 4;
  int* dstp    = (int*)pw;    pw += (size_t)E * 4;
  pw = (char*)(((size_t)pw + 63) & ~(size_t)63);
  ushortt* Pp  = (ushortt*)pw; pw += (size_t)N * 64 * 2;  // P fp16
  ushortt* ea  = (ushortt*)pw; pw += (size_t)E * 64 * 2;  // fp16, CSR-ordered
  ushortt* M   = (ushortt*)pw;                            // fp16 tj, CSR-ordered

  const int gE64 = (E + 63) / 64;
  const int gN64 = (N + 63) / 64;

  // CSR build (dst = eidx[E..2E)), then index permutes
  hipMemsetAsync(counts, 0, 2 * (size_t)N * sizeof(int), stream);
  k_count<<<2048, 256, 0, stream>>>(eidx + E, counts, E);
  k_scan<<<1, 1024, 0, stream>>>(counts, offs, N);
  k_fill<<<2048, 256, 0, stream>>>(eidx + E, offs, cursors, eids, E);
  k_permidx<<<2048, 256, 0, stream>>>(eids, eidx, srcp, dstp, E);

  k_gemm_rt<92, 0, 1, 0, 0, 0, float, float><<<gN64, 256, 0, stream>>>(
      x, embnW, embnb, h, N, nullptr, nullptr, nullptr, nullptr, nullptr,
      nullptr, nullptr);
  // ea-embed: gather eattr rows by eids -> ea written CSR-ordered, coalesced
  k_gemm_rt<41, 1, 1, 0, 0, 1, float, ushortt><<<gE64, 256, 0, stream>>>(
      eattr, embeW, embeb, ea, E, eids, nullptr, nullptr, nullptr, nullptr,
      nullptr, nullptr);

  for (int l = 0; l < 3; ++l) {
    const float* Wl = convW + (size_t)l * 128 * 64;
    const float* Al = convA + (size_t)l * 128;
    hipMemsetAsync(stats, 0, 1024 * sizeof(float), stream);
    k_gemm_rt<64, 0, 0, 0, 0, 0, float, ushortt><<<gN64, 256, 0, stream>>>(
        h, Wl, nullptr, Pp, N, nullptr, nullptr, nullptr, nullptr, nullptr,
        nullptr, nullptr);
    k_gemm_rt<64, 0, 0, 1, 1, 0, ushortt, ushortt><<<gE64, 256, 0, stream>>>(
        ea, Wl + 64 * 64, nullptr, M, E, nullptr, Pp, srcp, dstp, Al, aE, stats);
    k_aggregate<<<2048, 256, 0, stream>>>(offs, aE, M, stats,
                                          1.0f / (float)E, aggn, stats + 64, N);
    k_hnew<<<2048, 256, 0, stream>>>(aggn, stats + 64, 1.0f / (float)N, h, N);
  }

  k_comp<<<gN64, 256, 0, stream>>>(h, gfeat, batch, compW, compb, attW, attb, aN, N);
  k_pool<<<G, 64, 0, stream>>>(h, aN, batch, fcW, fcb, out, N, G);

  (void)n_in; (void)out_size; (void)ws_size;
}

// Round 14
// 1037.204 us; speedup vs baseline: 1.8192x; 1.0198x over previous
//
#include <hip/hip_runtime.h>
#include <hip/hip_bf16.h>
#include <hip/hip_fp16.h>
#include <math.h>

// ---------------------------------------------------------------------------
// GATGNN forward. fp32 math; edge streams fp16, ALL CSR-ordered (~140 MB ws).
//   CSR build first: eids (CSR slot -> edge), srcp/dstp (CSR-ordered endpoints)
//   h = x@Wn + bn
//   ea = leaky_relu(eattr@We + be)   [gathered by eids -> CSR-ordered fp16]
//   per layer (edge streams sequential in CSR slot):
//     P = h@Wtop (fp16 out)   [layers 1,2: staging reads aggn and applies
//                              BN+softplus inline -> no separate hnew pass]
//     fused: M = ea@Wbot  [fp16 LDS + v_dot2_f32_f16, ROLLED k8 loop];
//            P[src]/P[dst] rows PREFETCHED before MAC loop (latency hiding);
//            ti=sp(Pd+M), tj=sp(Ps+M); M<-tj (fp16); a1=sp(dot att); a1 stats
//     aggregate: per dst node sequential walk; w=exp(sp(BN(a1)));
//            aggn=(sum tj*w)/(sum w); col stats -> 4-way banked cs
//   final h = sp(BN(aggn)) once; comp attention + seg-softmax + pool + fc
// Lessons pinned:
//  - NEVER pass min-waves to __launch_bounds__ (r6/r7: VGPR cap -> GB spills).
//  - r9: FULL-UNROLL k8 loop hoisted reg tiles -> VGPR 144, occupancy 10%.
//  - r11: >500 same-address atomics queue (~20ns each) -> banked cs.
//  - r13: halving LDS+VALU+2x occupancy left fused GEMM at 179us -> the
//    bottleneck is the post-MAC scattered P-gather tail. Prefetch pre-MAC.
// ---------------------------------------------------------------------------

typedef unsigned short ushortt;
typedef _Float16 half2v __attribute__((ext_vector_type(2)));

__device__ __forceinline__ float sp_f(float x) {
  return x > 20.0f ? x : __logf(1.0f + __expf(x));
}
__device__ __forceinline__ float h2f(ushortt u) {
  union { ushortt u; __half h; } c; c.u = u;
  return __half2float(c.h);
}
__device__ __forceinline__ ushortt f2h(float f) {
  union { __half h; ushortt u; } c; c.h = __float2half(f);
  return c.u;
}
__device__ __forceinline__ float4 h4_to_f4(ushort4 u) {
  return make_float4(h2f(u.x), h2f(u.y), h2f(u.z), h2f(u.w));
}
__device__ __forceinline__ unsigned pack2h(float a, float b) {
  union { _Float16 h[2]; unsigned u; } c;
  c.h[0] = (_Float16)a; c.h[1] = (_Float16)b;
  return c.u;
}
__device__ __forceinline__ float fdot2f(unsigned a, unsigned b, float c) {
  return __builtin_amdgcn_fdot2(__builtin_bit_cast(half2v, a),
                                __builtin_bit_cast(half2v, b), c, false);
}

// Register-tiled GEMM: out[R,64] = act(in[rows?][K] @ W[K,64] (+ b))
// Block: 256 thr, tile 64 rows x 64 cols; thread: 4 rows x 4 cols.
// LH16: fp16 in; A-tile fp16 raw copy; W k-pair-packed half2; dot2 MACs,
//       ROLLED k8 loop (VGPR control).  else: fp32 LDS tiles.
// GATHER: staging reads rows[r].  FUSE_BN: staging input is aggn (fp32) and
// BN+softplus applied inline using banked cs (csbn) and invN.
// FUSE_A: P rows prefetched pre-MAC; epilogue writes tj (fp16) to out[e],
//         a1[e], a1 sum/sumsq into stats[0..1]. All e-sequential.
template<int K, int ACT, int BIAS, int FUSE_A, int LH16, int GATHER, int FUSE_BN,
         typename IT, typename OT>
__global__ __launch_bounds__(256) void k_gemm_rt(
    const IT* __restrict__ in, const float* __restrict__ W,
    const float* __restrict__ b, OT* __restrict__ out, int R,
    const int* __restrict__ rows, const ushortt* __restrict__ P,
    const int* __restrict__ srcp, const int* __restrict__ dstp,
    const float* __restrict__ catt, float* __restrict__ a1,
    float* __restrict__ stats, const float* __restrict__ csbn, float invN)
{
  constexpr int KP  = (K + 3) / 4 * 4;       // fp32 path: k padded to x4
  constexpr int LSf = KP + 4;                // fp32 ins stride (floats)
  constexpr int LSb = K + 8;                 // fp16 ins stride (shorts)
  constexpr size_t INS_B = LH16 ? (size_t)64 * LSb * 2 : (size_t)64 * LSf * 4;
  constexpr size_t WS_B  = LH16 ? (size_t)(K / 2) * 64 * 4 : (size_t)KP * 64 * 4;
  __shared__ __align__(16) unsigned char smem[INS_B + WS_B];
  __shared__ float atts[128];
  __shared__ float ssum[4], ssq[4];
  ushortt*  insb = (ushortt*)smem;
  unsigned* Wp   = (unsigned*)(smem + INS_B);   // LH16: [K/2][64] half2-packed
  float*    insf = (float*)smem;
  float*    Wsf  = (float*)(smem + INS_B);

  const int tx = threadIdx.x;
  const int b0 = blockIdx.x * 64;

  if (LH16) {
    static_assert(!LH16 || (K % 8 == 0), "fp16 path needs K%8==0");
    for (int i = tx; i < (K / 2) * 64; i += 256) {
      const int k2 = i >> 6;
      const int c = i & 63;
      Wp[i] = pack2h(W[(2 * k2) * 64 + c], W[(2 * k2 + 1) * 64 + c]);
    }
    for (int i = tx; i < 64 * (K / 8); i += 256) {
      const int row = i / (K / 8);
      const int k8 = i % (K / 8);
      long r = b0 + row; if (r >= R) r = R - 1;   // clamp: values unused
      if (GATHER) r = rows[r];
      *(uint4*)&insb[row * LSb + k8 * 8] =
          *(const uint4*)&((const ushortt*)in)[r * (long)K + k8 * 8];
    }
  } else {
    for (int i = tx; i < KP * 64; i += 256) {
      const int k = i >> 6;
      Wsf[i] = (k < K) ? W[i] : 0.0f;
    }
    for (int i = tx; i < 64 * (KP / 4); i += 256) {
      const int row = i / (KP / 4);
      const int k4 = i % (KP / 4);
      long r = b0 + row; if (r >= R) r = R - 1;   // clamp: values unused
      if (GATHER) r = rows[r];
      float4 v;
      if (K % 4 == 0) {
        v = *(const float4*)&((const float*)in)[r * (long)K + k4 * 4];
      } else {
        float t[4];
        #pragma unroll
        for (int j = 0; j < 4; ++j) {
          const int k = k4 * 4 + j;
          t[j] = (k < K) ? ((const float*)in)[r * (long)K + k] : 0.0f;
        }
        v = make_float4(t[0], t[1], t[2], t[3]);
      }
      if (FUSE_BN) {
        float* vv = (float*)&v;
        #pragma unroll
        for (int j = 0; j < 4; ++j) {
          const int c = k4 * 4 + j;
          const float mn = (csbn[c] + csbn[128 + c] + csbn[256 + c] + csbn[384 + c]) * invN;
          const float sq = (csbn[64 + c] + csbn[192 + c] + csbn[320 + c] + csbn[448 + c]) * invN;
          vv[j] = sp_f((vv[j] - mn) * rsqrtf(sq - mn * mn + 1e-5f));
        }
      }
      *(float4*)&insf[row * LSf + k4 * 4] = v;
    }
  }
  if (FUSE_A) { if (tx < 128) atts[tx] = catt[tx]; }
  __syncthreads();

  const int lr0 = ((tx >> 6) << 4) + (((tx >> 4) & 3) << 2);  // local row base
  const int c0 = (tx & 15) << 2;                               // col base

  // FUSE_A: prefetch P rows NOW -- their latency hides under the MAC loop.
  ushort4 pdv[4], psv[4];
  if (FUSE_A) {
    #pragma unroll
    for (int ri = 0; ri < 4; ++ri) {
      long e = b0 + lr0 + ri; if (e >= R) e = R - 1;   // clamp: values unused
      const int s = srcp[e];
      const int d = dstp[e];
      psv[ri] = *(const ushort4*)&P[(long)s * 64 + c0];
      pdv[ri] = *(const ushort4*)&P[(long)d * 64 + c0];
    }
  }

  float acc[4][4];
  #pragma unroll
  for (int i = 0; i < 4; ++i)
    #pragma unroll
    for (int j = 0; j < 4; ++j) acc[i][j] = 0.0f;

  if (LH16) {
    // ROLLED k8 loop: wv loaded once/iter, av per-ri, consumed at once.
    #pragma unroll 1
    for (int k8 = 0; k8 < K / 8; ++k8) {
      const uint4 wv0 = *(const uint4*)&Wp[(k8 * 4 + 0) * 64 + c0];
      const uint4 wv1 = *(const uint4*)&Wp[(k8 * 4 + 1) * 64 + c0];
      const uint4 wv2 = *(const uint4*)&Wp[(k8 * 4 + 2) * 64 + c0];
      const uint4 wv3 = *(const uint4*)&Wp[(k8 * 4 + 3) * 64 + c0];
      #pragma unroll
      for (int ri = 0; ri < 4; ++ri) {
        const uint4 av = *(const uint4*)&insb[(lr0 + ri) * LSb + k8 * 8];
        acc[ri][0] = fdot2f(av.x, wv0.x, acc[ri][0]);
        acc[ri][1] = fdot2f(av.x, wv0.y, acc[ri][1]);
        acc[ri][2] = fdot2f(av.x, wv0.z, acc[ri][2]);
        acc[ri][3] = fdot2f(av.x, wv0.w, acc[ri][3]);
        acc[ri][0] = fdot2f(av.y, wv1.x, acc[ri][0]);
        acc[ri][1] = fdot2f(av.y, wv1.y, acc[ri][1]);
        acc[ri][2] = fdot2f(av.y, wv1.z, acc[ri][2]);
        acc[ri][3] = fdot2f(av.y, wv1.w, acc[ri][3]);
        acc[ri][0] = fdot2f(av.z, wv2.x, acc[ri][0]);
        acc[ri][1] = fdot2f(av.z, wv2.y, acc[ri][1]);
        acc[ri][2] = fdot2f(av.z, wv2.z, acc[ri][2]);
        acc[ri][3] = fdot2f(av.z, wv2.w, acc[ri][3]);
        acc[ri][0] = fdot2f(av.w, wv3.x, acc[ri][0]);
        acc[ri][1] = fdot2f(av.w, wv3.y, acc[ri][1]);
        acc[ri][2] = fdot2f(av.w, wv3.z, acc[ri][2]);
        acc[ri][3] = fdot2f(av.w, wv3.w, acc[ri][3]);
      }
    }
  } else {
    #pragma unroll 4
    for (int k4 = 0; k4 < KP / 4; ++k4) {
      float4 w[4], a[4];
      #pragma unroll
      for (int kk = 0; kk < 4; ++kk)
        w[kk] = *(const float4*)&Wsf[(k4 * 4 + kk) * 64 + c0];
      #pragma unroll
      for (int ri = 0; ri < 4; ++ri)
        a[ri] = *(const float4*)&insf[(lr0 + ri) * LSf + k4 * 4];
      #pragma unroll
      for (int ri = 0; ri < 4; ++ri) {
        const float* av = (const float*)&a[ri];
        #pragma unroll
        for (int kk = 0; kk < 4; ++kk) {
          acc[ri][0] = fmaf(av[kk], w[kk].x, acc[ri][0]);
          acc[ri][1] = fmaf(av[kk], w[kk].y, acc[ri][1]);
          acc[ri][2] = fmaf(av[kk], w[kk].z, acc[ri][2]);
          acc[ri][3] = fmaf(av[kk], w[kk].w, acc[ri][3]);
        }
      }
    }
  }

  if (!FUSE_A) {
    float4 bias = make_float4(0.f, 0.f, 0.f, 0.f);
    if (BIAS) bias = *(const float4*)&b[c0];
    #pragma unroll
    for (int ri = 0; ri < 4; ++ri) {
      const long r = b0 + lr0 + ri;
      if (r >= R) continue;
      float4 v;
      v.x = acc[ri][0] + bias.x; v.y = acc[ri][1] + bias.y;
      v.z = acc[ri][2] + bias.z; v.w = acc[ri][3] + bias.w;
      if (ACT == 1) {
        v.x = v.x >= 0.f ? v.x : 0.2f * v.x;  v.y = v.y >= 0.f ? v.y : 0.2f * v.y;
        v.z = v.z >= 0.f ? v.z : 0.2f * v.z;  v.w = v.w >= 0.f ? v.w : 0.2f * v.w;
      }
      if (sizeof(OT) == 4) {
        *(float4*)&out[r * 64 + c0] = v;
      } else {
        ushort4 u;
        u.x = f2h(v.x); u.y = f2h(v.y); u.z = f2h(v.z); u.w = f2h(v.w);
        *(ushort4*)&out[r * 64 + c0] = u;
      }
    }
  } else {
    // epilogue: ti/tj from prefetched P; tj -> out[e] (fp16), a1[e]; a1 stats
    float s1 = 0.f, s2 = 0.f;
    #pragma unroll
    for (int ri = 0; ri < 4; ++ri) {
      const long e = b0 + lr0 + ri;
      float part = 0.0f;
      if (e < R) {
        const float4 Pd = h4_to_f4(pdv[ri]);
        const float4 Ps = h4_to_f4(psv[ri]);
        float tj[4];
        const float ti0 = sp_f(Pd.x + acc[ri][0]);
        const float ti1 = sp_f(Pd.y + acc[ri][1]);
        const float ti2 = sp_f(Pd.z + acc[ri][2]);
        const float ti3 = sp_f(Pd.w + acc[ri][3]);
        tj[0] = sp_f(Ps.x + acc[ri][0]);
        tj[1] = sp_f(Ps.y + acc[ri][1]);
        tj[2] = sp_f(Ps.z + acc[ri][2]);
        tj[3] = sp_f(Ps.w + acc[ri][3]);
        ushort4 u;
        u.x = f2h(tj[0]); u.y = f2h(tj[1]); u.z = f2h(tj[2]); u.w = f2h(tj[3]);
        *(ushort4*)&out[e * 64 + c0] = u;
        part = ti0 * atts[c0] + ti1 * atts[c0 + 1] + ti2 * atts[c0 + 2] + ti3 * atts[c0 + 3]
             + tj[0] * atts[64 + c0] + tj[1] * atts[64 + c0 + 1]
             + tj[2] * atts[64 + c0 + 2] + tj[3] * atts[64 + c0 + 3];
      }
      #pragma unroll
      for (int off = 8; off; off >>= 1) part += __shfl_xor(part, off);
      if ((tx & 15) == 0 && e < R) {
        const float v = sp_f(part);
        a1[e] = v;
        s1 += v; s2 += v * v;
      }
    }
    s1 += __shfl_xor(s1, 16); s2 += __shfl_xor(s2, 16);
    s1 += __shfl_xor(s1, 32); s2 += __shfl_xor(s2, 32);
    if ((tx & 63) == 0) { ssum[tx >> 6] = s1; ssq[tx >> 6] = s2; }
    __syncthreads();
    if (tx == 0) {
      atomicAdd(&stats[0], ssum[0] + ssum[1] + ssum[2] + ssum[3]);
      atomicAdd(&stats[1], ssq[0] + ssq[1] + ssq[2] + ssq[3]);
    }
  }
}

// ---------- CSR build (once per launch; graph static across layers) --------
__global__ __launch_bounds__(256) void k_count(
    const int* __restrict__ dst, int* __restrict__ counts, int E)
{
  for (int i = blockIdx.x * 256 + threadIdx.x; i < E; i += gridDim.x * 256)
    atomicAdd(&counts[dst[i]], 1);
}

// single-block exclusive scan: offs[0..N-1] = exclusive prefix, offs[N] = E
__global__ __launch_bounds__(1024) void k_scan(
    const int* __restrict__ counts, int* __restrict__ offs, int N)
{
  __shared__ int part[1024];
  const int t = threadIdx.x;
  const int chunk = (N + 1023) >> 10;
  const int s0 = t * chunk;
  int sum = 0;
  for (int i = 0; i < chunk; ++i) {
    const int idx = s0 + i;
    if (idx < N) sum += counts[idx];
  }
  part[t] = sum;
  __syncthreads();
  for (int off = 1; off < 1024; off <<= 1) {
    const int v = (t >= off) ? part[t - off] : 0;
    __syncthreads();
    part[t] += v;
    __syncthreads();
  }
  int base = (t == 0) ? 0 : part[t - 1];
  for (int i = 0; i < chunk; ++i) {
    const int idx = s0 + i;
    if (idx < N) { offs[idx] = base; base += counts[idx]; }
  }
  if (N - 1 >= s0 && N - 1 < s0 + chunk) offs[N] = base;
}

// eids[CSR slot] = original edge id
__global__ __launch_bounds__(256) void k_fill(
    const int* __restrict__ dst, const int* __restrict__ offs,
    int* __restrict__ cursors, int* __restrict__ eids, int E)
{
  for (int i = blockIdx.x * 256 + threadIdx.x; i < E; i += gridDim.x * 256) {
    const int d = dst[i];
    eids[offs[d] + atomicAdd(&cursors[d], 1)] = i;
  }
}

// srcp/dstp in CSR order
__global__ __launch_bounds__(256) void k_permidx(
    const int* __restrict__ eids, const int* __restrict__ eidx,
    int* __restrict__ srcp, int* __restrict__ dstp, int E)
{
  for (int i = blockIdx.x * 256 + threadIdx.x; i < E; i += gridDim.x * 256) {
    const int e = eids[i];
    srcp[i] = eidx[e];
    dstp[i] = eidx[(long)E + e];
  }
}

// ---------- aggregate: sequential CSR reads, banked col-stats ---------------
__global__ __launch_bounds__(256) void k_aggregate(
    const int* __restrict__ offs, const float* __restrict__ a1p,
    const ushortt* __restrict__ Mp, const float* __restrict__ stats,
    float invE, float* __restrict__ aggn, float* __restrict__ cs, int N)
{
  const float mean = stats[0] * invE;
  const float var = stats[1] * invE - mean * mean;
  const float scl = rsqrtf(var + 1e-5f);
  const int t = threadIdx.x & 63;
  const int wid = threadIdx.x >> 6;
  float s = 0.f, s2 = 0.f;
  const long step = (long)gridDim.x * 4;
  for (long n = (long)blockIdx.x * 4 + wid; n < N; n += step) {
    const int o0 = offs[n];
    const int o1 = offs[n + 1];
    float av = 0.f, sew = 0.f;
    #pragma unroll 4
    for (int i = o0; i < o1; ++i) {
      const float w = __expf(sp_f((a1p[i] - mean) * scl));
      av = fmaf(h2f(Mp[(long)i * 64 + t]), w, av);
      sew += w;
    }
    const float v = (o1 > o0) ? av / sew : 0.0f;
    aggn[n * 64 + t] = v;
    s += v; s2 += v * v;
  }
  __shared__ float b1[256], b2[256];
  b1[threadIdx.x] = s; b2[threadIdx.x] = s2;
  __syncthreads();
  if (threadIdx.x < 64) {
    const int bank = (blockIdx.x & 3) * 128;
    atomicAdd(&cs[bank + t], b1[t] + b1[64 + t] + b1[128 + t] + b1[192 + t]);
    atomicAdd(&cs[bank + 64 + t], b2[t] + b2[64 + t] + b2[128 + t] + b2[192 + t]);
  }
}

// h = sp((aggn - mean_c) * rsqrt(var_c + eps)); cs has 4 banks of 128
__global__ __launch_bounds__(256) void k_hnew(
    const float* __restrict__ aggn, const float* __restrict__ cs,
    float invN, float* __restrict__ h, int N)
{
  const int c = threadIdx.x & 63;
  const int r = threadIdx.x >> 6;
  const float mean = (cs[c] + cs[128 + c] + cs[256 + c] + cs[384 + c]) * invN;
  const float sq = (cs[64 + c] + cs[192 + c] + cs[320 + c] + cs[448 + c]) * invN;
  const float scl = rsqrtf(sq - mean * mean + 1e-5f);
  for (long n = (long)blockIdx.x * 4 + r; n < N; n += (long)gridDim.x * 4)
    h[n * 64 + c] = sp_f((aggn[n * 64 + c] - mean) * scl);
}

// composition attention score a[n] = sp(concat(h,gf)@Wc + bc) @ attW + attb
__global__ __launch_bounds__(256) void k_comp(
    const float* __restrict__ h, const float* __restrict__ gf,
    const int* __restrict__ batch, const float* __restrict__ Wc,
    const float* __restrict__ bc, const float* __restrict__ aw,
    const float* __restrict__ ab, float* __restrict__ aN, int N)
{
  __shared__ float Wcs[167 * 32];
  __shared__ float aws[32];
  __shared__ float bcs[32];
  for (int i = threadIdx.x; i < 167 * 32; i += 256) Wcs[i] = Wc[i];
  if (threadIdx.x < 32) { aws[threadIdx.x] = aw[threadIdx.x]; bcs[threadIdx.x] = bc[threadIdx.x]; }
  __syncthreads();
  const int t = threadIdx.x & 63;
  const int wid = threadIdx.x >> 6;
  const int col = t & 31;
  const float ab0 = ab[0];
  const int step = gridDim.x * 4;
  for (int n = blockIdx.x * 4 + wid; n < N; n += step) {
    const int g = batch[n];
    const float hq = h[(long)n * 64 + t];
    const float g1 = gf[(long)g * 103 + t];
    const float g2 = (t < 39) ? gf[(long)g * 103 + 64 + t] : 0.f;
    float acc = bcs[col];
    #pragma unroll 8
    for (int k = 0; k < 64; ++k) acc = fmaf(__shfl(hq, k), Wcs[k * 32 + col], acc);
    #pragma unroll 8
    for (int k = 0; k < 64; ++k) acc = fmaf(__shfl(g1, k), Wcs[(64 + k) * 32 + col], acc);
    #pragma unroll
    for (int k = 0; k < 39; ++k) acc = fmaf(__shfl(g2, k), Wcs[(128 + k) * 32 + col], acc);
    float val = sp_f(acc) * aws[col];
    #pragma unroll
    for (int off = 16; off; off >>= 1) val += __shfl_xor(val, off);
    if (t == 0) aN[n] = val + ab0;
  }
}

// one 64-thread block per graph: seg-softmax over sorted batch + pool + fc
__global__ __launch_bounds__(64) void k_pool(
    const float* __restrict__ h, const float* __restrict__ aN,
    const int* __restrict__ batch, const float* __restrict__ fcW,
    const float* __restrict__ fcb, float* __restrict__ out, int N, int G)
{
  const int g = blockIdx.x;
  const int t = threadIdx.x;
  int lo = 0, hi = N;
  while (lo < hi) { int mid = (lo + hi) >> 1; if (batch[mid] < g) lo = mid + 1; else hi = mid; }
  const int s = lo;
  hi = N;
  while (lo < hi) { int mid = (lo + hi) >> 1; if (batch[mid] < g + 1) lo = mid + 1; else hi = mid; }
  const int e2 = lo;
  if (s >= e2) { if (t == 0) out[g] = fcb[0]; return; }
  float mx = -1e30f;
  for (int i = s + t; i < e2; i += 64) mx = fmaxf(mx, aN[i]);
  #pragma unroll
  for (int off = 32; off; off >>= 1) mx = fmaxf(mx, __shfl_xor(mx, off));
  float se = 0.f;
  for (int i = s + t; i < e2; i += 64) se += __expf(aN[i] - mx);
  #pragma unroll
  for (int off = 32; off; off >>= 1) se += __shfl_xor(se, off);
  float acc = 0.f;
  for (int n = s; n < e2; ++n) {
    const float w = __expf(aN[n] - mx);
    acc = fmaf(h[(long)n * 64 + t], w, acc);
  }
  float part = (acc / se) * fcW[t];
  #pragma unroll
  for (int off = 32; off; off >>= 1) part += __shfl_xor(part, off);
  if (t == 0) out[g] = part + fcb[0];
}

extern "C" void kernel_launch(void* const* d_in, const int* in_sizes, int n_in,
                              void* d_out, int out_size, void* d_ws, size_t ws_size,
                              hipStream_t stream)
{
  const float* x     = (const float*)d_in[0];
  const int*   eidx  = (const int*)  d_in[1];
  const float* eattr = (const float*)d_in[2];
  const int*   batch = (const int*)  d_in[3];
  const float* gfeat = (const float*)d_in[4];
  const float* embnW = (const float*)d_in[5];
  const float* embnb = (const float*)d_in[6];
  const float* embeW = (const float*)d_in[7];
  const float* embeb = (const float*)d_in[8];
  const float* convW = (const float*)d_in[9];
  const float* convA = (const float*)d_in[10];
  // d_in[11] = conv_bias: cancels exactly in training-mode BatchNorm
  const float* compW = (const float*)d_in[12];
  const float* compb = (const float*)d_in[13];
  const float* attW  = (const float*)d_in[14];
  const float* attb  = (const float*)d_in[15];
  const float* fcW   = (const float*)d_in[16];
  const float* fcb   = (const float*)d_in[17];
  float* out = (float*)d_out;

  const int N = in_sizes[0] / 92;
  const int E = in_sizes[1] / 2;
  const int G = in_sizes[4] / 103;
  const float invN = 1.0f / (float)N;
  const float invE = 1.0f / (float)E;

  // workspace (~140 MB): fp32 node buffers, CSR ints, fp16 edge streams + P
  char* pw = (char*)d_ws;
  float* h     = (float*)pw;  pw += (size_t)N * 64 * 4;
  float* aggn  = (float*)pw;  pw += (size_t)N * 64 * 4;
  float* aE    = (float*)pw;  pw += (size_t)E * 4;        // a1 (CSR-ordered)
  float* statsB = (float*)pw; pw += 3 * 1024 * 4;         // per-layer: [0..1] BN-E; cs@64 (4x128)
  float* aN    = (float*)pw;  pw += (size_t)N * 4;
  int* counts  = (int*)pw;    pw += (size_t)N * 4;        // counts+cursors: one memset
  int* cursors = (int*)pw;    pw += (size_t)N * 4;
  int* offs    = (int*)pw;    pw += ((size_t)N + 1) * 4;
  int* eids    = (int*)pw;    pw += (size_t)E * 4;
  int* srcp    = (int*)pw;    pw += (size_t)E * 4;
  int* dstp    = (int*)pw;    pw += (size_t)E * 4;
  pw = (char*)(((size_t)pw + 63) & ~(size_t)63);
  ushortt* Pp  = (ushortt*)pw; pw += (size_t)N * 64 * 2;  // P fp16
  ushortt* ea  = (ushortt*)pw; pw += (size_t)E * 64 * 2;  // fp16, CSR-ordered
  ushortt* M   = (ushortt*)pw;                            // fp16 tj, CSR-ordered

  const int gE64 = (E + 63) / 64;
  const int gN64 = (N + 63) / 64;

  // CSR build (dst = eidx[E..2E)), then index permutes
  hipMemsetAsync(counts, 0, 2 * (size_t)N * sizeof(int), stream);
  hipMemsetAsync(statsB, 0, 3 * 1024 * sizeof(float), stream);
  k_count<<<2048, 256, 0, stream>>>(eidx + E, counts, E);
  k_scan<<<1, 1024, 0, stream>>>(counts, offs, N);
  k_fill<<<2048, 256, 0, stream>>>(eidx + E, offs, cursors, eids, E);
  k_permidx<<<2048, 256, 0, stream>>>(eids, eidx, srcp, dstp, E);

  k_gemm_rt<92, 0, 1, 0, 0, 0, 0, float, float><<<gN64, 256, 0, stream>>>(
      x, embnW, embnb, h, N, nullptr, nullptr, nullptr, nullptr, nullptr,
      nullptr, nullptr, nullptr, 0.f);
  // ea-embed: gather eattr rows by eids -> ea written CSR-ordered, coalesced
  k_gemm_rt<41, 1, 1, 0, 0, 1, 0, float, ushortt><<<gE64, 256, 0, stream>>>(
      eattr, embeW, embeb, ea, E, eids, nullptr, nullptr, nullptr, nullptr,
      nullptr, nullptr, nullptr, 0.f);

  for (int l = 0; l < 3; ++l) {
    const float* Wl = convW + (size_t)l * 128 * 64;
    const float* Al = convA + (size_t)l * 128;
    float* statsL = statsB + (size_t)l * 1024;
    if (l == 0) {
      k_gemm_rt<64, 0, 0, 0, 0, 0, 0, float, ushortt><<<gN64, 256, 0, stream>>>(
          h, Wl, nullptr, Pp, N, nullptr, nullptr, nullptr, nullptr, nullptr,
          nullptr, nullptr, nullptr, 0.f);
    } else {
      // staging reads aggn and applies BN+softplus inline (cs of layer l-1)
      k_gemm_rt<64, 0, 0, 0, 0, 0, 1, float, ushortt><<<gN64, 256, 0, stream>>>(
          aggn, Wl, nullptr, Pp, N, nullptr, nullptr, nullptr, nullptr, nullptr,
          nullptr, nullptr, statsB + (size_t)(l - 1) * 1024 + 64, invN);
    }
    k_gemm_rt<64, 0, 0, 1, 1, 0, 0, ushortt, ushortt><<<gE64, 256, 0, stream>>>(
        ea, Wl + 64 * 64, nullptr, M, E, nullptr, Pp, srcp, dstp, Al, aE,
        statsL, nullptr, 0.f);
    k_aggregate<<<2048, 256, 0, stream>>>(offs, aE, M, statsL,
                                          invE, aggn, statsL + 64, N);
  }

  k_hnew<<<2048, 256, 0, stream>>>(aggn, statsB + 2 * 1024 + 64, invN, h, N);
  k_comp<<<gN64, 256, 0, stream>>>(h, gfeat, batch, compW, compb, attW, attb, aN, N);
  k_pool<<<G, 64, 0, stream>>>(h, aN, batch, fcW, fcb, out, N, G);

  (void)n_in; (void)out_size; (void)ws_size;
}

// Round 15
// 736.643 us; speedup vs baseline: 2.5615x; 1.4080x over previous
//
#include <hip/hip_runtime.h>
#include <hip/hip_bf16.h>
#include <hip/hip_fp16.h>
#include <math.h>

// ---------------------------------------------------------------------------
// GATGNN forward. fp32 math; edge streams fp16, ALL CSR-ordered (~140 MB ws).
//   CSR build first: eids (CSR slot -> edge), srcp/dstp (CSR-ordered endpoints)
//   h = x@Wn + bn
//   ea = leaky_relu(eattr@We + be)   [gathered by eids -> CSR-ordered fp16]
//   per layer (edge streams sequential in CSR slot):
//     P = h@Wtop (fp16 out)   [layers 1,2: staging reads aggn and applies
//                              BN+softplus inline via 16-bank cs -> no hnew]
//     fused: M = ea@Wbot  [fp16 LDS + v_dot2_f32_f16, ROLLED k8 loop];
//            P rows prefetched pre-MAC; ti=sp(Pd+M), tj=sp(Ps+M); M<-tj;
//            a1=sp(dot att); a1 stats -> 64-WAY-BANKED atomics
//     aggregate: reduce stat banks once; per dst node sequential walk;
//            w=exp(sp(BN(a1))); aggn=(sum tj*w)/(sum w); col stats -> 16-bank cs
//   final h = sp(BN(aggn)); comp attention + seg-softmax + pool + fc
// Lessons pinned:
//  - NEVER pass min-waves to __launch_bounds__ (r6/r7: VGPR cap -> GB spills).
//  - r9: FULL-UNROLL k8 loop hoisted reg tiles -> VGPR 144, occupancy 10%.
//  - r11: same-address L2 atomic ~22ns SERIALIZED. r12-r14's fused GEMM was
//    floor-limited by 6250 blocks x 2 atomics to stats[0..1] (~135us) -- which
//    is why halving LDS+VALU (r13) and prefetch (r14) changed nothing.
//    Keep per-address atomic count <= ~128 EVERYWHERE.
// ---------------------------------------------------------------------------

typedef unsigned short ushortt;
typedef _Float16 half2v __attribute__((ext_vector_type(2)));

__device__ __forceinline__ float sp_f(float x) {
  return x > 20.0f ? x : __logf(1.0f + __expf(x));
}
__device__ __forceinline__ float h2f(ushortt u) {
  union { ushortt u; __half h; } c; c.u = u;
  return __half2float(c.h);
}
__device__ __forceinline__ ushortt f2h(float f) {
  union { __half h; ushortt u; } c; c.h = __float2half(f);
  return c.u;
}
__device__ __forceinline__ float4 h4_to_f4(ushort4 u) {
  return make_float4(h2f(u.x), h2f(u.y), h2f(u.z), h2f(u.w));
}
__device__ __forceinline__ unsigned pack2h(float a, float b) {
  union { _Float16 h[2]; unsigned u; } c;
  c.h[0] = (_Float16)a; c.h[1] = (_Float16)b;
  return c.u;
}
__device__ __forceinline__ float fdot2f(unsigned a, unsigned b, float c) {
  return __builtin_amdgcn_fdot2(__builtin_bit_cast(half2v, a),
                                __builtin_bit_cast(half2v, b), c, false);
}

// per-layer stats block layout (floats), stride SLOTS:
//   [0..63]    a1 sum banks      [64..127]  a1 sumsq banks
//   [128 .. 128+16*128)  col-stats cs, 16 banks x (64 sum + 64 sumsq)
#define SLOTS 2304

// Register-tiled GEMM: out[R,64] = act(in[rows?][K] @ W[K,64] (+ b))
// Block: 256 thr, tile 64 rows x 64 cols; thread: 4 rows x 4 cols.
// LH16: fp16 in; A-tile fp16 raw copy; W k-pair-packed half2; dot2 MACs,
//       ROLLED k8 loop.  else: fp32 LDS tiles.
// GATHER: staging reads rows[r].  FUSE_BN: staging input aggn (fp32), BN+sp
// applied inline; per-column mean/scl precomputed into LDS from 16-bank csbn.
// FUSE_A: P rows prefetched pre-MAC; epilogue writes tj (fp16) to out[e],
//         a1[e]; a1 sum/sumsq -> 64-way banked atomics in stats[0..127].
template<int K, int ACT, int BIAS, int FUSE_A, int LH16, int GATHER, int FUSE_BN,
         typename IT, typename OT>
__global__ __launch_bounds__(256) void k_gemm_rt(
    const IT* __restrict__ in, const float* __restrict__ W,
    const float* __restrict__ b, OT* __restrict__ out, int R,
    const int* __restrict__ rows, const ushortt* __restrict__ P,
    const int* __restrict__ srcp, const int* __restrict__ dstp,
    const float* __restrict__ catt, float* __restrict__ a1,
    float* __restrict__ stats, const float* __restrict__ csbn, float invN)
{
  constexpr int KP  = (K + 3) / 4 * 4;       // fp32 path: k padded to x4
  constexpr int LSf = KP + 4;                // fp32 ins stride (floats)
  constexpr int LSb = K + 8;                 // fp16 ins stride (shorts)
  constexpr size_t INS_B = LH16 ? (size_t)64 * LSb * 2 : (size_t)64 * LSf * 4;
  constexpr size_t WS_B  = LH16 ? (size_t)(K / 2) * 64 * 4 : (size_t)KP * 64 * 4;
  __shared__ __align__(16) unsigned char smem[INS_B + WS_B];
  __shared__ float atts[128];
  __shared__ float ssum[4], ssq[4];
  __shared__ float bnm[64], bns[64];
  ushortt*  insb = (ushortt*)smem;
  unsigned* Wp   = (unsigned*)(smem + INS_B);   // LH16: [K/2][64] half2-packed
  float*    insf = (float*)smem;
  float*    Wsf  = (float*)(smem + INS_B);

  const int tx = threadIdx.x;
  const int b0 = blockIdx.x * 64;

  if (FUSE_BN) {
    if (tx < 64) {
      float mn = 0.f, sq = 0.f;
      #pragma unroll
      for (int bk = 0; bk < 16; ++bk) {
        mn += csbn[bk * 128 + tx];
        sq += csbn[bk * 128 + 64 + tx];
      }
      mn *= invN; sq *= invN;
      bnm[tx] = mn;
      bns[tx] = rsqrtf(sq - mn * mn + 1e-5f);
    }
    __syncthreads();
  }

  if (LH16) {
    static_assert(!LH16 || (K % 8 == 0), "fp16 path needs K%8==0");
    for (int i = tx; i < (K / 2) * 64; i += 256) {
      const int k2 = i >> 6;
      const int c = i & 63;
      Wp[i] = pack2h(W[(2 * k2) * 64 + c], W[(2 * k2 + 1) * 64 + c]);
    }
    for (int i = tx; i < 64 * (K / 8); i += 256) {
      const int row = i / (K / 8);
      const int k8 = i % (K / 8);
      long r = b0 + row; if (r >= R) r = R - 1;   // clamp: values unused
      if (GATHER) r = rows[r];
      *(uint4*)&insb[row * LSb + k8 * 8] =
          *(const uint4*)&((const ushortt*)in)[r * (long)K + k8 * 8];
    }
  } else {
    for (int i = tx; i < KP * 64; i += 256) {
      const int k = i >> 6;
      Wsf[i] = (k < K) ? W[i] : 0.0f;
    }
    for (int i = tx; i < 64 * (KP / 4); i += 256) {
      const int row = i / (KP / 4);
      const int k4 = i % (KP / 4);
      long r = b0 + row; if (r >= R) r = R - 1;   // clamp: values unused
      if (GATHER) r = rows[r];
      float4 v;
      if (K % 4 == 0) {
        v = *(const float4*)&((const float*)in)[r * (long)K + k4 * 4];
      } else {
        float t[4];
        #pragma unroll
        for (int j = 0; j < 4; ++j) {
          const int k = k4 * 4 + j;
          t[j] = (k < K) ? ((const float*)in)[r * (long)K + k] : 0.0f;
        }
        v = make_float4(t[0], t[1], t[2], t[3]);
      }
      if (FUSE_BN) {
        float* vv = (float*)&v;
        #pragma unroll
        for (int j = 0; j < 4; ++j) {
          const int c = k4 * 4 + j;
          vv[j] = sp_f((vv[j] - bnm[c]) * bns[c]);
        }
      }
      *(float4*)&insf[row * LSf + k4 * 4] = v;
    }
  }
  if (FUSE_A) { if (tx < 128) atts[tx] = catt[tx]; }
  __syncthreads();

  const int lr0 = ((tx >> 6) << 4) + (((tx >> 4) & 3) << 2);  // local row base
  const int c0 = (tx & 15) << 2;                               // col base

  // FUSE_A: prefetch P rows NOW -- latency hides under the MAC loop.
  ushort4 pdv[4], psv[4];
  if (FUSE_A) {
    #pragma unroll
    for (int ri = 0; ri < 4; ++ri) {
      long e = b0 + lr0 + ri; if (e >= R) e = R - 1;   // clamp: values unused
      const int s = srcp[e];
      const int d = dstp[e];
      psv[ri] = *(const ushort4*)&P[(long)s * 64 + c0];
      pdv[ri] = *(const ushort4*)&P[(long)d * 64 + c0];
    }
  }

  float acc[4][4];
  #pragma unroll
  for (int i = 0; i < 4; ++i)
    #pragma unroll
    for (int j = 0; j < 4; ++j) acc[i][j] = 0.0f;

  if (LH16) {
    // ROLLED k8 loop: wv loaded once/iter, av per-ri, consumed at once.
    #pragma unroll 1
    for (int k8 = 0; k8 < K / 8; ++k8) {
      const uint4 wv0 = *(const uint4*)&Wp[(k8 * 4 + 0) * 64 + c0];
      const uint4 wv1 = *(const uint4*)&Wp[(k8 * 4 + 1) * 64 + c0];
      const uint4 wv2 = *(const uint4*)&Wp[(k8 * 4 + 2) * 64 + c0];
      const uint4 wv3 = *(const uint4*)&Wp[(k8 * 4 + 3) * 64 + c0];
      #pragma unroll
      for (int ri = 0; ri < 4; ++ri) {
        const uint4 av = *(const uint4*)&insb[(lr0 + ri) * LSb + k8 * 8];
        acc[ri][0] = fdot2f(av.x, wv0.x, acc[ri][0]);
        acc[ri][1] = fdot2f(av.x, wv0.y, acc[ri][1]);
        acc[ri][2] = fdot2f(av.x, wv0.z, acc[ri][2]);
        acc[ri][3] = fdot2f(av.x, wv0.w, acc[ri][3]);
        acc[ri][0] = fdot2f(av.y, wv1.x, acc[ri][0]);
        acc[ri][1] = fdot2f(av.y, wv1.y, acc[ri][1]);
        acc[ri][2] = fdot2f(av.y, wv1.z, acc[ri][2]);
        acc[ri][3] = fdot2f(av.y, wv1.w, acc[ri][3]);
        acc[ri][0] = fdot2f(av.z, wv2.x, acc[ri][0]);
        acc[ri][1] = fdot2f(av.z, wv2.y, acc[ri][1]);
        acc[ri][2] = fdot2f(av.z, wv2.z, acc[ri][2]);
        acc[ri][3] = fdot2f(av.z, wv2.w, acc[ri][3]);
        acc[ri][0] = fdot2f(av.w, wv3.x, acc[ri][0]);
        acc[ri][1] = fdot2f(av.w, wv3.y, acc[ri][1]);
        acc[ri][2] = fdot2f(av.w, wv3.z, acc[ri][2]);
        acc[ri][3] = fdot2f(av.w, wv3.w, acc[ri][3]);
      }
    }
  } else {
    #pragma unroll 4
    for (int k4 = 0; k4 < KP / 4; ++k4) {
      float4 w[4], a[4];
      #pragma unroll
      for (int kk = 0; kk < 4; ++kk)
        w[kk] = *(const float4*)&Wsf[(k4 * 4 + kk) * 64 + c0];
      #pragma unroll
      for (int ri = 0; ri < 4; ++ri)
        a[ri] = *(const float4*)&insf[(lr0 + ri) * LSf + k4 * 4];
      #pragma unroll
      for (int ri = 0; ri < 4; ++ri) {
        const float* av = (const float*)&a[ri];
        #pragma unroll
        for (int kk = 0; kk < 4; ++kk) {
          acc[ri][0] = fmaf(av[kk], w[kk].x, acc[ri][0]);
          acc[ri][1] = fmaf(av[kk], w[kk].y, acc[ri][1]);
          acc[ri][2] = fmaf(av[kk], w[kk].z, acc[ri][2]);
          acc[ri][3] = fmaf(av[kk], w[kk].w, acc[ri][3]);
        }
      }
    }
  }

  if (!FUSE_A) {
    float4 bias = make_float4(0.f, 0.f, 0.f, 0.f);
    if (BIAS) bias = *(const float4*)&b[c0];
    #pragma unroll
    for (int ri = 0; ri < 4; ++ri) {
      const long r = b0 + lr0 + ri;
      if (r >= R) continue;
      float4 v;
      v.x = acc[ri][0] + bias.x; v.y = acc[ri][1] + bias.y;
      v.z = acc[ri][2] + bias.z; v.w = acc[ri][3] + bias.w;
      if (ACT == 1) {
        v.x = v.x >= 0.f ? v.x : 0.2f * v.x;  v.y = v.y >= 0.f ? v.y : 0.2f * v.y;
        v.z = v.z >= 0.f ? v.z : 0.2f * v.z;  v.w = v.w >= 0.f ? v.w : 0.2f * v.w;
      }
      if (sizeof(OT) == 4) {
        *(float4*)&out[r * 64 + c0] = v;
      } else {
        ushort4 u;
        u.x = f2h(v.x); u.y = f2h(v.y); u.z = f2h(v.z); u.w = f2h(v.w);
        *(ushort4*)&out[r * 64 + c0] = u;
      }
    }
  } else {
    // epilogue: ti/tj from prefetched P; tj -> out[e] (fp16), a1[e]; a1 stats
    float s1 = 0.f, s2 = 0.f;
    #pragma unroll
    for (int ri = 0; ri < 4; ++ri) {
      const long e = b0 + lr0 + ri;
      float part = 0.0f;
      if (e < R) {
        const float4 Pd = h4_to_f4(pdv[ri]);
        const float4 Ps = h4_to_f4(psv[ri]);
        float tj[4];
        const float ti0 = sp_f(Pd.x + acc[ri][0]);
        const float ti1 = sp_f(Pd.y + acc[ri][1]);
        const float ti2 = sp_f(Pd.z + acc[ri][2]);
        const float ti3 = sp_f(Pd.w + acc[ri][3]);
        tj[0] = sp_f(Ps.x + acc[ri][0]);
        tj[1] = sp_f(Ps.y + acc[ri][1]);
        tj[2] = sp_f(Ps.z + acc[ri][2]);
        tj[3] = sp_f(Ps.w + acc[ri][3]);
        ushort4 u;
        u.x = f2h(tj[0]); u.y = f2h(tj[1]); u.z = f2h(tj[2]); u.w = f2h(tj[3]);
        *(ushort4*)&out[e * 64 + c0] = u;
        part = ti0 * atts[c0] + ti1 * atts[c0 + 1] + ti2 * atts[c0 + 2] + ti3 * atts[c0 + 3]
             + tj[0] * atts[64 + c0] + tj[1] * atts[64 + c0 + 1]
             + tj[2] * atts[64 + c0 + 2] + tj[3] * atts[64 + c0 + 3];
      }
      #pragma unroll
      for (int off = 8; off; off >>= 1) part += __shfl_xor(part, off);
      if ((tx & 15) == 0 && e < R) {
        const float v = sp_f(part);
        a1[e] = v;
        s1 += v; s2 += v * v;
      }
    }
    s1 += __shfl_xor(s1, 16); s2 += __shfl_xor(s2, 16);
    s1 += __shfl_xor(s1, 32); s2 += __shfl_xor(s2, 32);
    if ((tx & 63) == 0) { ssum[tx >> 6] = s1; ssq[tx >> 6] = s2; }
    __syncthreads();
    if (tx == 0) {
      // 64-way banked: ~98 same-address atomics instead of 6250 (r11 lesson)
      const int bk = blockIdx.x & 63;
      atomicAdd(&stats[bk], ssum[0] + ssum[1] + ssum[2] + ssum[3]);
      atomicAdd(&stats[64 + bk], ssq[0] + ssq[1] + ssq[2] + ssq[3]);
    }
  }
}

// ---------- CSR build (once per launch; graph static across layers) --------
__global__ __launch_bounds__(256) void k_count(
    const int* __restrict__ dst, int* __restrict__ counts, int E)
{
  for (int i = blockIdx.x * 256 + threadIdx.x; i < E; i += gridDim.x * 256)
    atomicAdd(&counts[dst[i]], 1);
}

// single-block exclusive scan: offs[0..N-1] = exclusive prefix, offs[N] = E
__global__ __launch_bounds__(1024) void k_scan(
    const int* __restrict__ counts, int* __restrict__ offs, int N)
{
  __shared__ int part[1024];
  const int t = threadIdx.x;
  const int chunk = (N + 1023) >> 10;
  const int s0 = t * chunk;
  int sum = 0;
  for (int i = 0; i < chunk; ++i) {
    const int idx = s0 + i;
    if (idx < N) sum += counts[idx];
  }
  part[t] = sum;
  __syncthreads();
  for (int off = 1; off < 1024; off <<= 1) {
    const int v = (t >= off) ? part[t - off] : 0;
    __syncthreads();
    part[t] += v;
    __syncthreads();
  }
  int base = (t == 0) ? 0 : part[t - 1];
  for (int i = 0; i < chunk; ++i) {
    const int idx = s0 + i;
    if (idx < N) { offs[idx] = base; base += counts[idx]; }
  }
  if (N - 1 >= s0 && N - 1 < s0 + chunk) offs[N] = base;
}

// eids[CSR slot] = original edge id
__global__ __launch_bounds__(256) void k_fill(
    const int* __restrict__ dst, const int* __restrict__ offs,
    int* __restrict__ cursors, int* __restrict__ eids, int E)
{
  for (int i = blockIdx.x * 256 + threadIdx.x; i < E; i += gridDim.x * 256) {
    const int d = dst[i];
    eids[offs[d] + atomicAdd(&cursors[d], 1)] = i;
  }
}

// srcp/dstp in CSR order
__global__ __launch_bounds__(256) void k_permidx(
    const int* __restrict__ eids, const int* __restrict__ eidx,
    int* __restrict__ srcp, int* __restrict__ dstp, int E)
{
  for (int i = blockIdx.x * 256 + threadIdx.x; i < E; i += gridDim.x * 256) {
    const int e = eids[i];
    srcp[i] = eidx[e];
    dstp[i] = eidx[(long)E + e];
  }
}

// ---------- aggregate: sequential CSR reads, banked stats everywhere --------
__global__ __launch_bounds__(256) void k_aggregate(
    const int* __restrict__ offs, const float* __restrict__ a1p,
    const ushortt* __restrict__ Mp, const float* __restrict__ stats,
    float invE, float* __restrict__ aggn, float* __restrict__ cs, int N)
{
  __shared__ float sm_mean, sm_scl;
  const int tx = threadIdx.x;
  if (tx < 64) {   // reduce the 64 a1-stat banks (wave 0)
    float s1 = stats[tx];
    float s2 = stats[64 + tx];
    #pragma unroll
    for (int off = 32; off; off >>= 1) {
      s1 += __shfl_xor(s1, off);
      s2 += __shfl_xor(s2, off);
    }
    if (tx == 0) {
      const float mean = s1 * invE;
      sm_mean = mean;
      sm_scl = rsqrtf(s2 * invE - mean * mean + 1e-5f);
    }
  }
  __syncthreads();
  const float mean = sm_mean;
  const float scl = sm_scl;

  const int t = tx & 63;
  const int wid = tx >> 6;
  float s = 0.f, s2 = 0.f;
  const long step = (long)gridDim.x * 4;
  for (long n = (long)blockIdx.x * 4 + wid; n < N; n += step) {
    const int o0 = offs[n];
    const int o1 = offs[n + 1];
    float av = 0.f, sew = 0.f;
    #pragma unroll 4
    for (int i = o0; i < o1; ++i) {
      const float w = __expf(sp_f((a1p[i] - mean) * scl));
      av = fmaf(h2f(Mp[(long)i * 64 + t]), w, av);
      sew += w;
    }
    const float v = (o1 > o0) ? av / sew : 0.0f;
    aggn[n * 64 + t] = v;
    s += v; s2 += v * v;
  }
  __shared__ float b1[256], b2[256];
  b1[tx] = s; b2[tx] = s2;
  __syncthreads();
  if (tx < 64) {
    const int bank = (blockIdx.x & 15) * 128;   // 16 banks: ~128 atomics/addr
    atomicAdd(&cs[bank + t], b1[t] + b1[64 + t] + b1[128 + t] + b1[192 + t]);
    atomicAdd(&cs[bank + 64 + t], b2[t] + b2[64 + t] + b2[128 + t] + b2[192 + t]);
  }
}

// h = sp((aggn - mean_c) * rsqrt(var_c + eps)); cs has 16 banks of 128
__global__ __launch_bounds__(256) void k_hnew(
    const float* __restrict__ aggn, const float* __restrict__ cs,
    float invN, float* __restrict__ h, int N)
{
  const int c = threadIdx.x & 63;
  const int r = threadIdx.x >> 6;
  float mn = 0.f, sq = 0.f;
  #pragma unroll
  for (int bk = 0; bk < 16; ++bk) {
    mn += cs[bk * 128 + c];
    sq += cs[bk * 128 + 64 + c];
  }
  mn *= invN; sq *= invN;
  const float scl = rsqrtf(sq - mn * mn + 1e-5f);
  for (long n = (long)blockIdx.x * 4 + r; n < N; n += (long)gridDim.x * 4)
    h[n * 64 + c] = sp_f((aggn[n * 64 + c] - mn) * scl);
}

// composition attention score a[n] = sp(concat(h,gf)@Wc + bc) @ attW + attb
__global__ __launch_bounds__(256) void k_comp(
    const float* __restrict__ h, const float* __restrict__ gf,
    const int* __restrict__ batch, const float* __restrict__ Wc,
    const float* __restrict__ bc, const float* __restrict__ aw,
    const float* __restrict__ ab, float* __restrict__ aN, int N)
{
  __shared__ float Wcs[167 * 32];
  __shared__ float aws[32];
  __shared__ float bcs[32];
  for (int i = threadIdx.x; i < 167 * 32; i += 256) Wcs[i] = Wc[i];
  if (threadIdx.x < 32) { aws[threadIdx.x] = aw[threadIdx.x]; bcs[threadIdx.x] = bc[threadIdx.x]; }
  __syncthreads();
  const int t = threadIdx.x & 63;
  const int wid = threadIdx.x >> 6;
  const int col = t & 31;
  const float ab0 = ab[0];
  const int step = gridDim.x * 4;
  for (int n = blockIdx.x * 4 + wid; n < N; n += step) {
    const int g = batch[n];
    const float hq = h[(long)n * 64 + t];
    const float g1 = gf[(long)g * 103 + t];
    const float g2 = (t < 39) ? gf[(long)g * 103 + 64 + t] : 0.f;
    float acc = bcs[col];
    #pragma unroll 8
    for (int k = 0; k < 64; ++k) acc = fmaf(__shfl(hq, k), Wcs[k * 32 + col], acc);
    #pragma unroll 8
    for (int k = 0; k < 64; ++k) acc = fmaf(__shfl(g1, k), Wcs[(64 + k) * 32 + col], acc);
    #pragma unroll
    for (int k = 0; k < 39; ++k) acc = fmaf(__shfl(g2, k), Wcs[(128 + k) * 32 + col], acc);
    float val = sp_f(acc) * aws[col];
    #pragma unroll
    for (int off = 16; off; off >>= 1) val += __shfl_xor(val, off);
    if (t == 0) aN[n] = val + ab0;
  }
}

// one 64-thread block per graph: seg-softmax over sorted batch + pool + fc
__global__ __launch_bounds__(64) void k_pool(
    const float* __restrict__ h, const float* __restrict__ aN,
    const int* __restrict__ batch, const float* __restrict__ fcW,
    const float* __restrict__ fcb, float* __restrict__ out, int N, int G)
{
  const int g = blockIdx.x;
  const int t = threadIdx.x;
  int lo = 0, hi = N;
  while (lo < hi) { int mid = (lo + hi) >> 1; if (batch[mid] < g) lo = mid + 1; else hi = mid; }
  const int s = lo;
  hi = N;
  while (lo < hi) { int mid = (lo + hi) >> 1; if (batch[mid] < g + 1) lo = mid + 1; else hi = mid; }
  const int e2 = lo;
  if (s >= e2) { if (t == 0) out[g] = fcb[0]; return; }
  float mx = -1e30f;
  for (int i = s + t; i < e2; i += 64) mx = fmaxf(mx, aN[i]);
  #pragma unroll
  for (int off = 32; off; off >>= 1) mx = fmaxf(mx, __shfl_xor(mx, off));
  float se = 0.f;
  for (int i = s + t; i < e2; i += 64) se += __expf(aN[i] - mx);
  #pragma unroll
  for (int off = 32; off; off >>= 1) se += __shfl_xor(se, off);
  float acc = 0.f;
  for (int n = s; n < e2; ++n) {
    const float w = __expf(aN[n] - mx);
    acc = fmaf(h[(long)n * 64 + t], w, acc);
  }
  float part = (acc / se) * fcW[t];
  #pragma unroll
  for (int off = 32; off; off >>= 1) part += __shfl_xor(part, off);
  if (t == 0) out[g] = part + fcb[0];
}

extern "C" void kernel_launch(void* const* d_in, const int* in_sizes, int n_in,
                              void* d_out, int out_size, void* d_ws, size_t ws_size,
                              hipStream_t stream)
{
  const float* x     = (const float*)d_in[0];
  const int*   eidx  = (const int*)  d_in[1];
  const float* eattr = (const float*)d_in[2];
  const int*   batch = (const int*)  d_in[3];
  const float* gfeat = (const float*)d_in[4];
  const float* embnW = (const float*)d_in[5];
  const float* embnb = (const float*)d_in[6];
  const float* embeW = (const float*)d_in[7];
  const float* embeb = (const float*)d_in[8];
  const float* convW = (const float*)d_in[9];
  const float* convA = (const float*)d_in[10];
  // d_in[11] = conv_bias: cancels exactly in training-mode BatchNorm
  const float* compW = (const float*)d_in[12];
  const float* compb = (const float*)d_in[13];
  const float* attW  = (const float*)d_in[14];
  const float* attb  = (const float*)d_in[15];
  const float* fcW   = (const float*)d_in[16];
  const float* fcb   = (const float*)d_in[17];
  float* out = (float*)d_out;

  const int N = in_sizes[0] / 92;
  const int E = in_sizes[1] / 2;
  const int G = in_sizes[4] / 103;
  const float invN = 1.0f / (float)N;
  const float invE = 1.0f / (float)E;

  // workspace (~140 MB): fp32 node buffers, CSR ints, fp16 edge streams + P
  char* pw = (char*)d_ws;
  float* h     = (float*)pw;  pw += (size_t)N * 64 * 4;
  float* aggn  = (float*)pw;  pw += (size_t)N * 64 * 4;
  float* aE    = (float*)pw;  pw += (size_t)E * 4;        // a1 (CSR-ordered)
  float* statsB = (float*)pw; pw += 3 * SLOTS * 4;        // per-layer stat blocks
  float* aN    = (float*)pw;  pw += (size_t)N * 4;
  int* counts  = (int*)pw;    pw += (size_t)N * 4;        // counts+cursors: one memset
  int* cursors = (int*)pw;    pw += (size_t)N * 4;
  int* offs    = (int*)pw;    pw += ((size_t)N + 1) * 4;
  int* eids    = (int*)pw;    pw += (size_t)E * 4;
  int* srcp    = (int*)pw;    pw += (size_t)E * 4;
  int* dstp    = (int*)pw;    pw += (size_t)E * 4;
  pw = (char*)(((size_t)pw + 63) & ~(size_t)63);
  ushortt* Pp  = (ushortt*)pw; pw += (size_t)N * 64 * 2;  // P fp16
  ushortt* ea  = (ushortt*)pw; pw += (size_t)E * 64 * 2;  // fp16, CSR-ordered
  ushortt* M   = (ushortt*)pw;                            // fp16 tj, CSR-ordered

  const int gE64 = (E + 63) / 64;
  const int gN64 = (N + 63) / 64;

  // CSR build (dst = eidx[E..2E)), then index permutes
  hipMemsetAsync(counts, 0, 2 * (size_t)N * sizeof(int), stream);
  hipMemsetAsync(statsB, 0, 3 * SLOTS * sizeof(float), stream);
  k_count<<<2048, 256, 0, stream>>>(eidx + E, counts, E);
  k_scan<<<1, 1024, 0, stream>>>(counts, offs, N);
  k_fill<<<2048, 256, 0, stream>>>(eidx + E, offs, cursors, eids, E);
  k_permidx<<<2048, 256, 0, stream>>>(eids, eidx, srcp, dstp, E);

  k_gemm_rt<92, 0, 1, 0, 0, 0, 0, float, float><<<gN64, 256, 0, stream>>>(
      x, embnW, embnb, h, N, nullptr, nullptr, nullptr, nullptr, nullptr,
      nullptr, nullptr, nullptr, 0.f);
  // ea-embed: gather eattr rows by eids -> ea written CSR-ordered, coalesced
  k_gemm_rt<41, 1, 1, 0, 0, 1, 0, float, ushortt><<<gE64, 256, 0, stream>>>(
      eattr, embeW, embeb, ea, E, eids, nullptr, nullptr, nullptr, nullptr,
      nullptr, nullptr, nullptr, 0.f);

  for (int l = 0; l < 3; ++l) {
    const float* Wl = convW + (size_t)l * 128 * 64;
    const float* Al = convA + (size_t)l * 128;
    float* statsL = statsB + (size_t)l * SLOTS;
    if (l == 0) {
      k_gemm_rt<64, 0, 0, 0, 0, 0, 0, float, ushortt><<<gN64, 256, 0, stream>>>(
          h, Wl, nullptr, Pp, N, nullptr, nullptr, nullptr, nullptr, nullptr,
          nullptr, nullptr, nullptr, 0.f);
    } else {
      // staging reads aggn, applies BN+softplus inline (16-bank cs of layer l-1)
      k_gemm_rt<64, 0, 0, 0, 0, 0, 1, float, ushortt><<<gN64, 256, 0, stream>>>(
          aggn, Wl, nullptr, Pp, N, nullptr, nullptr, nullptr, nullptr, nullptr,
          nullptr, nullptr, statsB + (size_t)(l - 1) * SLOTS + 128, invN);
    }
    k_gemm_rt<64, 0, 0, 1, 1, 0, 0, ushortt, ushortt><<<gE64, 256, 0, stream>>>(
        ea, Wl + 64 * 64, nullptr, M, E, nullptr, Pp, srcp, dstp, Al, aE,
        statsL, nullptr, 0.f);
    k_aggregate<<<2048, 256, 0, stream>>>(offs, aE, M, statsL,
                                          invE, aggn, statsL + 128, N);
  }

  k_hnew<<<2048, 256, 0, stream>>>(aggn, statsB + 2 * SLOTS + 128, invN, h, N);
  k_comp<<<gN64, 256, 0, stream>>>(h, gfeat, batch, compW, compb, attW, attb, aN, N);
  k_pool<<<G, 64, 0, stream>>>(h, aN, batch, fcW, fcb, out, N, G);

  (void)n_in; (void)out_size; (void)ws_size;
}

// Round 16
// 621.994 us; speedup vs baseline: 3.0337x; 1.1843x over previous
//
#include <hip/hip_runtime.h>
#include <hip/hip_bf16.h>
#include <hip/hip_fp16.h>
#include <math.h>

// ---------------------------------------------------------------------------
// GATGNN forward. fp32 math; edge streams fp16, ALL CSR-ordered (~140 MB ws).
//   CSR build first: eids (CSR slot -> edge), srcp/dstp (CSR-ordered endpoints)
//   h = x@Wn + bn
//   ea = leaky_relu(eattr@We + be)   [gathered by eids -> CSR-ordered fp16]
//   per layer (edge streams sequential in CSR slot):
//     P = h@Wtop (fp16 out)   [layers 1,2: staging reads aggn and applies
//                              BN+softplus inline via 16-bank cs -> no hnew]
//     fused: M = ea@Wbot  [fp16 LDS + v_dot2_f32_f16, ROLLED k8 loop];
//            P rows prefetched pre-MAC; ti=sp(Pd+M), tj=sp(Ps+M); M<-tj;
//            a1=sp(dot att); a1 stats -> 64-WAY-BANKED atomics
//     aggregate: reduce stat banks once; per dst node sequential walk;
//            w=exp(sp(BN(a1))); aggn=(sum tj*w)/(sum w); col stats -> 16-bank cs
//   final h = sp(BN(aggn)); comp attention (LDS-tiled, 8-way ILP, no shfl
//   chain) + seg-softmax + pool + fc
// Lessons pinned:
//  - NEVER pass min-waves to __launch_bounds__ (r6/r7: VGPR cap -> GB spills).
//  - r9: FULL-UNROLL k8 loop hoisted reg tiles -> VGPR 144, occupancy 10%.
//  - r11/r15: same-address L2 atomic ~22ns SERIALIZED; r12-r14 fused GEMM was
//    floor-limited by 6250x2 atomics to stats[0..1] (~135us). Banking it
//    bought -300us. Keep per-address atomic count <= ~128 EVERYWHERE.
//  - r15 PMC: k_comp's 167-deep serial shfl+fma chain = 157us for 7us of
//    math. No serial cross-lane chains in hot loops.
// ---------------------------------------------------------------------------

typedef unsigned short ushortt;
typedef _Float16 half2v __attribute__((ext_vector_type(2)));

__device__ __forceinline__ float sp_f(float x) {
  return x > 20.0f ? x : __logf(1.0f + __expf(x));
}
__device__ __forceinline__ float h2f(ushortt u) {
  union { ushortt u; __half h; } c; c.u = u;
  return __half2float(c.h);
}
__device__ __forceinline__ ushortt f2h(float f) {
  union { __half h; ushortt u; } c; c.h = __float2half(f);
  return c.u;
}
__device__ __forceinline__ float4 h4_to_f4(ushort4 u) {
  return make_float4(h2f(u.x), h2f(u.y), h2f(u.z), h2f(u.w));
}
__device__ __forceinline__ unsigned pack2h(float a, float b) {
  union { _Float16 h[2]; unsigned u; } c;
  c.h[0] = (_Float16)a; c.h[1] = (_Float16)b;
  return c.u;
}
__device__ __forceinline__ float fdot2f(unsigned a, unsigned b, float c) {
  return __builtin_amdgcn_fdot2(__builtin_bit_cast(half2v, a),
                                __builtin_bit_cast(half2v, b), c, false);
}

// per-layer stats block layout (floats), stride SLOTS:
//   [0..63]    a1 sum banks      [64..127]  a1 sumsq banks
//   [128 .. 128+16*128)  col-stats cs, 16 banks x (64 sum + 64 sumsq)
#define SLOTS 2304

// Register-tiled GEMM: out[R,64] = act(in[rows?][K] @ W[K,64] (+ b))
// Block: 256 thr, tile 64 rows x 64 cols; thread: 4 rows x 4 cols.
// LH16: fp16 in; A-tile fp16 raw copy; W k-pair-packed half2; dot2 MACs,
//       ROLLED k8 loop.  else: fp32 LDS tiles.
// GATHER: staging reads rows[r].  FUSE_BN: staging input aggn (fp32), BN+sp
// applied inline; per-column mean/scl precomputed into LDS from 16-bank csbn.
// FUSE_A: P rows prefetched pre-MAC; epilogue writes tj (fp16) to out[e],
//         a1[e]; a1 sum/sumsq -> 64-way banked atomics in stats[0..127].
template<int K, int ACT, int BIAS, int FUSE_A, int LH16, int GATHER, int FUSE_BN,
         typename IT, typename OT>
__global__ __launch_bounds__(256) void k_gemm_rt(
    const IT* __restrict__ in, const float* __restrict__ W,
    const float* __restrict__ b, OT* __restrict__ out, int R,
    const int* __restrict__ rows, const ushortt* __restrict__ P,
    const int* __restrict__ srcp, const int* __restrict__ dstp,
    const float* __restrict__ catt, float* __restrict__ a1,
    float* __restrict__ stats, const float* __restrict__ csbn, float invN)
{
  constexpr int KP  = (K + 3) / 4 * 4;       // fp32 path: k padded to x4
  constexpr int LSf = KP + 4;                // fp32 ins stride (floats)
  constexpr int LSb = K + 8;                 // fp16 ins stride (shorts)
  constexpr size_t INS_B = LH16 ? (size_t)64 * LSb * 2 : (size_t)64 * LSf * 4;
  constexpr size_t WS_B  = LH16 ? (size_t)(K / 2) * 64 * 4 : (size_t)KP * 64 * 4;
  __shared__ __align__(16) unsigned char smem[INS_B + WS_B];
  __shared__ float atts[128];
  __shared__ float ssum[4], ssq[4];
  __shared__ float bnm[64], bns[64];
  ushortt*  insb = (ushortt*)smem;
  unsigned* Wp   = (unsigned*)(smem + INS_B);   // LH16: [K/2][64] half2-packed
  float*    insf = (float*)smem;
  float*    Wsf  = (float*)(smem + INS_B);

  const int tx = threadIdx.x;
  const int b0 = blockIdx.x * 64;

  if (FUSE_BN) {
    if (tx < 64) {
      float mn = 0.f, sq = 0.f;
      #pragma unroll
      for (int bk = 0; bk < 16; ++bk) {
        mn += csbn[bk * 128 + tx];
        sq += csbn[bk * 128 + 64 + tx];
      }
      mn *= invN; sq *= invN;
      bnm[tx] = mn;
      bns[tx] = rsqrtf(sq - mn * mn + 1e-5f);
    }
    __syncthreads();
  }

  if (LH16) {
    static_assert(!LH16 || (K % 8 == 0), "fp16 path needs K%8==0");
    for (int i = tx; i < (K / 2) * 64; i += 256) {
      const int k2 = i >> 6;
      const int c = i & 63;
      Wp[i] = pack2h(W[(2 * k2) * 64 + c], W[(2 * k2 + 1) * 64 + c]);
    }
    for (int i = tx; i < 64 * (K / 8); i += 256) {
      const int row = i / (K / 8);
      const int k8 = i % (K / 8);
      long r = b0 + row; if (r >= R) r = R - 1;   // clamp: values unused
      if (GATHER) r = rows[r];
      *(uint4*)&insb[row * LSb + k8 * 8] =
          *(const uint4*)&((const ushortt*)in)[r * (long)K + k8 * 8];
    }
  } else {
    for (int i = tx; i < KP * 64; i += 256) {
      const int k = i >> 6;
      Wsf[i] = (k < K) ? W[i] : 0.0f;
    }
    for (int i = tx; i < 64 * (KP / 4); i += 256) {
      const int row = i / (KP / 4);
      const int k4 = i % (KP / 4);
      long r = b0 + row; if (r >= R) r = R - 1;   // clamp: values unused
      if (GATHER) r = rows[r];
      float4 v;
      if (K % 4 == 0) {
        v = *(const float4*)&((const float*)in)[r * (long)K + k4 * 4];
      } else {
        float t[4];
        #pragma unroll
        for (int j = 0; j < 4; ++j) {
          const int k = k4 * 4 + j;
          t[j] = (k < K) ? ((const float*)in)[r * (long)K + k] : 0.0f;
        }
        v = make_float4(t[0], t[1], t[2], t[3]);
      }
      if (FUSE_BN) {
        float* vv = (float*)&v;
        #pragma unroll
        for (int j = 0; j < 4; ++j) {
          const int c = k4 * 4 + j;
          vv[j] = sp_f((vv[j] - bnm[c]) * bns[c]);
        }
      }
      *(float4*)&insf[row * LSf + k4 * 4] = v;
    }
  }
  if (FUSE_A) { if (tx < 128) atts[tx] = catt[tx]; }
  __syncthreads();

  const int lr0 = ((tx >> 6) << 4) + (((tx >> 4) & 3) << 2);  // local row base
  const int c0 = (tx & 15) << 2;                               // col base

  // FUSE_A: prefetch P rows NOW -- latency hides under the MAC loop.
  ushort4 pdv[4], psv[4];
  if (FUSE_A) {
    #pragma unroll
    for (int ri = 0; ri < 4; ++ri) {
      long e = b0 + lr0 + ri; if (e >= R) e = R - 1;   // clamp: values unused
      const int s = srcp[e];
      const int d = dstp[e];
      psv[ri] = *(const ushort4*)&P[(long)s * 64 + c0];
      pdv[ri] = *(const ushort4*)&P[(long)d * 64 + c0];
    }
  }

  float acc[4][4];
  #pragma unroll
  for (int i = 0; i < 4; ++i)
    #pragma unroll
    for (int j = 0; j < 4; ++j) acc[i][j] = 0.0f;

  if (LH16) {
    // ROLLED k8 loop: wv loaded once/iter, av per-ri, consumed at once.
    #pragma unroll 1
    for (int k8 = 0; k8 < K / 8; ++k8) {
      const uint4 wv0 = *(const uint4*)&Wp[(k8 * 4 + 0) * 64 + c0];
      const uint4 wv1 = *(const uint4*)&Wp[(k8 * 4 + 1) * 64 + c0];
      const uint4 wv2 = *(const uint4*)&Wp[(k8 * 4 + 2) * 64 + c0];
      const uint4 wv3 = *(const uint4*)&Wp[(k8 * 4 + 3) * 64 + c0];
      #pragma unroll
      for (int ri = 0; ri < 4; ++ri) {
        const uint4 av = *(const uint4*)&insb[(lr0 + ri) * LSb + k8 * 8];
        acc[ri][0] = fdot2f(av.x, wv0.x, acc[ri][0]);
        acc[ri][1] = fdot2f(av.x, wv0.y, acc[ri][1]);
        acc[ri][2] = fdot2f(av.x, wv0.z, acc[ri][2]);
        acc[ri][3] = fdot2f(av.x, wv0.w, acc[ri][3]);
        acc[ri][0] = fdot2f(av.y, wv1.x, acc[ri][0]);
        acc[ri][1] = fdot2f(av.y, wv1.y, acc[ri][1]);
        acc[ri][2] = fdot2f(av.y, wv1.z, acc[ri][2]);
        acc[ri][3] = fdot2f(av.y, wv1.w, acc[ri][3]);
        acc[ri][0] = fdot2f(av.z, wv2.x, acc[ri][0]);
        acc[ri][1] = fdot2f(av.z, wv2.y, acc[ri][1]);
        acc[ri][2] = fdot2f(av.z, wv2.z, acc[ri][2]);
        acc[ri][3] = fdot2f(av.z, wv2.w, acc[ri][3]);
        acc[ri][0] = fdot2f(av.w, wv3.x, acc[ri][0]);
        acc[ri][1] = fdot2f(av.w, wv3.y, acc[ri][1]);
        acc[ri][2] = fdot2f(av.w, wv3.z, acc[ri][2]);
        acc[ri][3] = fdot2f(av.w, wv3.w, acc[ri][3]);
      }
    }
  } else {
    #pragma unroll 4
    for (int k4 = 0; k4 < KP / 4; ++k4) {
      float4 w[4], a[4];
      #pragma unroll
      for (int kk = 0; kk < 4; ++kk)
        w[kk] = *(const float4*)&Wsf[(k4 * 4 + kk) * 64 + c0];
      #pragma unroll
      for (int ri = 0; ri < 4; ++ri)
        a[ri] = *(const float4*)&insf[(lr0 + ri) * LSf + k4 * 4];
      #pragma unroll
      for (int ri = 0; ri < 4; ++ri) {
        const float* av = (const float*)&a[ri];
        #pragma unroll
        for (int kk = 0; kk < 4; ++kk) {
          acc[ri][0] = fmaf(av[kk], w[kk].x, acc[ri][0]);
          acc[ri][1] = fmaf(av[kk], w[kk].y, acc[ri][1]);
          acc[ri][2] = fmaf(av[kk], w[kk].z, acc[ri][2]);
          acc[ri][3] = fmaf(av[kk], w[kk].w, acc[ri][3]);
        }
      }
    }
  }

  if (!FUSE_A) {
    float4 bias = make_float4(0.f, 0.f, 0.f, 0.f);
    if (BIAS) bias = *(const float4*)&b[c0];
    #pragma unroll
    for (int ri = 0; ri < 4; ++ri) {
      const long r = b0 + lr0 + ri;
      if (r >= R) continue;
      float4 v;
      v.x = acc[ri][0] + bias.x; v.y = acc[ri][1] + bias.y;
      v.z = acc[ri][2] + bias.z; v.w = acc[ri][3] + bias.w;
      if (ACT == 1) {
        v.x = v.x >= 0.f ? v.x : 0.2f * v.x;  v.y = v.y >= 0.f ? v.y : 0.2f * v.y;
        v.z = v.z >= 0.f ? v.z : 0.2f * v.z;  v.w = v.w >= 0.f ? v.w : 0.2f * v.w;
      }
      if (sizeof(OT) == 4) {
        *(float4*)&out[r * 64 + c0] = v;
      } else {
        ushort4 u;
        u.x = f2h(v.x); u.y = f2h(v.y); u.z = f2h(v.z); u.w = f2h(v.w);
        *(ushort4*)&out[r * 64 + c0] = u;
      }
    }
  } else {
    // epilogue: ti/tj from prefetched P; tj -> out[e] (fp16), a1[e]; a1 stats
    float s1 = 0.f, s2 = 0.f;
    #pragma unroll
    for (int ri = 0; ri < 4; ++ri) {
      const long e = b0 + lr0 + ri;
      float part = 0.0f;
      if (e < R) {
        const float4 Pd = h4_to_f4(pdv[ri]);
        const float4 Ps = h4_to_f4(psv[ri]);
        float tj[4];
        const float ti0 = sp_f(Pd.x + acc[ri][0]);
        const float ti1 = sp_f(Pd.y + acc[ri][1]);
        const float ti2 = sp_f(Pd.z + acc[ri][2]);
        const float ti3 = sp_f(Pd.w + acc[ri][3]);
        tj[0] = sp_f(Ps.x + acc[ri][0]);
        tj[1] = sp_f(Ps.y + acc[ri][1]);
        tj[2] = sp_f(Ps.z + acc[ri][2]);
        tj[3] = sp_f(Ps.w + acc[ri][3]);
        ushort4 u;
        u.x = f2h(tj[0]); u.y = f2h(tj[1]); u.z = f2h(tj[2]); u.w = f2h(tj[3]);
        *(ushort4*)&out[e * 64 + c0] = u;
        part = ti0 * atts[c0] + ti1 * atts[c0 + 1] + ti2 * atts[c0 + 2] + ti3 * atts[c0 + 3]
             + tj[0] * atts[64 + c0] + tj[1] * atts[64 + c0 + 1]
             + tj[2] * atts[64 + c0 + 2] + tj[3] * atts[64 + c0 + 3];
      }
      #pragma unroll
      for (int off = 8; off; off >>= 1) part += __shfl_xor(part, off);
      if ((tx & 15) == 0 && e < R) {
        const float v = sp_f(part);
        a1[e] = v;
        s1 += v; s2 += v * v;
      }
    }
    s1 += __shfl_xor(s1, 16); s2 += __shfl_xor(s2, 16);
    s1 += __shfl_xor(s1, 32); s2 += __shfl_xor(s2, 32);
    if ((tx & 63) == 0) { ssum[tx >> 6] = s1; ssq[tx >> 6] = s2; }
    __syncthreads();
    if (tx == 0) {
      // 64-way banked: ~98 same-address atomics instead of 6250 (r11 lesson)
      const int bk = blockIdx.x & 63;
      atomicAdd(&stats[bk], ssum[0] + ssum[1] + ssum[2] + ssum[3]);
      atomicAdd(&stats[64 + bk], ssq[0] + ssq[1] + ssq[2] + ssq[3]);
    }
  }
}

// ---------- CSR build (once per launch; graph static across layers) --------
__global__ __launch_bounds__(256) void k_count(
    const int* __restrict__ dst, int* __restrict__ counts, int E)
{
  for (int i = blockIdx.x * 256 + threadIdx.x; i < E; i += gridDim.x * 256)
    atomicAdd(&counts[dst[i]], 1);
}

// single-block exclusive scan: offs[0..N-1] = exclusive prefix, offs[N] = E
__global__ __launch_bounds__(1024) void k_scan(
    const int* __restrict__ counts, int* __restrict__ offs, int N)
{
  __shared__ int part[1024];
  const int t = threadIdx.x;
  const int chunk = (N + 1023) >> 10;
  const int s0 = t * chunk;
  int sum = 0;
  for (int i = 0; i < chunk; ++i) {
    const int idx = s0 + i;
    if (idx < N) sum += counts[idx];
  }
  part[t] = sum;
  __syncthreads();
  for (int off = 1; off < 1024; off <<= 1) {
    const int v = (t >= off) ? part[t - off] : 0;
    __syncthreads();
    part[t] += v;
    __syncthreads();
  }
  int base = (t == 0) ? 0 : part[t - 1];
  for (int i = 0; i < chunk; ++i) {
    const int idx = s0 + i;
    if (idx < N) { offs[idx] = base; base += counts[idx]; }
  }
  if (N - 1 >= s0 && N - 1 < s0 + chunk) offs[N] = base;
}

// eids[CSR slot] = original edge id
__global__ __launch_bounds__(256) void k_fill(
    const int* __restrict__ dst, const int* __restrict__ offs,
    int* __restrict__ cursors, int* __restrict__ eids, int E)
{
  for (int i = blockIdx.x * 256 + threadIdx.x; i < E; i += gridDim.x * 256) {
    const int d = dst[i];
    eids[offs[d] + atomicAdd(&cursors[d], 1)] = i;
  }
}

// srcp/dstp in CSR order
__global__ __launch_bounds__(256) void k_permidx(
    const int* __restrict__ eids, const int* __restrict__ eidx,
    int* __restrict__ srcp, int* __restrict__ dstp, int E)
{
  for (int i = blockIdx.x * 256 + threadIdx.x; i < E; i += gridDim.x * 256) {
    const int e = eids[i];
    srcp[i] = eidx[e];
    dstp[i] = eidx[(long)E + e];
  }
}

// ---------- aggregate: sequential CSR reads, banked stats everywhere --------
__global__ __launch_bounds__(256) void k_aggregate(
    const int* __restrict__ offs, const float* __restrict__ a1p,
    const ushortt* __restrict__ Mp, const float* __restrict__ stats,
    float invE, float* __restrict__ aggn, float* __restrict__ cs, int N)
{
  __shared__ float sm_mean, sm_scl;
  const int tx = threadIdx.x;
  if (tx < 64) {   // reduce the 64 a1-stat banks (wave 0)
    float s1 = stats[tx];
    float s2 = stats[64 + tx];
    #pragma unroll
    for (int off = 32; off; off >>= 1) {
      s1 += __shfl_xor(s1, off);
      s2 += __shfl_xor(s2, off);
    }
    if (tx == 0) {
      const float mean = s1 * invE;
      sm_mean = mean;
      sm_scl = rsqrtf(s2 * invE - mean * mean + 1e-5f);
    }
  }
  __syncthreads();
  const float mean = sm_mean;
  const float scl = sm_scl;

  const int t = tx & 63;
  const int wid = tx >> 6;
  float s = 0.f, s2 = 0.f;
  const long step = (long)gridDim.x * 4;
  for (long n = (long)blockIdx.x * 4 + wid; n < N; n += step) {
    const int o0 = offs[n];
    const int o1 = offs[n + 1];
    float av = 0.f, sew = 0.f;
    #pragma unroll 4
    for (int i = o0; i < o1; ++i) {
      const float w = __expf(sp_f((a1p[i] - mean) * scl));
      av = fmaf(h2f(Mp[(long)i * 64 + t]), w, av);
      sew += w;
    }
    const float v = (o1 > o0) ? av / sew : 0.0f;
    aggn[n * 64 + t] = v;
    s += v; s2 += v * v;
  }
  __shared__ float b1[256], b2[256];
  b1[tx] = s; b2[tx] = s2;
  __syncthreads();
  if (tx < 64) {
    const int bank = (blockIdx.x & 15) * 128;   // 16 banks: ~128 atomics/addr
    atomicAdd(&cs[bank + t], b1[t] + b1[64 + t] + b1[128 + t] + b1[192 + t]);
    atomicAdd(&cs[bank + 64 + t], b2[t] + b2[64 + t] + b2[128 + t] + b2[192 + t]);
  }
}

// h = sp((aggn - mean_c) * rsqrt(var_c + eps)); cs has 16 banks of 128
__global__ __launch_bounds__(256) void k_hnew(
    const float* __restrict__ aggn, const float* __restrict__ cs,
    float invN, float* __restrict__ h, int N)
{
  const int c = threadIdx.x & 63;
  const int r = threadIdx.x >> 6;
  float mn = 0.f, sq = 0.f;
  #pragma unroll
  for (int bk = 0; bk < 16; ++bk) {
    mn += cs[bk * 128 + c];
    sq += cs[bk * 128 + 64 + c];
  }
  mn *= invN; sq *= invN;
  const float scl = rsqrtf(sq - mn * mn + 1e-5f);
  for (long n = (long)blockIdx.x * 4 + r; n < N; n += (long)gridDim.x * 4)
    h[n * 64 + c] = sp_f((aggn[n * 64 + c] - mn) * scl);
}

// composition attention: per block, 64-node tile, LDS-staged q + Wc.
// q[n] = concat(h[n] (64), gf[batch[n]] (103)); z = q@Wc (32 cols);
// aN[n] = sum_col sp(z+bc)*aw + ab.
// Thread: node = tx>>2, colg = (tx&3)*8 -> 8 cols, acc[8] independent chains.
// No serial cross-lane chain (r15 lesson).
#define QSS 170   // q LDS stride (floats): 16 nodes/wave -> 16 distinct banks
__global__ __launch_bounds__(256) void k_comp(
    const float* __restrict__ h, const float* __restrict__ gf,
    const int* __restrict__ batch, const float* __restrict__ Wc,
    const float* __restrict__ bc, const float* __restrict__ aw,
    const float* __restrict__ ab, float* __restrict__ aN, int N)
{
  __shared__ __align__(16) float qs[64 * QSS];
  __shared__ __align__(16) float Wcs[167 * 32];
  __shared__ float aws[32], bcs[32];
  const int tx = threadIdx.x;
  const int b0 = blockIdx.x * 64;
  for (int i = tx; i < 167 * 32; i += 256) Wcs[i] = Wc[i];
  if (tx < 32) { aws[tx] = aw[tx]; bcs[tx] = bc[tx]; }
  // stage h rows (float4, coalesced)
  for (int i = tx; i < 64 * 16; i += 256) {
    const int n = i >> 4;
    const int c4 = (i & 15) << 2;
    long r = b0 + n; if (r >= N) r = N - 1;   // clamp: values unused
    *(float4*)&qs[n * QSS + c4] = *(const float4*)&h[r * 64 + c4];
  }
  // stage gf rows (scalar; 103 per node)
  for (int i = tx; i < 64 * 103; i += 256) {
    const int n = i / 103;
    const int c = i % 103;
    long r = b0 + n; if (r >= N) r = N - 1;
    qs[n * QSS + 64 + c] = gf[(long)batch[r] * 103 + c];
  }
  __syncthreads();

  const int n = tx >> 2;
  const int colg = (tx & 3) << 3;
  float acc[8];
  #pragma unroll
  for (int j = 0; j < 8; ++j) acc[j] = 0.f;
  #pragma unroll 2
  for (int k = 0; k < 167; ++k) {
    const float q = qs[n * QSS + k];
    const float4 w0 = *(const float4*)&Wcs[k * 32 + colg];
    const float4 w1 = *(const float4*)&Wcs[k * 32 + colg + 4];
    acc[0] = fmaf(q, w0.x, acc[0]);
    acc[1] = fmaf(q, w0.y, acc[1]);
    acc[2] = fmaf(q, w0.z, acc[2]);
    acc[3] = fmaf(q, w0.w, acc[3]);
    acc[4] = fmaf(q, w1.x, acc[4]);
    acc[5] = fmaf(q, w1.y, acc[5]);
    acc[6] = fmaf(q, w1.z, acc[6]);
    acc[7] = fmaf(q, w1.w, acc[7]);
  }
  float val = 0.f;
  #pragma unroll
  for (int j = 0; j < 8; ++j)
    val += sp_f(acc[j] + bcs[colg + j]) * aws[colg + j];
  val += __shfl_xor(val, 1);
  val += __shfl_xor(val, 2);
  const long r = b0 + n;
  if ((tx & 3) == 0 && r < N) aN[r] = val + ab[0];
}

// one 64-thread block per graph: seg-softmax over sorted batch + pool + fc
__global__ __launch_bounds__(64) void k_pool(
    const float* __restrict__ h, const float* __restrict__ aN,
    const int* __restrict__ batch, const float* __restrict__ fcW,
    const float* __restrict__ fcb, float* __restrict__ out, int N, int G)
{
  const int g = blockIdx.x;
  const int t = threadIdx.x;
  int lo = 0, hi = N;
  while (lo < hi) { int mid = (lo + hi) >> 1; if (batch[mid] < g) lo = mid + 1; else hi = mid; }
  const int s = lo;
  hi = N;
  while (lo < hi) { int mid = (lo + hi) >> 1; if (batch[mid] < g + 1) lo = mid + 1; else hi = mid; }
  const int e2 = lo;
  if (s >= e2) { if (t == 0) out[g] = fcb[0]; return; }
  float mx = -1e30f;
  for (int i = s + t; i < e2; i += 64) mx = fmaxf(mx, aN[i]);
  #pragma unroll
  for (int off = 32; off; off >>= 1) mx = fmaxf(mx, __shfl_xor(mx, off));
  float se = 0.f;
  for (int i = s + t; i < e2; i += 64) se += __expf(aN[i] - mx);
  #pragma unroll
  for (int off = 32; off; off >>= 1) se += __shfl_xor(se, off);
  float acc = 0.f;
  for (int n = s; n < e2; ++n) {
    const float w = __expf(aN[n] - mx);
    acc = fmaf(h[(long)n * 64 + t], w, acc);
  }
  float part = (acc / se) * fcW[t];
  #pragma unroll
  for (int off = 32; off; off >>= 1) part += __shfl_xor(part, off);
  if (t == 0) out[g] = part + fcb[0];
}

extern "C" void kernel_launch(void* const* d_in, const int* in_sizes, int n_in,
                              void* d_out, int out_size, void* d_ws, size_t ws_size,
                              hipStream_t stream)
{
  const float* x     = (const float*)d_in[0];
  const int*   eidx  = (const int*)  d_in[1];
  const float* eattr = (const float*)d_in[2];
  const int*   batch = (const int*)  d_in[3];
  const float* gfeat = (const float*)d_in[4];
  const float* embnW = (const float*)d_in[5];
  const float* embnb = (const float*)d_in[6];
  const float* embeW = (const float*)d_in[7];
  const float* embeb = (const float*)d_in[8];
  const float* convW = (const float*)d_in[9];
  const float* convA = (const float*)d_in[10];
  // d_in[11] = conv_bias: cancels exactly in training-mode BatchNorm
  const float* compW = (const float*)d_in[12];
  const float* compb = (const float*)d_in[13];
  const float* attW  = (const float*)d_in[14];
  const float* attb  = (const float*)d_in[15];
  const float* fcW   = (const float*)d_in[16];
  const float* fcb   = (const float*)d_in[17];
  float* out = (float*)d_out;

  const int N = in_sizes[0] / 92;
  const int E = in_sizes[1] / 2;
  const int G = in_sizes[4] / 103;
  const float invN = 1.0f / (float)N;
  const float invE = 1.0f / (float)E;

  // workspace (~140 MB): fp32 node buffers, CSR ints, fp16 edge streams + P
  char* pw = (char*)d_ws;
  float* h     = (float*)pw;  pw += (size_t)N * 64 * 4;
  float* aggn  = (float*)pw;  pw += (size_t)N * 64 * 4;
  float* aE    = (float*)pw;  pw += (size_t)E * 4;        // a1 (CSR-ordered)
  float* statsB = (float*)pw; pw += 3 * SLOTS * 4;        // per-layer stat blocks
  float* aN    = (float*)pw;  pw += (size_t)N * 4;
  int* counts  = (int*)pw;    pw += (size_t)N * 4;        // counts+cursors: one memset
  int* cursors = (int*)pw;    pw += (size_t)N * 4;
  int* offs    = (int*)pw;    pw += ((size_t)N + 1) * 4;
  int* eids    = (int*)pw;    pw += (size_t)E * 4;
  int* srcp    = (int*)pw;    pw += (size_t)E * 4;
  int* dstp    = (int*)pw;    pw += (size_t)E * 4;
  pw = (char*)(((size_t)pw + 63) & ~(size_t)63);
  ushortt* Pp  = (ushortt*)pw; pw += (size_t)N * 64 * 2;  // P fp16
  ushortt* ea  = (ushortt*)pw; pw += (size_t)E * 64 * 2;  // fp16, CSR-ordered
  ushortt* M   = (ushortt*)pw;                            // fp16 tj, CSR-ordered

  const int gE64 = (E + 63) / 64;
  const int gN64 = (N + 63) / 64;

  // CSR build (dst = eidx[E..2E)), then index permutes
  hipMemsetAsync(counts, 0, 2 * (size_t)N * sizeof(int), stream);
  hipMemsetAsync(statsB, 0, 3 * SLOTS * sizeof(float), stream);
  k_count<<<2048, 256, 0, stream>>>(eidx + E, counts, E);
  k_scan<<<1, 1024, 0, stream>>>(counts, offs, N);
  k_fill<<<2048, 256, 0, stream>>>(eidx + E, offs, cursors, eids, E);
  k_permidx<<<2048, 256, 0, stream>>>(eids, eidx, srcp, dstp, E);

  k_gemm_rt<92, 0, 1, 0, 0, 0, 0, float, float><<<gN64, 256, 0, stream>>>(
      x, embnW, embnb, h, N, nullptr, nullptr, nullptr, nullptr, nullptr,
      nullptr, nullptr, nullptr, 0.f);
  // ea-embed: gather eattr rows by eids -> ea written CSR-ordered, coalesced
  k_gemm_rt<41, 1, 1, 0, 0, 1, 0, float, ushortt><<<gE64, 256, 0, stream>>>(
      eattr, embeW, embeb, ea, E, eids, nullptr, nullptr, nullptr, nullptr,
      nullptr, nullptr, nullptr, 0.f);

  for (int l = 0; l < 3; ++l) {
    const float* Wl = convW + (size_t)l * 128 * 64;
    const float* Al = convA + (size_t)l * 128;
    float* statsL = statsB + (size_t)l * SLOTS;
    if (l == 0) {
      k_gemm_rt<64, 0, 0, 0, 0, 0, 0, float, ushortt><<<gN64, 256, 0, stream>>>(
          h, Wl, nullptr, Pp, N, nullptr, nullptr, nullptr, nullptr, nullptr,
          nullptr, nullptr, nullptr, 0.f);
    } else {
      // staging reads aggn, applies BN+softplus inline (16-bank cs of layer l-1)
      k_gemm_rt<64, 0, 0, 0, 0, 0, 1, float, ushortt><<<gN64, 256, 0, stream>>>(
          aggn, Wl, nullptr, Pp, N, nullptr, nullptr, nullptr, nullptr, nullptr,
          nullptr, nullptr, statsB + (size_t)(l - 1) * SLOTS + 128, invN);
    }
    k_gemm_rt<64, 0, 0, 1, 1, 0, 0, ushortt, ushortt><<<gE64, 256, 0, stream>>>(
        ea, Wl + 64 * 64, nullptr, M, E, nullptr, Pp, srcp, dstp, Al, aE,
        statsL, nullptr, 0.f);
    k_aggregate<<<2048, 256, 0, stream>>>(offs, aE, M, statsL,
                                          invE, aggn, statsL + 128, N);
  }

  k_hnew<<<2048, 256, 0, stream>>>(aggn, statsB + 2 * SLOTS + 128, invN, h, N);
  k_comp<<<gN64, 256, 0, stream>>>(h, gfeat, batch, compW, compb, attW, attb, aN, N);
  k_pool<<<G, 64, 0, stream>>>(h, aN, batch, fcW, fcb, out, N, G);

  (void)n_in; (void)out_size; (void)ws_size;
}

// Round 17
// 541.104 us; speedup vs baseline: 3.4872x; 1.1495x over previous
//
#include <hip/hip_runtime.h>
#include <hip/hip_bf16.h>
#include <hip/hip_fp16.h>
#include <math.h>

// ---------------------------------------------------------------------------
// GATGNN forward. fp32 math; edge streams fp16, ALL CSR-ordered (~140 MB ws).
//   CSR build first: eids (CSR slot -> edge), srcp/dstp (CSR-ordered endpoints)
//   h = x@Wn + bn
//   ea = leaky_relu(eattr@We + be)   [gathered by eids -> CSR-ordered fp16]
//   per layer (edge streams sequential in CSR slot):
//     P = h@Wtop (fp16 out)   [layers 1,2: staging reads aggn and applies
//                              BN+softplus inline via 16-bank cs -> no hnew]
//     fused: M = ea@Wbot  [fp16 LDS + v_dot2_f32_f16, ROLLED k8 loop];
//            P rows prefetched pre-MAC; ti=sp(Pd+M), tj=sp(Ps+M); M<-tj;
//            a1=sp(dot att); a1 stats -> 64-WAY-BANKED atomics
//     aggregate: reduce stat banks once; per dst node sequential walk;
//            w=exp(sp(BN(a1))); aggn=(sum tj*w)/(sum w); col stats -> 16-bank cs
//   final h = sp(BN(aggn)); comp attention (LDS-tiled, 8-way ILP) + pool + fc
// Lessons pinned:
//  - NEVER pass min-waves to __launch_bounds__ (r6/r7: VGPR cap -> GB spills).
//  - r9: FULL-UNROLL k8 loop hoisted reg tiles -> VGPR 144, occupancy 10%.
//  - r11/r15: same-address L2 atomic ~22ns SERIALIZED; keep per-address
//    atomic count <= ~128 EVERYWHERE (banking bought -300us).
//  - r15: no serial cross-lane chains in hot loops (k_comp 157us -> 30us).
//  - r16 PMC: single-block k_scan = 92us Amdahl tail -> hierarchical scan.
// ---------------------------------------------------------------------------

typedef unsigned short ushortt;
typedef _Float16 half2v __attribute__((ext_vector_type(2)));

__device__ __forceinline__ float sp_f(float x) {
  return x > 20.0f ? x : __logf(1.0f + __expf(x));
}
__device__ __forceinline__ float h2f(ushortt u) {
  union { ushortt u; __half h; } c; c.u = u;
  return __half2float(c.h);
}
__device__ __forceinline__ ushortt f2h(float f) {
  union { __half h; ushortt u; } c; c.h = __float2half(f);
  return c.u;
}
__device__ __forceinline__ float4 h4_to_f4(ushort4 u) {
  return make_float4(h2f(u.x), h2f(u.y), h2f(u.z), h2f(u.w));
}
__device__ __forceinline__ unsigned pack2h(float a, float b) {
  union { _Float16 h[2]; unsigned u; } c;
  c.h[0] = (_Float16)a; c.h[1] = (_Float16)b;
  return c.u;
}
__device__ __forceinline__ float fdot2f(unsigned a, unsigned b, float c) {
  return __builtin_amdgcn_fdot2(__builtin_bit_cast(half2v, a),
                                __builtin_bit_cast(half2v, b), c, false);
}

// per-layer stats block layout (floats), stride SLOTS:
//   [0..63]    a1 sum banks      [64..127]  a1 sumsq banks
//   [128 .. 128+16*128)  col-stats cs, 16 banks x (64 sum + 64 sumsq)
#define SLOTS 2304

// Register-tiled GEMM: out[R,64] = act(in[rows?][K] @ W[K,64] (+ b))
// Block: 256 thr, tile 64 rows x 64 cols; thread: 4 rows x 4 cols.
// LH16: fp16 in; A-tile fp16 raw copy; W k-pair-packed half2; dot2 MACs,
//       ROLLED k8 loop.  else: fp32 LDS tiles.
// GATHER: staging reads rows[r].  FUSE_BN: staging input aggn (fp32), BN+sp
// applied inline; per-column mean/scl precomputed into LDS from 16-bank csbn.
// FUSE_A: P rows prefetched pre-MAC; epilogue writes tj (fp16) to out[e],
//         a1[e]; a1 sum/sumsq -> 64-way banked atomics in stats[0..127].
template<int K, int ACT, int BIAS, int FUSE_A, int LH16, int GATHER, int FUSE_BN,
         typename IT, typename OT>
__global__ __launch_bounds__(256) void k_gemm_rt(
    const IT* __restrict__ in, const float* __restrict__ W,
    const float* __restrict__ b, OT* __restrict__ out, int R,
    const int* __restrict__ rows, const ushortt* __restrict__ P,
    const int* __restrict__ srcp, const int* __restrict__ dstp,
    const float* __restrict__ catt, float* __restrict__ a1,
    float* __restrict__ stats, const float* __restrict__ csbn, float invN)
{
  constexpr int KP  = (K + 3) / 4 * 4;       // fp32 path: k padded to x4
  constexpr int LSf = KP + 4;                // fp32 ins stride (floats)
  constexpr int LSb = K + 8;                 // fp16 ins stride (shorts)
  constexpr size_t INS_B = LH16 ? (size_t)64 * LSb * 2 : (size_t)64 * LSf * 4;
  constexpr size_t WS_B  = LH16 ? (size_t)(K / 2) * 64 * 4 : (size_t)KP * 64 * 4;
  __shared__ __align__(16) unsigned char smem[INS_B + WS_B];
  __shared__ float atts[128];
  __shared__ float ssum[4], ssq[4];
  __shared__ float bnm[64], bns[64];
  ushortt*  insb = (ushortt*)smem;
  unsigned* Wp   = (unsigned*)(smem + INS_B);   // LH16: [K/2][64] half2-packed
  float*    insf = (float*)smem;
  float*    Wsf  = (float*)(smem + INS_B);

  const int tx = threadIdx.x;
  const int b0 = blockIdx.x * 64;

  if (FUSE_BN) {
    if (tx < 64) {
      float mn = 0.f, sq = 0.f;
      #pragma unroll
      for (int bk = 0; bk < 16; ++bk) {
        mn += csbn[bk * 128 + tx];
        sq += csbn[bk * 128 + 64 + tx];
      }
      mn *= invN; sq *= invN;
      bnm[tx] = mn;
      bns[tx] = rsqrtf(sq - mn * mn + 1e-5f);
    }
    __syncthreads();
  }

  if (LH16) {
    static_assert(!LH16 || (K % 8 == 0), "fp16 path needs K%8==0");
    for (int i = tx; i < (K / 2) * 64; i += 256) {
      const int k2 = i >> 6;
      const int c = i & 63;
      Wp[i] = pack2h(W[(2 * k2) * 64 + c], W[(2 * k2 + 1) * 64 + c]);
    }
    for (int i = tx; i < 64 * (K / 8); i += 256) {
      const int row = i / (K / 8);
      const int k8 = i % (K / 8);
      long r = b0 + row; if (r >= R) r = R - 1;   // clamp: values unused
      if (GATHER) r = rows[r];
      *(uint4*)&insb[row * LSb + k8 * 8] =
          *(const uint4*)&((const ushortt*)in)[r * (long)K + k8 * 8];
    }
  } else {
    for (int i = tx; i < KP * 64; i += 256) {
      const int k = i >> 6;
      Wsf[i] = (k < K) ? W[i] : 0.0f;
    }
    for (int i = tx; i < 64 * (KP / 4); i += 256) {
      const int row = i / (KP / 4);
      const int k4 = i % (KP / 4);
      long r = b0 + row; if (r >= R) r = R - 1;   // clamp: values unused
      if (GATHER) r = rows[r];
      float4 v;
      if (K % 4 == 0) {
        v = *(const float4*)&((const float*)in)[r * (long)K + k4 * 4];
      } else {
        float t[4];
        #pragma unroll
        for (int j = 0; j < 4; ++j) {
          const int k = k4 * 4 + j;
          t[j] = (k < K) ? ((const float*)in)[r * (long)K + k] : 0.0f;
        }
        v = make_float4(t[0], t[1], t[2], t[3]);
      }
      if (FUSE_BN) {
        float* vv = (float*)&v;
        #pragma unroll
        for (int j = 0; j < 4; ++j) {
          const int c = k4 * 4 + j;
          vv[j] = sp_f((vv[j] - bnm[c]) * bns[c]);
        }
      }
      *(float4*)&insf[row * LSf + k4 * 4] = v;
    }
  }
  if (FUSE_A) { if (tx < 128) atts[tx] = catt[tx]; }
  __syncthreads();

  const int lr0 = ((tx >> 6) << 4) + (((tx >> 4) & 3) << 2);  // local row base
  const int c0 = (tx & 15) << 2;                               // col base

  // FUSE_A: prefetch P rows NOW -- latency hides under the MAC loop.
  ushort4 pdv[4], psv[4];
  if (FUSE_A) {
    #pragma unroll
    for (int ri = 0; ri < 4; ++ri) {
      long e = b0 + lr0 + ri; if (e >= R) e = R - 1;   // clamp: values unused
      const int s = srcp[e];
      const int d = dstp[e];
      psv[ri] = *(const ushort4*)&P[(long)s * 64 + c0];
      pdv[ri] = *(const ushort4*)&P[(long)d * 64 + c0];
    }
  }

  float acc[4][4];
  #pragma unroll
  for (int i = 0; i < 4; ++i)
    #pragma unroll
    for (int j = 0; j < 4; ++j) acc[i][j] = 0.0f;

  if (LH16) {
    // ROLLED k8 loop: wv loaded once/iter, av per-ri, consumed at once.
    #pragma unroll 1
    for (int k8 = 0; k8 < K / 8; ++k8) {
      const uint4 wv0 = *(const uint4*)&Wp[(k8 * 4 + 0) * 64 + c0];
      const uint4 wv1 = *(const uint4*)&Wp[(k8 * 4 + 1) * 64 + c0];
      const uint4 wv2 = *(const uint4*)&Wp[(k8 * 4 + 2) * 64 + c0];
      const uint4 wv3 = *(const uint4*)&Wp[(k8 * 4 + 3) * 64 + c0];
      #pragma unroll
      for (int ri = 0; ri < 4; ++ri) {
        const uint4 av = *(const uint4*)&insb[(lr0 + ri) * LSb + k8 * 8];
        acc[ri][0] = fdot2f(av.x, wv0.x, acc[ri][0]);
        acc[ri][1] = fdot2f(av.x, wv0.y, acc[ri][1]);
        acc[ri][2] = fdot2f(av.x, wv0.z, acc[ri][2]);
        acc[ri][3] = fdot2f(av.x, wv0.w, acc[ri][3]);
        acc[ri][0] = fdot2f(av.y, wv1.x, acc[ri][0]);
        acc[ri][1] = fdot2f(av.y, wv1.y, acc[ri][1]);
        acc[ri][2] = fdot2f(av.y, wv1.z, acc[ri][2]);
        acc[ri][3] = fdot2f(av.y, wv1.w, acc[ri][3]);
        acc[ri][0] = fdot2f(av.z, wv2.x, acc[ri][0]);
        acc[ri][1] = fdot2f(av.z, wv2.y, acc[ri][1]);
        acc[ri][2] = fdot2f(av.z, wv2.z, acc[ri][2]);
        acc[ri][3] = fdot2f(av.z, wv2.w, acc[ri][3]);
        acc[ri][0] = fdot2f(av.w, wv3.x, acc[ri][0]);
        acc[ri][1] = fdot2f(av.w, wv3.y, acc[ri][1]);
        acc[ri][2] = fdot2f(av.w, wv3.z, acc[ri][2]);
        acc[ri][3] = fdot2f(av.w, wv3.w, acc[ri][3]);
      }
    }
  } else {
    #pragma unroll 4
    for (int k4 = 0; k4 < KP / 4; ++k4) {
      float4 w[4], a[4];
      #pragma unroll
      for (int kk = 0; kk < 4; ++kk)
        w[kk] = *(const float4*)&Wsf[(k4 * 4 + kk) * 64 + c0];
      #pragma unroll
      for (int ri = 0; ri < 4; ++ri)
        a[ri] = *(const float4*)&insf[(lr0 + ri) * LSf + k4 * 4];
      #pragma unroll
      for (int ri = 0; ri < 4; ++ri) {
        const float* av = (const float*)&a[ri];
        #pragma unroll
        for (int kk = 0; kk < 4; ++kk) {
          acc[ri][0] = fmaf(av[kk], w[kk].x, acc[ri][0]);
          acc[ri][1] = fmaf(av[kk], w[kk].y, acc[ri][1]);
          acc[ri][2] = fmaf(av[kk], w[kk].z, acc[ri][2]);
          acc[ri][3] = fmaf(av[kk], w[kk].w, acc[ri][3]);
        }
      }
    }
  }

  if (!FUSE_A) {
    float4 bias = make_float4(0.f, 0.f, 0.f, 0.f);
    if (BIAS) bias = *(const float4*)&b[c0];
    #pragma unroll
    for (int ri = 0; ri < 4; ++ri) {
      const long r = b0 + lr0 + ri;
      if (r >= R) continue;
      float4 v;
      v.x = acc[ri][0] + bias.x; v.y = acc[ri][1] + bias.y;
      v.z = acc[ri][2] + bias.z; v.w = acc[ri][3] + bias.w;
      if (ACT == 1) {
        v.x = v.x >= 0.f ? v.x : 0.2f * v.x;  v.y = v.y >= 0.f ? v.y : 0.2f * v.y;
        v.z = v.z >= 0.f ? v.z : 0.2f * v.z;  v.w = v.w >= 0.f ? v.w : 0.2f * v.w;
      }
      if (sizeof(OT) == 4) {
        *(float4*)&out[r * 64 + c0] = v;
      } else {
        ushort4 u;
        u.x = f2h(v.x); u.y = f2h(v.y); u.z = f2h(v.z); u.w = f2h(v.w);
        *(ushort4*)&out[r * 64 + c0] = u;
      }
    }
  } else {
    // epilogue: ti/tj from prefetched P; tj -> out[e] (fp16), a1[e]; a1 stats
    float s1 = 0.f, s2 = 0.f;
    #pragma unroll
    for (int ri = 0; ri < 4; ++ri) {
      const long e = b0 + lr0 + ri;
      float part = 0.0f;
      if (e < R) {
        const float4 Pd = h4_to_f4(pdv[ri]);
        const float4 Ps = h4_to_f4(psv[ri]);
        float tj[4];
        const float ti0 = sp_f(Pd.x + acc[ri][0]);
        const float ti1 = sp_f(Pd.y + acc[ri][1]);
        const float ti2 = sp_f(Pd.z + acc[ri][2]);
        const float ti3 = sp_f(Pd.w + acc[ri][3]);
        tj[0] = sp_f(Ps.x + acc[ri][0]);
        tj[1] = sp_f(Ps.y + acc[ri][1]);
        tj[2] = sp_f(Ps.z + acc[ri][2]);
        tj[3] = sp_f(Ps.w + acc[ri][3]);
        ushort4 u;
        u.x = f2h(tj[0]); u.y = f2h(tj[1]); u.z = f2h(tj[2]); u.w = f2h(tj[3]);
        *(ushort4*)&out[e * 64 + c0] = u;
        part = ti0 * atts[c0] + ti1 * atts[c0 + 1] + ti2 * atts[c0 + 2] + ti3 * atts[c0 + 3]
             + tj[0] * atts[64 + c0] + tj[1] * atts[64 + c0 + 1]
             + tj[2] * atts[64 + c0 + 2] + tj[3] * atts[64 + c0 + 3];
      }
      #pragma unroll
      for (int off = 8; off; off >>= 1) part += __shfl_xor(part, off);
      if ((tx & 15) == 0 && e < R) {
        const float v = sp_f(part);
        a1[e] = v;
        s1 += v; s2 += v * v;
      }
    }
    s1 += __shfl_xor(s1, 16); s2 += __shfl_xor(s2, 16);
    s1 += __shfl_xor(s1, 32); s2 += __shfl_xor(s2, 32);
    if ((tx & 63) == 0) { ssum[tx >> 6] = s1; ssq[tx >> 6] = s2; }
    __syncthreads();
    if (tx == 0) {
      // 64-way banked: ~98 same-address atomics instead of 6250 (r11 lesson)
      const int bk = blockIdx.x & 63;
      atomicAdd(&stats[bk], ssum[0] + ssum[1] + ssum[2] + ssum[3]);
      atomicAdd(&stats[64 + bk], ssq[0] + ssq[1] + ssq[2] + ssq[3]);
    }
  }
}

// ---------- CSR build (once per launch; graph static across layers) --------
__global__ __launch_bounds__(256) void k_count(
    const int* __restrict__ dst, int* __restrict__ counts, int E)
{
  for (int i = blockIdx.x * 256 + threadIdx.x; i < E; i += gridDim.x * 256)
    atomicAdd(&counts[dst[i]], 1);
}

// hierarchical scan (r16 lesson: single-block scan was a 92us Amdahl tail)
// phase 1: per-256-block inclusive scan -> local exclusive into offs, total->bsum
__global__ __launch_bounds__(256) void k_scan1(
    const int* __restrict__ counts, int* __restrict__ offs,
    int* __restrict__ bsum, int N)
{
  __shared__ int sm[256];
  const int t = threadIdx.x;
  const int idx = blockIdx.x * 256 + t;
  const int v = (idx < N) ? counts[idx] : 0;
  sm[t] = v;
  __syncthreads();
  for (int off = 1; off < 256; off <<= 1) {
    const int u = (t >= off) ? sm[t - off] : 0;
    __syncthreads();
    sm[t] += u;
    __syncthreads();
  }
  if (idx < N) offs[idx] = sm[t] - v;   // local exclusive prefix
  if (t == 255) bsum[blockIdx.x] = sm[255];
}

// phase 2: single small block: exclusive scan of bsum[SB] (SB <= 1024)
__global__ __launch_bounds__(1024) void k_scan2(int* __restrict__ bsum, int SB)
{
  __shared__ int sm[1024];
  const int t = threadIdx.x;
  const int v = (t < SB) ? bsum[t] : 0;
  sm[t] = v;
  __syncthreads();
  for (int off = 1; off < 1024; off <<= 1) {
    const int u = (t >= off) ? sm[t - off] : 0;
    __syncthreads();
    sm[t] += u;
    __syncthreads();
  }
  if (t < SB) bsum[t] = sm[t] - v;      // exclusive block base
}

// phase 3: offs[idx] += bsum[block]; offs[N] = E (total known a priori)
__global__ __launch_bounds__(256) void k_scan3(
    int* __restrict__ offs, const int* __restrict__ bsum, int N, int E)
{
  const int idx = blockIdx.x * 256 + threadIdx.x;
  if (idx < N) offs[idx] += bsum[blockIdx.x];
  if (idx == 0) offs[N] = E;
}

// eids[CSR slot] = original edge id
__global__ __launch_bounds__(256) void k_fill(
    const int* __restrict__ dst, const int* __restrict__ offs,
    int* __restrict__ cursors, int* __restrict__ eids, int E)
{
  for (int i = blockIdx.x * 256 + threadIdx.x; i < E; i += gridDim.x * 256) {
    const int d = dst[i];
    eids[offs[d] + atomicAdd(&cursors[d], 1)] = i;
  }
}

// srcp/dstp in CSR order
__global__ __launch_bounds__(256) void k_permidx(
    const int* __restrict__ eids, const int* __restrict__ eidx,
    int* __restrict__ srcp, int* __restrict__ dstp, int E)
{
  for (int i = blockIdx.x * 256 + threadIdx.x; i < E; i += gridDim.x * 256) {
    const int e = eids[i];
    srcp[i] = eidx[e];
    dstp[i] = eidx[(long)E + e];
  }
}

// ---------- aggregate: sequential CSR reads, banked stats everywhere --------
__global__ __launch_bounds__(256) void k_aggregate(
    const int* __restrict__ offs, const float* __restrict__ a1p,
    const ushortt* __restrict__ Mp, const float* __restrict__ stats,
    float invE, float* __restrict__ aggn, float* __restrict__ cs, int N)
{
  __shared__ float sm_mean, sm_scl;
  const int tx = threadIdx.x;
  if (tx < 64) {   // reduce the 64 a1-stat banks (wave 0)
    float s1 = stats[tx];
    float s2 = stats[64 + tx];
    #pragma unroll
    for (int off = 32; off; off >>= 1) {
      s1 += __shfl_xor(s1, off);
      s2 += __shfl_xor(s2, off);
    }
    if (tx == 0) {
      const float mean = s1 * invE;
      sm_mean = mean;
      sm_scl = rsqrtf(s2 * invE - mean * mean + 1e-5f);
    }
  }
  __syncthreads();
  const float mean = sm_mean;
  const float scl = sm_scl;

  const int t = tx & 63;
  const int wid = tx >> 6;
  float s = 0.f, s2 = 0.f;
  const long step = (long)gridDim.x * 4;
  for (long n = (long)blockIdx.x * 4 + wid; n < N; n += step) {
    const int o0 = offs[n];
    const int o1 = offs[n + 1];
    float av = 0.f, sew = 0.f;
    #pragma unroll 4
    for (int i = o0; i < o1; ++i) {
      const float w = __expf(sp_f((a1p[i] - mean) * scl));
      av = fmaf(h2f(Mp[(long)i * 64 + t]), w, av);
      sew += w;
    }
    const float v = (o1 > o0) ? av / sew : 0.0f;
    aggn[n * 64 + t] = v;
    s += v; s2 += v * v;
  }
  __shared__ float b1[256], b2[256];
  b1[tx] = s; b2[tx] = s2;
  __syncthreads();
  if (tx < 64) {
    const int bank = (blockIdx.x & 15) * 128;   // 16 banks: ~128 atomics/addr
    atomicAdd(&cs[bank + t], b1[t] + b1[64 + t] + b1[128 + t] + b1[192 + t]);
    atomicAdd(&cs[bank + 64 + t], b2[t] + b2[64 + t] + b2[128 + t] + b2[192 + t]);
  }
}

// h = sp((aggn - mean_c) * rsqrt(var_c + eps)); cs has 16 banks of 128
__global__ __launch_bounds__(256) void k_hnew(
    const float* __restrict__ aggn, const float* __restrict__ cs,
    float invN, float* __restrict__ h, int N)
{
  const int c = threadIdx.x & 63;
  const int r = threadIdx.x >> 6;
  float mn = 0.f, sq = 0.f;
  #pragma unroll
  for (int bk = 0; bk < 16; ++bk) {
    mn += cs[bk * 128 + c];
    sq += cs[bk * 128 + 64 + c];
  }
  mn *= invN; sq *= invN;
  const float scl = rsqrtf(sq - mn * mn + 1e-5f);
  for (long n = (long)blockIdx.x * 4 + r; n < N; n += (long)gridDim.x * 4)
    h[n * 64 + c] = sp_f((aggn[n * 64 + c] - mn) * scl);
}

// composition attention: per block, 64-node tile, LDS-staged q + Wc.
// q[n] = concat(h[n] (64), gf[batch[n]] (103)); z = q@Wc (32 cols);
// aN[n] = sum_col sp(z+bc)*aw + ab.
// Thread: node = tx>>2, colg = (tx&3)*8 -> 8 cols, acc[8] independent chains.
#define QSS 170   // q LDS stride (floats): 16 nodes/wave -> 16 distinct banks
__global__ __launch_bounds__(256) void k_comp(
    const float* __restrict__ h, const float* __restrict__ gf,
    const int* __restrict__ batch, const float* __restrict__ Wc,
    const float* __restrict__ bc, const float* __restrict__ aw,
    const float* __restrict__ ab, float* __restrict__ aN, int N)
{
  __shared__ __align__(16) float qs[64 * QSS];
  __shared__ __align__(16) float Wcs[167 * 32];
  __shared__ float aws[32], bcs[32];
  const int tx = threadIdx.x;
  const int b0 = blockIdx.x * 64;
  for (int i = tx; i < 167 * 32; i += 256) Wcs[i] = Wc[i];
  if (tx < 32) { aws[tx] = aw[tx]; bcs[tx] = bc[tx]; }
  // stage h rows (float4, coalesced)
  for (int i = tx; i < 64 * 16; i += 256) {
    const int n = i >> 4;
    const int c4 = (i & 15) << 2;
    long r = b0 + n; if (r >= N) r = N - 1;   // clamp: values unused
    *(float4*)&qs[n * QSS + c4] = *(const float4*)&h[r * 64 + c4];
  }
  // stage gf rows (scalar; 103 per node)
  for (int i = tx; i < 64 * 103; i += 256) {
    const int n = i / 103;
    const int c = i % 103;
    long r = b0 + n; if (r >= N) r = N - 1;
    qs[n * QSS + 64 + c] = gf[(long)batch[r] * 103 + c];
  }
  __syncthreads();

  const int n = tx >> 2;
  const int colg = (tx & 3) << 3;
  float acc[8];
  #pragma unroll
  for (int j = 0; j < 8; ++j) acc[j] = 0.f;
  #pragma unroll 2
  for (int k = 0; k < 167; ++k) {
    const float q = qs[n * QSS + k];
    const float4 w0 = *(const float4*)&Wcs[k * 32 + colg];
    const float4 w1 = *(const float4*)&Wcs[k * 32 + colg + 4];
    acc[0] = fmaf(q, w0.x, acc[0]);
    acc[1] = fmaf(q, w0.y, acc[1]);
    acc[2] = fmaf(q, w0.z, acc[2]);
    acc[3] = fmaf(q, w0.w, acc[3]);
    acc[4] = fmaf(q, w1.x, acc[4]);
    acc[5] = fmaf(q, w1.y, acc[5]);
    acc[6] = fmaf(q, w1.z, acc[6]);
    acc[7] = fmaf(q, w1.w, acc[7]);
  }
  float val = 0.f;
  #pragma unroll
  for (int j = 0; j < 8; ++j)
    val += sp_f(acc[j] + bcs[colg + j]) * aws[colg + j];
  val += __shfl_xor(val, 1);
  val += __shfl_xor(val, 2);
  const long r = b0 + n;
  if ((tx & 3) == 0 && r < N) aN[r] = val + ab[0];
}

// one 64-thread block per graph: seg-softmax over sorted batch + pool + fc
__global__ __launch_bounds__(64) void k_pool(
    const float* __restrict__ h, const float* __restrict__ aN,
    const int* __restrict__ batch, const float* __restrict__ fcW,
    const float* __restrict__ fcb, float* __restrict__ out, int N, int G)
{
  const int g = blockIdx.x;
  const int t = threadIdx.x;
  int lo = 0, hi = N;
  while (lo < hi) { int mid = (lo + hi) >> 1; if (batch[mid] < g) lo = mid + 1; else hi = mid; }
  const int s = lo;
  hi = N;
  while (lo < hi) { int mid = (lo + hi) >> 1; if (batch[mid] < g + 1) lo = mid + 1; else hi = mid; }
  const int e2 = lo;
  if (s >= e2) { if (t == 0) out[g] = fcb[0]; return; }
  float mx = -1e30f;
  for (int i = s + t; i < e2; i += 64) mx = fmaxf(mx, aN[i]);
  #pragma unroll
  for (int off = 32; off; off >>= 1) mx = fmaxf(mx, __shfl_xor(mx, off));
  float se = 0.f;
  for (int i = s + t; i < e2; i += 64) se += __expf(aN[i] - mx);
  #pragma unroll
  for (int off = 32; off; off >>= 1) se += __shfl_xor(se, off);
  float acc = 0.f;
  for (int n = s; n < e2; ++n) {
    const float w = __expf(aN[n] - mx);
    acc = fmaf(h[(long)n * 64 + t], w, acc);
  }
  float part = (acc / se) * fcW[t];
  #pragma unroll
  for (int off = 32; off; off >>= 1) part += __shfl_xor(part, off);
  if (t == 0) out[g] = part + fcb[0];
}

extern "C" void kernel_launch(void* const* d_in, const int* in_sizes, int n_in,
                              void* d_out, int out_size, void* d_ws, size_t ws_size,
                              hipStream_t stream)
{
  const float* x     = (const float*)d_in[0];
  const int*   eidx  = (const int*)  d_in[1];
  const float* eattr = (const float*)d_in[2];
  const int*   batch = (const int*)  d_in[3];
  const float* gfeat = (const float*)d_in[4];
  const float* embnW = (const float*)d_in[5];
  const float* embnb = (const float*)d_in[6];
  const float* embeW = (const float*)d_in[7];
  const float* embeb = (const float*)d_in[8];
  const float* convW = (const float*)d_in[9];
  const float* convA = (const float*)d_in[10];
  // d_in[11] = conv_bias: cancels exactly in training-mode BatchNorm
  const float* compW = (const float*)d_in[12];
  const float* compb = (const float*)d_in[13];
  const float* attW  = (const float*)d_in[14];
  const float* attb  = (const float*)d_in[15];
  const float* fcW   = (const float*)d_in[16];
  const float* fcb   = (const float*)d_in[17];
  float* out = (float*)d_out;

  const int N = in_sizes[0] / 92;
  const int E = in_sizes[1] / 2;
  const int G = in_sizes[4] / 103;
  const float invN = 1.0f / (float)N;
  const float invE = 1.0f / (float)E;

  // workspace (~140 MB): fp32 node buffers, CSR ints, fp16 edge streams + P
  char* pw = (char*)d_ws;
  float* h     = (float*)pw;  pw += (size_t)N * 64 * 4;
  float* aggn  = (float*)pw;  pw += (size_t)N * 64 * 4;
  float* aE    = (float*)pw;  pw += (size_t)E * 4;        // a1 (CSR-ordered)
  float* statsB = (float*)pw; pw += 3 * SLOTS * 4;        // per-layer stat blocks
  float* aN    = (float*)pw;  pw += (size_t)N * 4;
  int* counts  = (int*)pw;    pw += (size_t)N * 4;        // counts+cursors: one memset
  int* cursors = (int*)pw;    pw += (size_t)N * 4;
  int* offs    = (int*)pw;    pw += ((size_t)N + 1) * 4;
  int* bsum    = (int*)pw;    pw += 1024 * 4;
  int* eids    = (int*)pw;    pw += (size_t)E * 4;
  int* srcp    = (int*)pw;    pw += (size_t)E * 4;
  int* dstp    = (int*)pw;    pw += (size_t)E * 4;
  pw = (char*)(((size_t)pw + 63) & ~(size_t)63);
  ushortt* Pp  = (ushortt*)pw; pw += (size_t)N * 64 * 2;  // P fp16
  ushortt* ea  = (ushortt*)pw; pw += (size_t)E * 64 * 2;  // fp16, CSR-ordered
  ushortt* M   = (ushortt*)pw;                            // fp16 tj, CSR-ordered

  const int gE64 = (E + 63) / 64;
  const int gN64 = (N + 63) / 64;
  const int SB = (N + 255) / 256;   // scan blocks (<=1024 for N<=262k)

  // CSR build (dst = eidx[E..2E)), hierarchical scan, then index permutes
  hipMemsetAsync(counts, 0, 2 * (size_t)N * sizeof(int), stream);
  hipMemsetAsync(statsB, 0, 3 * SLOTS * sizeof(float), stream);
  k_count<<<2048, 256, 0, stream>>>(eidx + E, counts, E);
  k_scan1<<<SB, 256, 0, stream>>>(counts, offs, bsum, N);
  k_scan2<<<1, 1024, 0, stream>>>(bsum, SB);
  k_scan3<<<SB, 256, 0, stream>>>(offs, bsum, N, E);
  k_fill<<<2048, 256, 0, stream>>>(eidx + E, offs, cursors, eids, E);
  k_permidx<<<2048, 256, 0, stream>>>(eids, eidx, srcp, dstp, E);

  k_gemm_rt<92, 0, 1, 0, 0, 0, 0, float, float><<<gN64, 256, 0, stream>>>(
      x, embnW, embnb, h, N, nullptr, nullptr, nullptr, nullptr, nullptr,
      nullptr, nullptr, nullptr, 0.f);
  // ea-embed: gather eattr rows by eids -> ea written CSR-ordered, coalesced
  k_gemm_rt<41, 1, 1, 0, 0, 1, 0, float, ushortt><<<gE64, 256, 0, stream>>>(
      eattr, embeW, embeb, ea, E, eids, nullptr, nullptr, nullptr, nullptr,
      nullptr, nullptr, nullptr, 0.f);

  for (int l = 0; l < 3; ++l) {
    const float* Wl = convW + (size_t)l * 128 * 64;
    const float* Al = convA + (size_t)l * 128;
    float* statsL = statsB + (size_t)l * SLOTS;
    if (l == 0) {
      k_gemm_rt<64, 0, 0, 0, 0, 0, 0, float, ushortt><<<gN64, 256, 0, stream>>>(
          h, Wl, nullptr, Pp, N, nullptr, nullptr, nullptr, nullptr, nullptr,
          nullptr, nullptr, nullptr, 0.f);
    } else {
      // staging reads aggn, applies BN+softplus inline (16-bank cs of layer l-1)
      k_gemm_rt<64, 0, 0, 0, 0, 0, 1, float, ushortt><<<gN64, 256, 0, stream>>>(
          aggn, Wl, nullptr, Pp, N, nullptr, nullptr, nullptr, nullptr, nullptr,
          nullptr, nullptr, statsB + (size_t)(l - 1) * SLOTS + 128, invN);
    }
    k_gemm_rt<64, 0, 0, 1, 1, 0, 0, ushortt, ushortt><<<gE64, 256, 0, stream>>>(
        ea, Wl + 64 * 64, nullptr, M, E, nullptr, Pp, srcp, dstp, Al, aE,
        statsL, nullptr, 0.f);
    k_aggregate<<<2048, 256, 0, stream>>>(offs, aE, M, statsL,
                                          invE, aggn, statsL + 128, N);
  }

  k_hnew<<<2048, 256, 0, stream>>>(aggn, statsB + 2 * SLOTS + 128, invN, h, N);
  k_comp<<<gN64, 256, 0, stream>>>(h, gfeat, batch, compW, compb, attW, attb, aN, N);
  k_pool<<<G, 64, 0, stream>>>(h, aN, batch, fcW, fcb, out, N, G);

  (void)n_in; (void)out_size; (void)ws_size;
}

// Round 18
// 475.577 us; speedup vs baseline: 3.9677x; 1.1378x over previous
//
#include <hip/hip_runtime.h>
#include <hip/hip_bf16.h>
#include <hip/hip_fp16.h>
#include <math.h>

// ---------------------------------------------------------------------------
// GATGNN forward. fp32 math; edge streams fp16, ALL CSR-ordered (~140 MB ws).
//   CSR build (hierarchical scan) -> eids, srcp/dstp CSR-ordered.
//   h = x@Wn + bn;  ea = leaky_relu(eattr@We + be)  [gathered -> CSR fp16]
//   per layer:
//     P = h@Wtop (fp16)  [layers 1,2: BN+softplus fused into staging]
//     k_efused (MFMA): M = ea@Wbot via v_mfma_f32_16x16x32_f16 (matrix pipe);
//            acc -> LDS -> r14 epilogue: ti=sp(Pd+M), tj=sp(Ps+M); M<-tj;
//            a1=sp(att dot); a1 stats -> 64-way banked atomics
//     aggregate: sequential CSR walk; banked col stats
//   final h = sp(BN(aggn)); comp attention (LDS-tiled, ILP) + pool + fc
// Lessons pinned:
//  - NEVER pass min-waves to __launch_bounds__ (r6/r7 GB-scale spills).
//  - r9: full-unroll reg tiles -> VGPR 144, occupancy collapse.
//  - r11/r15: same-address L2 atomic ~22ns serialized; keep <=128/address.
//  - r15: no serial cross-lane chains in hot loops.
//  - r16: single-block scan = 92us Amdahl tail -> hierarchical.
//  - r17 PMC: fused GEMM VALUBusy 80% -> MAC (512 dot2/thread) moved to
//    matrix pipe (MFMA); epilogue unchanged via LDS acc round-trip.
// ---------------------------------------------------------------------------

typedef unsigned short ushortt;
typedef _Float16 half2v __attribute__((ext_vector_type(2)));
typedef _Float16 f16x8 __attribute__((ext_vector_type(8)));
typedef float f32x4 __attribute__((ext_vector_type(4)));

__device__ __forceinline__ float sp_f(float x) {
  return x > 20.0f ? x : __logf(1.0f + __expf(x));
}
__device__ __forceinline__ float h2f(ushortt u) {
  union { ushortt u; __half h; } c; c.u = u;
  return __half2float(c.h);
}
__device__ __forceinline__ ushortt f2h(float f) {
  union { __half h; ushortt u; } c; c.h = __float2half(f);
  return c.u;
}
__device__ __forceinline__ float4 h4_to_f4(ushort4 u) {
  return make_float4(h2f(u.x), h2f(u.y), h2f(u.z), h2f(u.w));
}
__device__ __forceinline__ unsigned pack2h(float a, float b) {
  union { _Float16 h[2]; unsigned u; } c;
  c.h[0] = (_Float16)a; c.h[1] = (_Float16)b;
  return c.u;
}

// per-layer stats block layout (floats), stride SLOTS:
//   [0..63] a1 sum banks  [64..127] a1 sumsq banks
//   [128 .. 128+16*128)   col-stats cs, 16 banks x (64 sum + 64 sumsq)
#define SLOTS 2304

// ---------- generic register-tiled GEMM (node-side + embeds, fp32 LDS) -----
template<int K, int ACT, int BIAS, int GATHER, int FUSE_BN,
         typename IT, typename OT>
__global__ __launch_bounds__(256) void k_gemm_rt(
    const IT* __restrict__ in, const float* __restrict__ W,
    const float* __restrict__ b, OT* __restrict__ out, int R,
    const int* __restrict__ rows, const float* __restrict__ csbn, float invN)
{
  constexpr int KP = (K + 3) / 4 * 4;
  constexpr int LS = KP + 4;
  __shared__ __align__(16) float ins[64 * LS];
  __shared__ __align__(16) float Ws[KP * 64];
  __shared__ float bnm[64], bns[64];

  const int tx = threadIdx.x;
  const int b0 = blockIdx.x * 64;

  if (FUSE_BN) {
    if (tx < 64) {
      float mn = 0.f, sq = 0.f;
      #pragma unroll
      for (int bk = 0; bk < 16; ++bk) {
        mn += csbn[bk * 128 + tx];
        sq += csbn[bk * 128 + 64 + tx];
      }
      mn *= invN; sq *= invN;
      bnm[tx] = mn;
      bns[tx] = rsqrtf(sq - mn * mn + 1e-5f);
    }
    __syncthreads();
  }

  for (int i = tx; i < KP * 64; i += 256) {
    const int k = i >> 6;
    Ws[i] = (k < K) ? W[i] : 0.0f;
  }
  for (int i = tx; i < 64 * (KP / 4); i += 256) {
    const int row = i / (KP / 4);
    const int k4 = i % (KP / 4);
    long r = b0 + row; if (r >= R) r = R - 1;   // clamp: values unused
    if (GATHER) r = rows[r];
    float4 v;
    if (K % 4 == 0) {
      v = *(const float4*)&((const float*)in)[r * (long)K + k4 * 4];
    } else {
      float t[4];
      #pragma unroll
      for (int j = 0; j < 4; ++j) {
        const int k = k4 * 4 + j;
        t[j] = (k < K) ? ((const float*)in)[r * (long)K + k] : 0.0f;
      }
      v = make_float4(t[0], t[1], t[2], t[3]);
    }
    if (FUSE_BN) {
      float* vv = (float*)&v;
      #pragma unroll
      for (int j = 0; j < 4; ++j) {
        const int c = k4 * 4 + j;
        vv[j] = sp_f((vv[j] - bnm[c]) * bns[c]);
      }
    }
    *(float4*)&ins[row * LS + k4 * 4] = v;
  }
  __syncthreads();

  const int lr0 = ((tx >> 6) << 4) + (((tx >> 4) & 3) << 2);
  const int c0 = (tx & 15) << 2;
  float acc[4][4];
  #pragma unroll
  for (int i = 0; i < 4; ++i)
    #pragma unroll
    for (int j = 0; j < 4; ++j) acc[i][j] = 0.0f;

  #pragma unroll 4
  for (int k4 = 0; k4 < KP / 4; ++k4) {
    float4 w[4], a[4];
    #pragma unroll
    for (int kk = 0; kk < 4; ++kk)
      w[kk] = *(const float4*)&Ws[(k4 * 4 + kk) * 64 + c0];
    #pragma unroll
    for (int ri = 0; ri < 4; ++ri)
      a[ri] = *(const float4*)&ins[(lr0 + ri) * LS + k4 * 4];
    #pragma unroll
    for (int ri = 0; ri < 4; ++ri) {
      const float* av = (const float*)&a[ri];
      #pragma unroll
      for (int kk = 0; kk < 4; ++kk) {
        acc[ri][0] = fmaf(av[kk], w[kk].x, acc[ri][0]);
        acc[ri][1] = fmaf(av[kk], w[kk].y, acc[ri][1]);
        acc[ri][2] = fmaf(av[kk], w[kk].z, acc[ri][2]);
        acc[ri][3] = fmaf(av[kk], w[kk].w, acc[ri][3]);
      }
    }
  }

  float4 bias = make_float4(0.f, 0.f, 0.f, 0.f);
  if (BIAS) bias = *(const float4*)&b[c0];
  #pragma unroll
  for (int ri = 0; ri < 4; ++ri) {
    const long r = b0 + lr0 + ri;
    if (r >= R) continue;
    float4 v;
    v.x = acc[ri][0] + bias.x; v.y = acc[ri][1] + bias.y;
    v.z = acc[ri][2] + bias.z; v.w = acc[ri][3] + bias.w;
    if (ACT == 1) {
      v.x = v.x >= 0.f ? v.x : 0.2f * v.x;  v.y = v.y >= 0.f ? v.y : 0.2f * v.y;
      v.z = v.z >= 0.f ? v.z : 0.2f * v.z;  v.w = v.w >= 0.f ? v.w : 0.2f * v.w;
    }
    if (sizeof(OT) == 4) {
      *(float4*)&out[r * 64 + c0] = v;
    } else {
      ushort4 u;
      u.x = f2h(v.x); u.y = f2h(v.y); u.z = f2h(v.z); u.w = f2h(v.w);
      *(ushort4*)&out[r * 64 + c0] = u;
    }
  }
}

// ---------- W pre-pack into MFMA B-fragment order (once per layer) ----------
// chunk idx = (kstep*4+ncol)*64 + lane: 8 halfs B[k=kstep*32+(lane>>4)*8+j]
//                                             [n=ncol*16+(lane&15)]
__global__ __launch_bounds__(512) void k_packW(
    const float* __restrict__ convW, uint4* __restrict__ WBg)
{
  const int l3 = blockIdx.x;                 // layer
  const float* W = convW + (size_t)l3 * 128 * 64 + 64 * 64;   // Wbot
  const int idx = threadIdx.x;               // 0..511
  const int kstep = idx >> 8;
  const int rem = idx & 255;
  const int ncol = rem >> 6;
  const int l = rem & 63;
  const int kbase = kstep * 32 + (l >> 4) * 8;
  const int n = ncol * 16 + (l & 15);
  ushortt tmp[8];
  #pragma unroll
  for (int j = 0; j < 8; ++j) tmp[j] = f2h(W[(kbase + j) * 64 + n]);
  WBg[l3 * 512 + idx] = *(uint4*)tmp;
}

// ---------- fused E-GEMM via MFMA -------------------------------------------
// Block 256 thr (4 waves), 64 edges, 64 cols, K=64 (2 MFMA ksteps).
// Wave w: rows 16w..16w+15. acc -> LDS -> r14-identical epilogue.
__global__ __launch_bounds__(256) void k_efused(
    const ushortt* __restrict__ ea, const uint4* __restrict__ WBg,
    ushortt* __restrict__ out, int E, const ushortt* __restrict__ P,
    const int* __restrict__ srcp, const int* __restrict__ dstp,
    const float* __restrict__ catt, float* __restrict__ a1,
    float* __restrict__ stats)
{
  // phase1: As[64][72] halfs (9216B) + WB[512] uint4 (8192B) = 17408B
  // phase2: accs[64][68] f32 (17408B) -- same buffer
  __shared__ __align__(16) unsigned char smem[17408];
  __shared__ float atts[128];
  __shared__ float ssum[4], ssq[4];
  ushortt* As   = (ushortt*)smem;          // stride 72 halfs
  uint4*   WB   = (uint4*)(smem + 9216);
  float*   accs = (float*)smem;            // stride 68 floats (phase 2)

  const int tx = threadIdx.x;
  const int b0 = blockIdx.x * 64;
  const int lane = tx & 63;
  const int w = tx >> 6;

  if (tx < 128) atts[tx] = catt[tx];
  #pragma unroll
  for (int i = tx; i < 64 * 8; i += 256) {    // A tile (raw fp16 rows)
    const int row = i >> 3;
    const int k8 = i & 7;
    long r = b0 + row; if (r >= E) r = E - 1;  // clamp: values unused
    *(uint4*)&As[row * 72 + k8 * 8] = *(const uint4*)&ea[r * (long)64 + k8 * 8];
  }
  #pragma unroll
  for (int i = tx; i < 512; i += 256) WB[i] = WBg[i];   // pre-packed B frags
  __syncthreads();

  // prefetch P rows in EPILOGUE thread layout (latency hides under MFMA)
  const int lr0 = ((tx >> 6) << 4) + (((tx >> 4) & 3) << 2);
  const int c0 = (tx & 15) << 2;
  ushort4 pdv[4], psv[4];
  #pragma unroll
  for (int ri = 0; ri < 4; ++ri) {
    long e = b0 + lr0 + ri; if (e >= E) e = E - 1;  // clamp: values unused
    const int s = srcp[e];
    const int d = dstp[e];
    psv[ri] = *(const ushort4*)&P[(long)s * 64 + c0];
    pdv[ri] = *(const ushort4*)&P[(long)d * 64 + c0];
  }

  // MFMA: A lane = row(l&15), k=(l>>4)*8+j ; B lane = col(l&15), same k.
  f32x4 acc0 = {0.f,0.f,0.f,0.f}, acc1 = {0.f,0.f,0.f,0.f};
  f32x4 acc2 = {0.f,0.f,0.f,0.f}, acc3 = {0.f,0.f,0.f,0.f};
  const int arow = 16 * w + (lane & 15);
  #pragma unroll
  for (int kstep = 0; kstep < 2; ++kstep) {
    const f16x8 a = __builtin_bit_cast(f16x8,
        *(const uint4*)&As[arow * 72 + kstep * 32 + (lane >> 4) * 8]);
    const int bb = kstep * 256 + lane;
    const f16x8 b0v = __builtin_bit_cast(f16x8, WB[bb]);
    const f16x8 b1v = __builtin_bit_cast(f16x8, WB[bb + 64]);
    const f16x8 b2v = __builtin_bit_cast(f16x8, WB[bb + 128]);
    const f16x8 b3v = __builtin_bit_cast(f16x8, WB[bb + 192]);
    acc0 = __builtin_amdgcn_mfma_f32_16x16x32_f16(a, b0v, acc0, 0, 0, 0);
    acc1 = __builtin_amdgcn_mfma_f32_16x16x32_f16(a, b1v, acc1, 0, 0, 0);
    acc2 = __builtin_amdgcn_mfma_f32_16x16x32_f16(a, b2v, acc2, 0, 0, 0);
    acc3 = __builtin_amdgcn_mfma_f32_16x16x32_f16(a, b3v, acc3, 0, 0, 0);
  }
  __syncthreads();   // all waves done with As/WB before acc overwrite

  // acc -> LDS: C/D layout col=lane&15, row=(lane>>4)*4+reg (m89)
  {
    const int rbase = 16 * w + (lane >> 4) * 4;
    const int cb = lane & 15;
    #pragma unroll
    for (int reg = 0; reg < 4; ++reg) {
      accs[(rbase + reg) * 68 + cb]      = acc0[reg];
      accs[(rbase + reg) * 68 + 16 + cb] = acc1[reg];
      accs[(rbase + reg) * 68 + 32 + cb] = acc2[reg];
      accs[(rbase + reg) * 68 + 48 + cb] = acc3[reg];
    }
  }
  __syncthreads();

  // epilogue (r14-identical): ti/tj, tj->out (fp16), a1, banked a1 stats
  float s1 = 0.f, s2 = 0.f;
  #pragma unroll
  for (int ri = 0; ri < 4; ++ri) {
    const long e = b0 + lr0 + ri;
    float part = 0.0f;
    if (e < E) {
      const float4 Pd = h4_to_f4(pdv[ri]);
      const float4 Ps = h4_to_f4(psv[ri]);
      const float4 m = *(const float4*)&accs[(lr0 + ri) * 68 + c0];
      float tj[4];
      const float ti0 = sp_f(Pd.x + m.x);
      const float ti1 = sp_f(Pd.y + m.y);
      const float ti2 = sp_f(Pd.z + m.z);
      const float ti3 = sp_f(Pd.w + m.w);
      tj[0] = sp_f(Ps.x + m.x);
      tj[1] = sp_f(Ps.y + m.y);
      tj[2] = sp_f(Ps.z + m.z);
      tj[3] = sp_f(Ps.w + m.w);
      ushort4 u;
      u.x = f2h(tj[0]); u.y = f2h(tj[1]); u.z = f2h(tj[2]); u.w = f2h(tj[3]);
      *(ushort4*)&out[e * 64 + c0] = u;
      part = ti0 * atts[c0] + ti1 * atts[c0 + 1] + ti2 * atts[c0 + 2] + ti3 * atts[c0 + 3]
           + tj[0] * atts[64 + c0] + tj[1] * atts[64 + c0 + 1]
           + tj[2] * atts[64 + c0 + 2] + tj[3] * atts[64 + c0 + 3];
    }
    #pragma unroll
    for (int off = 8; off; off >>= 1) part += __shfl_xor(part, off);
    if ((tx & 15) == 0 && e < E) {
      const float v = sp_f(part);
      a1[e] = v;
      s1 += v; s2 += v * v;
    }
  }
  s1 += __shfl_xor(s1, 16); s2 += __shfl_xor(s2, 16);
  s1 += __shfl_xor(s1, 32); s2 += __shfl_xor(s2, 32);
  if ((tx & 63) == 0) { ssum[tx >> 6] = s1; ssq[tx >> 6] = s2; }
  __syncthreads();
  if (tx == 0) {
    const int bk = blockIdx.x & 63;   // 64-way banked (r11/r15 lesson)
    atomicAdd(&stats[bk], ssum[0] + ssum[1] + ssum[2] + ssum[3]);
    atomicAdd(&stats[64 + bk], ssq[0] + ssq[1] + ssq[2] + ssq[3]);
  }
}

// ---------- CSR build (once per launch) -------------------------------------
__global__ __launch_bounds__(256) void k_count(
    const int* __restrict__ dst, int* __restrict__ counts, int E)
{
  for (int i = blockIdx.x * 256 + threadIdx.x; i < E; i += gridDim.x * 256)
    atomicAdd(&counts[dst[i]], 1);
}

__global__ __launch_bounds__(256) void k_scan1(
    const int* __restrict__ counts, int* __restrict__ offs,
    int* __restrict__ bsum, int N)
{
  __shared__ int sm[256];
  const int t = threadIdx.x;
  const int idx = blockIdx.x * 256 + t;
  const int v = (idx < N) ? counts[idx] : 0;
  sm[t] = v;
  __syncthreads();
  for (int off = 1; off < 256; off <<= 1) {
    const int u = (t >= off) ? sm[t - off] : 0;
    __syncthreads();
    sm[t] += u;
    __syncthreads();
  }
  if (idx < N) offs[idx] = sm[t] - v;
  if (t == 255) bsum[blockIdx.x] = sm[255];
}

__global__ __launch_bounds__(1024) void k_scan2(int* __restrict__ bsum, int SB)
{
  __shared__ int sm[1024];
  const int t = threadIdx.x;
  const int v = (t < SB) ? bsum[t] : 0;
  sm[t] = v;
  __syncthreads();
  for (int off = 1; off < 1024; off <<= 1) {
    const int u = (t >= off) ? sm[t - off] : 0;
    __syncthreads();
    sm[t] += u;
    __syncthreads();
  }
  if (t < SB) bsum[t] = sm[t] - v;
}

__global__ __launch_bounds__(256) void k_scan3(
    int* __restrict__ offs, const int* __restrict__ bsum, int N, int E)
{
  const int idx = blockIdx.x * 256 + threadIdx.x;
  if (idx < N) offs[idx] += bsum[blockIdx.x];
  if (idx == 0) offs[N] = E;
}

__global__ __launch_bounds__(256) void k_fill(
    const int* __restrict__ dst, const int* __restrict__ offs,
    int* __restrict__ cursors, int* __restrict__ eids, int E)
{
  for (int i = blockIdx.x * 256 + threadIdx.x; i < E; i += gridDim.x * 256) {
    const int d = dst[i];
    eids[offs[d] + atomicAdd(&cursors[d], 1)] = i;
  }
}

__global__ __launch_bounds__(256) void k_permidx(
    const int* __restrict__ eids, const int* __restrict__ eidx,
    int* __restrict__ srcp, int* __restrict__ dstp, int E)
{
  for (int i = blockIdx.x * 256 + threadIdx.x; i < E; i += gridDim.x * 256) {
    const int e = eids[i];
    srcp[i] = eidx[e];
    dstp[i] = eidx[(long)E + e];
  }
}

// ---------- aggregate: sequential CSR reads, banked stats -------------------
__global__ __launch_bounds__(256) void k_aggregate(
    const int* __restrict__ offs, const float* __restrict__ a1p,
    const ushortt* __restrict__ Mp, const float* __restrict__ stats,
    float invE, float* __restrict__ aggn, float* __restrict__ cs, int N)
{
  __shared__ float sm_mean, sm_scl;
  const int tx = threadIdx.x;
  if (tx < 64) {
    float s1 = stats[tx];
    float s2 = stats[64 + tx];
    #pragma unroll
    for (int off = 32; off; off >>= 1) {
      s1 += __shfl_xor(s1, off);
      s2 += __shfl_xor(s2, off);
    }
    if (tx == 0) {
      const float mean = s1 * invE;
      sm_mean = mean;
      sm_scl = rsqrtf(s2 * invE - mean * mean + 1e-5f);
    }
  }
  __syncthreads();
  const float mean = sm_mean;
  const float scl = sm_scl;

  const int t = tx & 63;
  const int wid = tx >> 6;
  float s = 0.f, s2 = 0.f;
  const long step = (long)gridDim.x * 4;
  for (long n = (long)blockIdx.x * 4 + wid; n < N; n += step) {
    const int o0 = offs[n];
    const int o1 = offs[n + 1];
    float av = 0.f, sew = 0.f;
    #pragma unroll 4
    for (int i = o0; i < o1; ++i) {
      const float w = __expf(sp_f((a1p[i] - mean) * scl));
      av = fmaf(h2f(Mp[(long)i * 64 + t]), w, av);
      sew += w;
    }
    const float v = (o1 > o0) ? av / sew : 0.0f;
    aggn[n * 64 + t] = v;
    s += v; s2 += v * v;
  }
  __shared__ float b1[256], b2[256];
  b1[tx] = s; b2[tx] = s2;
  __syncthreads();
  if (tx < 64) {
    const int bank = (blockIdx.x & 15) * 128;
    atomicAdd(&cs[bank + t], b1[t] + b1[64 + t] + b1[128 + t] + b1[192 + t]);
    atomicAdd(&cs[bank + 64 + t], b2[t] + b2[64 + t] + b2[128 + t] + b2[192 + t]);
  }
}

__global__ __launch_bounds__(256) void k_hnew(
    const float* __restrict__ aggn, const float* __restrict__ cs,
    float invN, float* __restrict__ h, int N)
{
  const int c = threadIdx.x & 63;
  const int r = threadIdx.x >> 6;
  float mn = 0.f, sq = 0.f;
  #pragma unroll
  for (int bk = 0; bk < 16; ++bk) {
    mn += cs[bk * 128 + c];
    sq += cs[bk * 128 + 64 + c];
  }
  mn *= invN; sq *= invN;
  const float scl = rsqrtf(sq - mn * mn + 1e-5f);
  for (long n = (long)blockIdx.x * 4 + r; n < N; n += (long)gridDim.x * 4)
    h[n * 64 + c] = sp_f((aggn[n * 64 + c] - mn) * scl);
}

// composition attention: per block 64-node tile, LDS-staged q + Wc, 8-way ILP
#define QSS 170
__global__ __launch_bounds__(256) void k_comp(
    const float* __restrict__ h, const float* __restrict__ gf,
    const int* __restrict__ batch, const float* __restrict__ Wc,
    const float* __restrict__ bc, const float* __restrict__ aw,
    const float* __restrict__ ab, float* __restrict__ aN, int N)
{
  __shared__ __align__(16) float qs[64 * QSS];
  __shared__ __align__(16) float Wcs[167 * 32];
  __shared__ float aws[32], bcs[32];
  const int tx = threadIdx.x;
  const int b0 = blockIdx.x * 64;
  for (int i = tx; i < 167 * 32; i += 256) Wcs[i] = Wc[i];
  if (tx < 32) { aws[tx] = aw[tx]; bcs[tx] = bc[tx]; }
  for (int i = tx; i < 64 * 16; i += 256) {
    const int n = i >> 4;
    const int c4 = (i & 15) << 2;
    long r = b0 + n; if (r >= N) r = N - 1;
    *(float4*)&qs[n * QSS + c4] = *(const float4*)&h[r * 64 + c4];
  }
  for (int i = tx; i < 64 * 103; i += 256) {
    const int n = i / 103;
    const int c = i % 103;
    long r = b0 + n; if (r >= N) r = N - 1;
    qs[n * QSS + 64 + c] = gf[(long)batch[r] * 103 + c];
  }
  __syncthreads();

  const int n = tx >> 2;
  const int colg = (tx & 3) << 3;
  float acc[8];
  #pragma unroll
  for (int j = 0; j < 8; ++j) acc[j] = 0.f;
  #pragma unroll 2
  for (int k = 0; k < 167; ++k) {
    const float q = qs[n * QSS + k];
    const float4 w0 = *(const float4*)&Wcs[k * 32 + colg];
    const float4 w1 = *(const float4*)&Wcs[k * 32 + colg + 4];
    acc[0] = fmaf(q, w0.x, acc[0]);
    acc[1] = fmaf(q, w0.y, acc[1]);
    acc[2] = fmaf(q, w0.z, acc[2]);
    acc[3] = fmaf(q, w0.w, acc[3]);
    acc[4] = fmaf(q, w1.x, acc[4]);
    acc[5] = fmaf(q, w1.y, acc[5]);
    acc[6] = fmaf(q, w1.z, acc[6]);
    acc[7] = fmaf(q, w1.w, acc[7]);
  }
  float val = 0.f;
  #pragma unroll
  for (int j = 0; j < 8; ++j)
    val += sp_f(acc[j] + bcs[colg + j]) * aws[colg + j];
  val += __shfl_xor(val, 1);
  val += __shfl_xor(val, 2);
  const long r = b0 + n;
  if ((tx & 3) == 0 && r < N) aN[r] = val + ab[0];
}

__global__ __launch_bounds__(64) void k_pool(
    const float* __restrict__ h, const float* __restrict__ aN,
    const int* __restrict__ batch, const float* __restrict__ fcW,
    const float* __restrict__ fcb, float* __restrict__ out, int N, int G)
{
  const int g = blockIdx.x;
  const int t = threadIdx.x;
  int lo = 0, hi = N;
  while (lo < hi) { int mid = (lo + hi) >> 1; if (batch[mid] < g) lo = mid + 1; else hi = mid; }
  const int s = lo;
  hi = N;
  while (lo < hi) { int mid = (lo + hi) >> 1; if (batch[mid] < g + 1) lo = mid + 1; else hi = mid; }
  const int e2 = lo;
  if (s >= e2) { if (t == 0) out[g] = fcb[0]; return; }
  float mx = -1e30f;
  for (int i = s + t; i < e2; i += 64) mx = fmaxf(mx, aN[i]);
  #pragma unroll
  for (int off = 32; off; off >>= 1) mx = fmaxf(mx, __shfl_xor(mx, off));
  float se = 0.f;
  for (int i = s + t; i < e2; i += 64) se += __expf(aN[i] - mx);
  #pragma unroll
  for (int off = 32; off; off >>= 1) se += __shfl_xor(se, off);
  float acc = 0.f;
  for (int n = s; n < e2; ++n) {
    const float w = __expf(aN[n] - mx);
    acc = fmaf(h[(long)n * 64 + t], w, acc);
  }
  float part = (acc / se) * fcW[t];
  #pragma unroll
  for (int off = 32; off; off >>= 1) part += __shfl_xor(part, off);
  if (t == 0) out[g] = part + fcb[0];
}

extern "C" void kernel_launch(void* const* d_in, const int* in_sizes, int n_in,
                              void* d_out, int out_size, void* d_ws, size_t ws_size,
                              hipStream_t stream)
{
  const float* x     = (const float*)d_in[0];
  const int*   eidx  = (const int*)  d_in[1];
  const float* eattr = (const float*)d_in[2];
  const int*   batch = (const int*)  d_in[3];
  const float* gfeat = (const float*)d_in[4];
  const float* embnW = (const float*)d_in[5];
  const float* embnb = (const float*)d_in[6];
  const float* embeW = (const float*)d_in[7];
  const float* embeb = (const float*)d_in[8];
  const float* convW = (const float*)d_in[9];
  const float* convA = (const float*)d_in[10];
  // d_in[11] = conv_bias: cancels exactly in training-mode BatchNorm
  const float* compW = (const float*)d_in[12];
  const float* compb = (const float*)d_in[13];
  const float* attW  = (const float*)d_in[14];
  const float* attb  = (const float*)d_in[15];
  const float* fcW   = (const float*)d_in[16];
  const float* fcb   = (const float*)d_in[17];
  float* out = (float*)d_out;

  const int N = in_sizes[0] / 92;
  const int E = in_sizes[1] / 2;
  const int G = in_sizes[4] / 103;
  const float invN = 1.0f / (float)N;
  const float invE = 1.0f / (float)E;

  // workspace (~140 MB)
  char* pw = (char*)d_ws;
  float* h     = (float*)pw;  pw += (size_t)N * 64 * 4;
  float* aggn  = (float*)pw;  pw += (size_t)N * 64 * 4;
  float* aE    = (float*)pw;  pw += (size_t)E * 4;        // a1 (CSR-ordered)
  float* statsB = (float*)pw; pw += 3 * SLOTS * 4;
  float* aN    = (float*)pw;  pw += (size_t)N * 4;
  int* counts  = (int*)pw;    pw += (size_t)N * 4;
  int* cursors = (int*)pw;    pw += (size_t)N * 4;
  int* offs    = (int*)pw;    pw += ((size_t)N + 1) * 4;
  int* bsum    = (int*)pw;    pw += 1024 * 4;
  int* eids    = (int*)pw;    pw += (size_t)E * 4;
  int* srcp    = (int*)pw;    pw += (size_t)E * 4;
  int* dstp    = (int*)pw;    pw += (size_t)E * 4;
  pw = (char*)(((size_t)pw + 63) & ~(size_t)63);
  uint4* WBg   = (uint4*)pw;   pw += 3 * 512 * 16;        // packed B frags
  ushortt* Pp  = (ushortt*)pw; pw += (size_t)N * 64 * 2;  // P fp16
  ushortt* ea  = (ushortt*)pw; pw += (size_t)E * 64 * 2;  // fp16, CSR-ordered
  ushortt* M   = (ushortt*)pw;                            // fp16 tj, CSR-ordered

  const int gE64 = (E + 63) / 64;
  const int gN64 = (N + 63) / 64;
  const int SB = (N + 255) / 256;

  hipMemsetAsync(counts, 0, 2 * (size_t)N * sizeof(int), stream);
  hipMemsetAsync(statsB, 0, 3 * SLOTS * sizeof(float), stream);
  k_count<<<2048, 256, 0, stream>>>(eidx + E, counts, E);
  k_scan1<<<SB, 256, 0, stream>>>(counts, offs, bsum, N);
  k_scan2<<<1, 1024, 0, stream>>>(bsum, SB);
  k_scan3<<<SB, 256, 0, stream>>>(offs, bsum, N, E);
  k_fill<<<2048, 256, 0, stream>>>(eidx + E, offs, cursors, eids, E);
  k_permidx<<<2048, 256, 0, stream>>>(eids, eidx, srcp, dstp, E);
  k_packW<<<3, 512, 0, stream>>>(convW, WBg);

  k_gemm_rt<92, 0, 1, 0, 0, float, float><<<gN64, 256, 0, stream>>>(
      x, embnW, embnb, h, N, nullptr, nullptr, 0.f);
  k_gemm_rt<41, 1, 1, 1, 0, float, ushortt><<<gE64, 256, 0, stream>>>(
      eattr, embeW, embeb, ea, E, eids, nullptr, 0.f);

  for (int l = 0; l < 3; ++l) {
    const float* Wl = convW + (size_t)l * 128 * 64;
    const float* Al = convA + (size_t)l * 128;
    float* statsL = statsB + (size_t)l * SLOTS;
    if (l == 0) {
      k_gemm_rt<64, 0, 0, 0, 0, float, ushortt><<<gN64, 256, 0, stream>>>(
          h, Wl, nullptr, Pp, N, nullptr, nullptr, 0.f);
    } else {
      k_gemm_rt<64, 0, 0, 0, 1, float, ushortt><<<gN64, 256, 0, stream>>>(
          aggn, Wl, nullptr, Pp, N, nullptr,
          statsB + (size_t)(l - 1) * SLOTS + 128, invN);
    }
    k_efused<<<gE64, 256, 0, stream>>>(ea, WBg + (size_t)l * 512, M, E,
                                       Pp, srcp, dstp, Al, aE, statsL);
    k_aggregate<<<2048, 256, 0, stream>>>(offs, aE, M, statsL,
                                          invE, aggn, statsL + 128, N);
  }

  k_hnew<<<2048, 256, 0, stream>>>(aggn, statsB + 2 * SLOTS + 128, invN, h, N);
  k_comp<<<gN64, 256, 0, stream>>>(h, gfeat, batch, compW, compb, attW, attb, aN, N);
  k_pool<<<G, 64, 0, stream>>>(h, aN, batch, fcW, fcb, out, N, G);

  (void)n_in; (void)out_size; (void)ws_size;
}